// Round 9
// baseline (234.089 us; speedup 1.0000x reference)
//
#include <hip/hip_runtime.h>
#include <math.h>

// Problem constants
#define BATCH 8
#define CH    256
#define HDIM  56
#define WDIM  56
#define HW    (HDIM*WDIM)          // 3136
#define MTOT  (BATCH*HW)           // 25088
#define GRP   8
#define GC    32
#define NP    9                    // K*K
#define NOFF  (GRP*NP*2)           // 144
#define NMSK  (GRP*NP)             // 72
#define NTOT  (NOFF+NMSK)          // 216
#define POSB  4                    // positions per sample block
#define NBLK128 ((MTOT/128)*2)     // 392: 196 m-tiles x 2 n-tiles
#define NBLKOUT ((MTOT/128)*4)     // 784: 196 m-tiles x 4 n-tiles (64 wide)

typedef float f32x4 __attribute__((ext_vector_type(4)));
typedef short s16x8 __attribute__((ext_vector_type(8)));

// split a,b into packed bf16 hi (truncation) and bf16 lo (exact remainder, truncated)
__device__ inline void split2(float a, float b, unsigned int& hp, unsigned int& lp)
{
    const unsigned int ua = __float_as_uint(a), ub = __float_as_uint(b);
    hp = (ub & 0xffff0000u) | (ua >> 16);
    const float ha = __uint_as_float(ua & 0xffff0000u);
    const float hb = __uint_as_float(ub & 0xffff0000u);
    const unsigned int la = __float_as_uint(a - ha), lb = __float_as_uint(b - hb);
    lp = (lb & 0xffff0000u) | (la >> 16);
}

// async global(16B/lane) -> LDS (wave-uniform base + lane*16)
__device__ __forceinline__ void gld_lds16(const unsigned short* g, unsigned short* l)
{
    __builtin_amdgcn_global_load_lds(
        (const __attribute__((address_space(1))) unsigned int*)g,
        (__attribute__((address_space(3))) unsigned int*)l, 16, 0, 0);
}

// ---------------------------------------------------------------------------
// Transpose + split x (NCHW) -> xt_hi/xt_lo [m][k] bf16. 64x64 LDS tiles.
// ---------------------------------------------------------------------------
__global__ __launch_bounds__(256)
void xt_split_kernel(const float* __restrict__ x,
                     unsigned short* __restrict__ hi,
                     unsigned short* __restrict__ lo)
{
    __shared__ float lds[64][68];
    const int hw0 = blockIdx.x * 64;       // 49 tiles (3136/64)
    const int k0  = blockIdx.y * 64;       // 4 tiles
    const int b   = blockIdx.z;            // 8
    const int t = threadIdx.x;
    #pragma unroll
    for (int p = 0; p < 4; ++p) {
        const int kr = (t >> 4) + p * 16;
        const int hc = (t & 15) * 4;
        *(float4*)&lds[kr][hc] =
            *(const float4*)(x + ((size_t)b * CH + k0 + kr) * HW + hw0 + hc);
    }
    __syncthreads();
    const int ml = t >> 2;             // m-row 0..63
    const int kc = (t & 3) * 16;       // k base 0,16,32,48
    unsigned int hbuf[8], lbuf[8];
    #pragma unroll
    for (int j = 0; j < 16; j += 2)
        split2(lds[kc + j][ml], lds[kc + j + 1][ml], hbuf[j >> 1], lbuf[j >> 1]);
    const size_t row = (size_t)(b * HW + hw0 + ml) * CH + k0 + kc;
    *(uint4*)&hi[row]     = *(uint4*)&hbuf[0];
    *(uint4*)&hi[row + 8] = *(uint4*)&hbuf[4];
    *(uint4*)&lo[row]     = *(uint4*)&lbuf[0];
    *(uint4*)&lo[row + 8] = *(uint4*)&lbuf[4];
}

// ---------------------------------------------------------------------------
// m97-style GEMM body: 128x128 tile, 4 waves (2m x 2n quadrants), BK=32,
// single-buffered LDS, 2-barrier k-loop, global_load_lds width-16 staging.
// Slot swizzle (slot ^= (row>>1)&3) applied on BOTH sides. (round-8 verified)
// ---------------------------------------------------------------------------
__device__ __forceinline__ void gemm128_body(
    const unsigned short* __restrict__ ahi,
    const unsigned short* __restrict__ alo,
    const unsigned short* __restrict__ whi,
    const unsigned short* __restrict__ wlo,
    unsigned short* sAh, unsigned short* sAl,
    unsigned short* sBh, unsigned short* sBl,
    int m0, int n0g, int t, f32x4 (&acc)[4][4])
{
    const int lane = t & 63, wv4 = t >> 6;
    const int wm = wv4 & 1, wn = wv4 >> 1;
    const int fm = lane & 15, q = lane >> 4;

    // staging decomposition (per issue i: 256 thr x 16B = 64 rows)
    int srow[2], sgs[2], slb[2];
    #pragma unroll
    for (int i = 0; i < 2; ++i) {
        const int u = i * 256 + t;
        srow[i] = u >> 2;
        const int ss = u & 3;
        sgs[i] = ss ^ ((srow[i] >> 1) & 3);      // pre-swizzled source slot
        slb[i] = i * 2048 + wv4 * 512;           // wave-uniform LDS base (shorts)
    }

    for (int kk = 0; kk < 8; ++kk) {
        const int k0 = kk * 32;
        #pragma unroll
        for (int i = 0; i < 2; ++i) {
            const size_t ga = (size_t)(m0 + srow[i]) * CH + k0 + sgs[i] * 8;
            const size_t gb = (size_t)(n0g + srow[i]) * CH + k0 + sgs[i] * 8;
            gld_lds16(ahi + ga, sAh + slb[i]);
            gld_lds16(alo + ga, sAl + slb[i]);
            gld_lds16(whi + gb, sBh + slb[i]);
            gld_lds16(wlo + gb, sBl + slb[i]);
        }
        __syncthreads();                          // vmcnt(0) drain + barrier

        s16x8 ah[4], al[4], wh[4], wl[4];
        #pragma unroll
        for (int i = 0; i < 4; ++i) {
            const int ar = wm * 64 + i * 16 + fm;
            const int as = (q ^ ((ar >> 1) & 3)) * 8;
            ah[i] = *(const s16x8*)&sAh[ar * 32 + as];
            al[i] = *(const s16x8*)&sAl[ar * 32 + as];
            const int br = wn * 64 + i * 16 + fm;
            const int bs = (q ^ ((br >> 1) & 3)) * 8;
            wh[i] = *(const s16x8*)&sBh[br * 32 + bs];
            wl[i] = *(const s16x8*)&sBl[br * 32 + bs];
        }
        #pragma unroll
        for (int nt = 0; nt < 4; ++nt)
            #pragma unroll
            for (int mt = 0; mt < 4; ++mt) {
                acc[nt][mt] = __builtin_amdgcn_mfma_f32_16x16x32_bf16(wh[nt], ah[mt], acc[nt][mt], 0, 0, 0);
                acc[nt][mt] = __builtin_amdgcn_mfma_f32_16x16x32_bf16(wh[nt], al[mt], acc[nt][mt], 0, 0, 0);
                acc[nt][mt] = __builtin_amdgcn_mfma_f32_16x16x32_bf16(wl[nt], ah[mt], acc[nt][mt], 0, 0, 0);
            }
        __syncthreads();                          // before next-stage overwrite
    }
}

// ---------------------------------------------------------------------------
// DUAL GEMM (both middle projections), 128x128 tiles, LDS-staged.
// bid<NBLK128: v = xt @ w_in; else: omb = f @ wt2. ~HBM roofline (round 8).
// ---------------------------------------------------------------------------
__global__ __launch_bounds__(256)
void gemm128_dual(const unsigned short* __restrict__ ahi1,
                  const unsigned short* __restrict__ alo1,
                  const unsigned short* __restrict__ whi1,
                  const unsigned short* __restrict__ wlo1,
                  const float* __restrict__ bias1,
                  float* __restrict__ out1,
                  const unsigned short* __restrict__ ahi2,
                  const unsigned short* __restrict__ alo2,
                  const unsigned short* __restrict__ whi2,
                  const unsigned short* __restrict__ wlo2,
                  const float* __restrict__ bias2,
                  float* __restrict__ out2)
{
    __shared__ unsigned short sAh[128*32], sAl[128*32], sBh[128*32], sBl[128*32];

    const int half = blockIdx.x >= NBLK128;
    const int lbid = blockIdx.x - (half ? NBLK128 : 0);
    const unsigned short* ahi = half ? ahi2 : ahi1;
    const unsigned short* alo = half ? alo2 : alo1;
    const unsigned short* whi = half ? whi2 : whi1;
    const unsigned short* wlo = half ? wlo2 : wlo1;
    const float* bias = half ? bias2 : bias1;
    float* out = half ? out2 : out1;

    const int sw = (lbid & 7) * (NBLK128 / 8) + (lbid >> 3);   // bijective, 392=8*49
    const int m0 = (sw >> 1) * 128;
    const int n0g = (sw & 1) * 128;
    const int t = threadIdx.x;
    const int lane = t & 63, wv4 = t >> 6;
    const int wm = wv4 & 1, wn = wv4 >> 1;
    const int fm = lane & 15, q = lane >> 4;

    f32x4 acc[4][4];
    const f32x4 zero = {0.0f, 0.0f, 0.0f, 0.0f};
    #pragma unroll
    for (int i = 0; i < 4; ++i)
        #pragma unroll
        for (int j = 0; j < 4; ++j) acc[i][j] = zero;

    gemm128_body(ahi, alo, whi, wlo, sAh, sAl, sBh, sBl, m0, n0g, t, acc);

    #pragma unroll
    for (int nt = 0; nt < 4; ++nt) {
        const int n = n0g + wn*64 + nt*16 + q*4;
        const float4 b4 = *(const float4*)&bias[n];
        #pragma unroll
        for (int mt = 0; mt < 4; ++mt) {
            const int mm = m0 + wm*64 + mt*16 + fm;
            f32x4 o = acc[nt][mt];
            o[0] += b4.x; o[1] += b4.y; o[2] += b4.z; o[3] += b4.w;
            *(f32x4*)&out[(size_t)mm * CH + n] = o;
        }
    }
}

// ---------------------------------------------------------------------------
// Output GEMM, 128m x 64n tiles, 128 threads (2 waves, one 64x64 quadrant
// each), LDS-staged. Grid 784 = 8 XCDs x 98 -> ~3 blocks/CU: the cross-block
// pipeline overlap that put gemm128_dual at its HBM roofline (round 8's
// isolated lever: 392 blocks = 1.5/CU was the ONLY difference keeping this
// GEMM at 50 us). Same k-order + 3-MFMA chain -> bit-identical math.
// Consecutive n-tiles of an m-tile land on the same XCD -> A re-reads L2-hit.
// ---------------------------------------------------------------------------
__global__ __launch_bounds__(128)
void gemm_out_128x64(const unsigned short* __restrict__ ahi,
                     const unsigned short* __restrict__ alo,
                     const unsigned short* __restrict__ whi,
                     const unsigned short* __restrict__ wlo,
                     const float* __restrict__ bias,
                     const float* __restrict__ bn_g,
                     const float* __restrict__ bn_b,
                     const float* __restrict__ bn_mean,
                     const float* __restrict__ bn_var,
                     float* __restrict__ y)                  // [B,256,3136]
{
    __shared__ unsigned short sAh[128*32], sAl[128*32], sBh[64*32], sBl[64*32];

    const int sw = (blockIdx.x & 7) * (NBLKOUT / 8) + (blockIdx.x >> 3);
    const int m0  = (sw >> 2) * 128;           // 196 m-tiles
    const int n0g = (sw & 3) * 64;             // 4 n-tiles
    const int t = threadIdx.x;
    const int lane = t & 63, wid = t >> 6;     // 2 waves: m-quadrant
    const int fm = lane & 15, q = lane >> 4;

    f32x4 acc[4][4];
    const f32x4 zero = {0.0f, 0.0f, 0.0f, 0.0f};
    #pragma unroll
    for (int i = 0; i < 4; ++i)
        #pragma unroll
        for (int j = 0; j < 4; ++j) acc[i][j] = zero;

    // staging decomposition: per issue 128 thr x 16B = 32 rows.
    // A: 4 issues (128 rows); B: 2 issues (64 rows). Linear LDS dest
    // (u*16B), pre-swizzled global source slot, XOR on read (rule #21).
    int arow[4], asl[4], albase[4];
    #pragma unroll
    for (int i = 0; i < 4; ++i) {
        const int u = i * 128 + t;
        arow[i] = u >> 2;
        asl[i] = (u & 3) ^ ((arow[i] >> 1) & 3);
        albase[i] = i * 1024 + wid * 512;      // shorts; wave-uniform
    }
    int brow[2], bsl[2], blbase[2];
    #pragma unroll
    for (int i = 0; i < 2; ++i) {
        const int u = i * 128 + t;
        brow[i] = u >> 2;
        bsl[i] = (u & 3) ^ ((brow[i] >> 1) & 3);
        blbase[i] = i * 1024 + wid * 512;
    }

    for (int kk = 0; kk < 8; ++kk) {
        const int k0 = kk * 32;
        #pragma unroll
        for (int i = 0; i < 4; ++i) {
            const size_t ga = (size_t)(m0 + arow[i]) * CH + k0 + asl[i] * 8;
            gld_lds16(ahi + ga, sAh + albase[i]);
            gld_lds16(alo + ga, sAl + albase[i]);
        }
        #pragma unroll
        for (int i = 0; i < 2; ++i) {
            const size_t gb = (size_t)(n0g + brow[i]) * CH + k0 + bsl[i] * 8;
            gld_lds16(whi + gb, sBh + blbase[i]);
            gld_lds16(wlo + gb, sBl + blbase[i]);
        }
        __syncthreads();

        s16x8 ah[4], al[4], wh[4], wl[4];
        #pragma unroll
        for (int i = 0; i < 4; ++i) {
            const int ar = wid * 64 + i * 16 + fm;
            const int as = (q ^ ((ar >> 1) & 3)) * 8;
            ah[i] = *(const s16x8*)&sAh[ar * 32 + as];
            al[i] = *(const s16x8*)&sAl[ar * 32 + as];
            const int br = i * 16 + fm;
            const int bs = (q ^ ((br >> 1) & 3)) * 8;
            wh[i] = *(const s16x8*)&sBh[br * 32 + bs];
            wl[i] = *(const s16x8*)&sBl[br * 32 + bs];
        }
        #pragma unroll
        for (int nt = 0; nt < 4; ++nt)
            #pragma unroll
            for (int mt = 0; mt < 4; ++mt) {
                acc[nt][mt] = __builtin_amdgcn_mfma_f32_16x16x32_bf16(wh[nt], ah[mt], acc[nt][mt], 0, 0, 0);
                acc[nt][mt] = __builtin_amdgcn_mfma_f32_16x16x32_bf16(wh[nt], al[mt], acc[nt][mt], 0, 0, 0);
                acc[nt][mt] = __builtin_amdgcn_mfma_f32_16x16x32_bf16(wl[nt], ah[mt], acc[nt][mt], 0, 0, 0);
            }
        __syncthreads();
    }

    #pragma unroll
    for (int nt = 0; nt < 4; ++nt) {
        #pragma unroll
        for (int r = 0; r < 4; ++r) {
            const int n = n0g + nt*16 + q*4 + r;
            const float sc = bn_g[n] * rsqrtf(bn_var[n] + 1e-5f);
            const float sb = bn_b[n] - bn_mean[n] * sc;
            const float bs = bias[n];
            #pragma unroll
            for (int mt = 0; mt < 4; ++mt) {
                const int mm = m0 + wid*64 + mt*16 + fm;
                const int bimg = mm / HW, hw = mm % HW;
                float val = (acc[nt][mt][r] + bs) * sc + sb;
                y[(size_t)bimg * CH * HW + (size_t)n * HW + hw] = val / (1.0f + expf(-val));
            }
        }
    }
}

// ---------------------------------------------------------------------------
// Fallback GEMM (proven round-4 structure): 256m x 64n blocks, grid (98,4).
// ---------------------------------------------------------------------------
__global__ __launch_bounds__(256)
void gemm_in_mfma(const unsigned short* __restrict__ xhi, // [m][k]
                  const unsigned short* __restrict__ xlo,
                  const unsigned short* __restrict__ whi, // [n][k]
                  const unsigned short* __restrict__ wlo,
                  const float* __restrict__ bias,
                  float* __restrict__ v)                  // [MTOT,256]
{
    const int m0 = blockIdx.x * 256;
    const int n0 = blockIdx.y * 64;
    const int t = threadIdx.x;
    const int lane = t & 63, wv = t >> 6;
    const int mblk = m0 + wv * 64;
    const int fm = lane & 15;
    const int q  = lane >> 4;

    f32x4 acc[4][4];              // [nt][mt]
    const f32x4 zero = {0.0f, 0.0f, 0.0f, 0.0f};
    #pragma unroll
    for (int i = 0; i < 4; ++i)
        #pragma unroll
        for (int j = 0; j < 4; ++j) acc[i][j] = zero;

    const unsigned short *xrh[4], *xrl[4], *wrh[4], *wrl[4];
    #pragma unroll
    for (int mt = 0; mt < 4; ++mt) {
        xrh[mt] = xhi + (size_t)(mblk + mt*16 + fm) * CH + q * 8;
        xrl[mt] = xlo + (size_t)(mblk + mt*16 + fm) * CH + q * 8;
    }
    #pragma unroll
    for (int nt = 0; nt < 4; ++nt) {
        wrh[nt] = whi + (size_t)(n0 + nt*16 + fm) * CH + q * 8;
        wrl[nt] = wlo + (size_t)(n0 + nt*16 + fm) * CH + q * 8;
    }

    for (int k0 = 0; k0 < CH; k0 += 32) {
        s16x8 wh[4], wl[4], ah[4], al[4];
        #pragma unroll
        for (int nt = 0; nt < 4; ++nt) {
            wh[nt] = *(const s16x8*)(wrh[nt] + k0);
            wl[nt] = *(const s16x8*)(wrl[nt] + k0);
        }
        #pragma unroll
        for (int mt = 0; mt < 4; ++mt) {
            ah[mt] = *(const s16x8*)(xrh[mt] + k0);
            al[mt] = *(const s16x8*)(xrl[mt] + k0);
        }
        #pragma unroll
        for (int nt = 0; nt < 4; ++nt)
            #pragma unroll
            for (int mt = 0; mt < 4; ++mt) {
                acc[nt][mt] = __builtin_amdgcn_mfma_f32_16x16x32_bf16(wh[nt], ah[mt], acc[nt][mt], 0, 0, 0);
                acc[nt][mt] = __builtin_amdgcn_mfma_f32_16x16x32_bf16(wh[nt], al[mt], acc[nt][mt], 0, 0, 0);
                acc[nt][mt] = __builtin_amdgcn_mfma_f32_16x16x32_bf16(wl[nt], ah[mt], acc[nt][mt], 0, 0, 0);
            }
    }

    #pragma unroll
    for (int nt = 0; nt < 4; ++nt) {
        const float4 b4 = *(const float4*)&bias[n0 + nt*16 + q*4];
        #pragma unroll
        for (int mt = 0; mt < 4; ++mt) {
            f32x4 o = acc[nt][mt];
            o[0] += b4.x; o[1] += b4.y; o[2] += b4.z; o[3] += b4.w;
            *(f32x4*)&v[(size_t)(mblk + mt*16 + fm) * CH + n0 + nt*16 + q*4] = o;
        }
    }
}

// ---------------------------------------------------------------------------
// Per-position-wave depthwise 3x3 + bias + LN + GELU from NHWC bf16 hi/lo xt,
// output stored PRE-SPLIT as bf16 hi/lo. One wave per position.
// ---------------------------------------------------------------------------
__global__ __launch_bounds__(256)
void dw_ln_gelu_nhwc_split(const unsigned short* __restrict__ xhi,
                           const unsigned short* __restrict__ xlo,
                           const float* __restrict__ dw_w,   // [256][9]
                           const float* __restrict__ dw_b,
                           const float* __restrict__ ln_g,
                           const float* __restrict__ ln_b,
                           unsigned short* __restrict__ fh,  // [MTOT][256]
                           unsigned short* __restrict__ fl)  // [MTOT][256]
{
    __shared__ float wt[NP][CH];                       // transposed dw weights
    __shared__ float lbias[CH], lgam[CH], lbet[CH];

    const int t = threadIdx.x;
    {
        const float* wp = dw_w + t * NP;
        #pragma unroll
        for (int p = 0; p < NP; ++p) wt[p][t] = wp[p];
        lbias[t] = dw_b[t]; lgam[t] = ln_g[t]; lbet[t] = ln_b[t];
    }
    __syncthreads();

    const int nblk = MTOT / POSB;          // 6272
    const int per  = nblk / 8;             // 784
    const int bid  = blockIdx.x;
    const int sw   = (bid & 7) * per + (bid >> 3);
    const int q    = t >> 6, lane = t & 63;
    const int n    = sw * POSB + q;
    const int b    = n / HW;
    const int hw   = n % HW;
    const int h    = hw / WDIM, w = hw % WDIM;
    const int c4   = lane * 4;
    const size_t base = (size_t)b * HW * CH + c4;

    float ax = 0.0f, ay = 0.0f, az = 0.0f, aw = 0.0f;
    #pragma unroll
    for (int p = 0; p < NP; ++p) {
        const int hh = h + p / 3 - 1;
        const int ww = w + p % 3 - 1;
        if ((unsigned)hh >= (unsigned)HDIM || (unsigned)ww >= (unsigned)WDIM)
            continue;                       // wave-uniform branch (h,w per-wave)
        const size_t idx = base + (size_t)(hh * WDIM + ww) * CH;
        const ushort4 uh = *(const ushort4*)(xhi + idx);
        const ushort4 ul = *(const ushort4*)(xlo + idx);
        const float4 wv = *(const float4*)&wt[p][c4];
        ax = fmaf(__uint_as_float((unsigned)uh.x << 16), wv.x,
             fmaf(__uint_as_float((unsigned)ul.x << 16), wv.x, ax));
        ay = fmaf(__uint_as_float((unsigned)uh.y << 16), wv.y,
             fmaf(__uint_as_float((unsigned)ul.y << 16), wv.y, ay));
        az = fmaf(__uint_as_float((unsigned)uh.z << 16), wv.z,
             fmaf(__uint_as_float((unsigned)ul.z << 16), wv.z, az));
        aw = fmaf(__uint_as_float((unsigned)uh.w << 16), wv.w,
             fmaf(__uint_as_float((unsigned)ul.w << 16), wv.w, aw));
    }
    {
        const float4 b4 = *(const float4*)&lbias[c4];
        ax += b4.x; ay += b4.y; az += b4.z; aw += b4.w;
    }

    // LayerNorm over the wave's 256 channel values: in-wave butterfly.
    float s1 = ax + ay + az + aw;
    float s2 = ax*ax + ay*ay + az*az + aw*aw;
    #pragma unroll
    for (int off = 32; off > 0; off >>= 1) {
        s1 += __shfl_xor(s1, off);
        s2 += __shfl_xor(s2, off);
    }
    const float mean = s1 * (1.0f / 256.0f);
    const float rstd = rsqrtf(s2 * (1.0f / 256.0f) - mean * mean + 1e-5f);

    const float4 g4 = *(const float4*)&lgam[c4];
    const float4 e4 = *(const float4*)&lbet[c4];
    const float x0 = (ax - mean) * rstd * g4.x + e4.x;
    const float x1 = (ay - mean) * rstd * g4.y + e4.y;
    const float x2 = (az - mean) * rstd * g4.z + e4.z;
    const float x3 = (aw - mean) * rstd * g4.w + e4.w;
    const float o0 = 0.5f * x0 * (1.0f + erff(x0 * 0.70710678118654752f));
    const float o1 = 0.5f * x1 * (1.0f + erff(x1 * 0.70710678118654752f));
    const float o2 = 0.5f * x2 * (1.0f + erff(x2 * 0.70710678118654752f));
    const float o3 = 0.5f * x3 * (1.0f + erff(x3 * 0.70710678118654752f));

    unsigned int hp0, lp0, hp1, lp1;
    split2(o0, o1, hp0, lp0);
    split2(o2, o3, hp1, lp1);
    *(uint2*)&fh[(size_t)n * CH + c4] = make_uint2(hp0, hp1);
    *(uint2*)&fl[(size_t)n * CH + c4] = make_uint2(lp0, lp1);
}

// ---------------------------------------------------------------------------
// Transpose + hi/lo bf16 split of a [256k][256n] fp32 weight -> [n][k] bf16.
// ---------------------------------------------------------------------------
__global__ __launch_bounds__(256)
void wt_split_kernel(const float* __restrict__ w,
                     unsigned short* __restrict__ hi,
                     unsigned short* __restrict__ lo)
{
    __shared__ float lds[64][68];
    const int kt = blockIdx.x * 64, nt = blockIdx.y * 64;
    const int t = threadIdx.x;
    #pragma unroll
    for (int p = 0; p < 4; ++p) {
        const int kr = (t >> 4) + p * 16, nc = (t & 15) * 4;
        *(float4*)&lds[kr][nc] = *(const float4*)(w + (size_t)(kt + kr) * CH + nt + nc);
    }
    __syncthreads();
    const int nl = t >> 2, kc = (t & 3) * 16;
    #pragma unroll
    for (int j = 0; j < 16; j += 2) {
        const float f0 = lds[kc + j][nl], f1 = lds[kc + j + 1][nl];
        unsigned int hp, lp;
        split2(f0, f1, hp, lp);
        *(unsigned int*)&hi[(size_t)(nt + nl) * CH + kt + kc + j] = hp;
        *(unsigned int*)&lo[(size_t)(nt + nl) * CH + kt + kc + j] = lp;
    }
}

// ---------------------------------------------------------------------------
// Transpose + split of [w_off | w_mask] -> wt2_hi/lo [256 n_pad][256 k] bf16.
// Also builds bcat[256] = [b_off | b_mask | 0] (block 0 only).
// ---------------------------------------------------------------------------
__global__ __launch_bounds__(256)
void wt2_split_kernel(const float* __restrict__ w_off,   // [256][144]
                      const float* __restrict__ w_mask,  // [256][72]
                      const float* __restrict__ b_off,
                      const float* __restrict__ b_mask,
                      unsigned short* __restrict__ hi,
                      unsigned short* __restrict__ lo,
                      float* __restrict__ bcat)          // [256]
{
    const int n = threadIdx.x;
    if (blockIdx.x == 0) {
        bcat[n] = (n < NOFF) ? b_off[n] : ((n < NTOT) ? b_mask[n - NOFF] : 0.0f);
    }
    const int k0 = blockIdx.x * 16;
    #pragma unroll
    for (int j = 0; j < 16; j += 2) {
        const int k = k0 + j;
        float f0 = 0.0f, f1 = 0.0f;
        if (n < NOFF) {
            f0 = w_off[(size_t)k * NOFF + n];
            f1 = w_off[(size_t)(k + 1) * NOFF + n];
        } else if (n < NTOT) {
            f0 = w_mask[(size_t)k * NMSK + (n - NOFF)];
            f1 = w_mask[(size_t)(k + 1) * NMSK + (n - NOFF)];
        }
        unsigned int hp, lp;
        split2(f0, f1, hp, lp);
        *(unsigned int*)&hi[(size_t)n * CH + k] = hp;
        *(unsigned int*)&lo[(size_t)n * CH + k] = lp;
    }
}

// ---------------------------------------------------------------------------
// Deformable sampling reading the padded omb [MTOT][256] rows
// (cols 0..143 offsets, 144..215 mask logits). Output s PRE-SPLIT bf16 hi/lo.
// ---------------------------------------------------------------------------
__global__ __launch_bounds__(256)
void sample_kernel_omb_split(const float* __restrict__ v,
                             const float* __restrict__ omb,
                             unsigned short* __restrict__ sh,  // [MTOT][256]
                             unsigned short* __restrict__ sl)  // [MTOT][256]
{
    __shared__ alignas(16) float loff[POSB][NOFF];
    __shared__ alignas(16) float lmsk[POSB][NMSK];
    __shared__ alignas(16) float wtab[POSB][GRP*NP][4];
    __shared__ alignas(16) int   itab[POSB][GRP*NP][4];

    const int nblk = MTOT / POSB;            // 6272
    const int per  = nblk / 8;               // 784
    const int bid  = blockIdx.x;
    const int sw   = (bid % 8) * per + (bid / 8);
    const int n0 = sw * POSB;
    const int t = threadIdx.x;

    if (t < POSB * (NOFF/4)) {
        const int q = t / (NOFF/4), r = t % (NOFF/4);
        *(float4*)&loff[q][r*4] = *(const float4*)&omb[(size_t)(n0+q)*CH + r*4];
    } else if (t < POSB * (NOFF/4) + POSB * (NMSK/4)) {
        const int u = t - POSB * (NOFF/4);
        const int q = u / (NMSK/4), r = u % (NMSK/4);
        *(float4*)&lmsk[q][r*4] = *(const float4*)&omb[(size_t)(n0+q)*CH + NOFF + r*4];
    }
    __syncthreads();

    if (t < POSB * GRP) {
        const int q = t >> 3, g = t & 7;
        float* mm = &lmsk[q][g * NP];
        float mx = -1e30f;
        #pragma unroll
        for (int p = 0; p < NP; ++p) mx = fmaxf(mx, mm[p]);
        float sum = 0.0f;
        #pragma unroll
        for (int p = 0; p < NP; ++p) { const float e = __expf(mm[p] - mx); mm[p] = e; sum += e; }
        const float inv = 1.0f / sum;
        #pragma unroll
        for (int p = 0; p < NP; ++p) mm[p] *= inv;
    }
    __syncthreads();

    for (int u = t; u < POSB * GRP * NP; u += 256) {
        const int q = u / (GRP*NP), j = u % (GRP*NP);
        const int g = j / NP, p = j % NP;
        const int n = n0 + q;
        const int hw = n % HW;
        const int h = hw / WDIM, w = hw % WDIM;
        const float ox = loff[q][g*18 + p*2 + 0];
        const float oy = loff[q][g*18 + p*2 + 1];
        const float m  = lmsk[q][g*NP + p];
        const float px = (float)(w + p/3) + ox;
        const float py = (float)(h + p%3) + oy;
        const float fx = floorf(px), fy = floorf(py);
        const float wx = px - fx, wy = py - fy;
        const int x0 = (int)fx, y0 = (int)fy;
        const int x1 = x0 + 1, y1 = y0 + 1;
        const float vx0 = (x0 >= 1 && x0 < 57) ? 1.0f : 0.0f;
        const float vx1 = (x1 >= 1 && x1 < 57) ? 1.0f : 0.0f;
        const float vy0 = (y0 >= 1 && y0 < 57) ? 1.0f : 0.0f;
        const float vy1 = (y1 >= 1 && y1 < 57) ? 1.0f : 0.0f;
        const int x0c = min(max(x0, 1), 56), x1c = min(max(x1, 1), 56);
        const int y0c = min(max(y0, 1), 56), y1c = min(max(y1, 1), 56);
        wtab[q][j][0] = m * (1.0f-wx) * (1.0f-wy) * vx0 * vy0;
        wtab[q][j][1] = m * wx        * (1.0f-wy) * vx1 * vy0;
        wtab[q][j][2] = m * (1.0f-wx) * wy        * vx0 * vy1;
        wtab[q][j][3] = m * wx        * wy        * vx1 * vy1;
        itab[q][j][0] = ((y0c-1)*WDIM + (x0c-1)) * CH;
        itab[q][j][1] = ((y0c-1)*WDIM + (x1c-1)) * CH;
        itab[q][j][2] = ((y1c-1)*WDIM + (x0c-1)) * CH;
        itab[q][j][3] = ((y1c-1)*WDIM + (x1c-1)) * CH;
    }
    __syncthreads();

    const int q = t >> 6, lane = t & 63;
    const int n = n0 + q;
    const int b = n / HW;
    const int g = lane >> 3;
    const float* vb = v + (size_t)b*HW*CH + lane*4;
    float4 acc = {0.0f, 0.0f, 0.0f, 0.0f};
    #pragma unroll
    for (int p = 0; p < NP; ++p) {
        const int j = g*NP + p;
        const float4 wv = *(const float4*)&wtab[q][j][0];
        const int4  iv = *(const int4*)&itab[q][j][0];
        const float4 c0 = *(const float4*)(vb + iv.x);
        const float4 c1 = *(const float4*)(vb + iv.y);
        const float4 c2 = *(const float4*)(vb + iv.z);
        const float4 c3 = *(const float4*)(vb + iv.w);
        acc.x += wv.x*c0.x + wv.y*c1.x + wv.z*c2.x + wv.w*c3.x;
        acc.y += wv.x*c0.y + wv.y*c1.y + wv.z*c2.y + wv.w*c3.y;
        acc.z += wv.x*c0.z + wv.y*c1.z + wv.z*c2.z + wv.w*c3.z;
        acc.w += wv.x*c0.w + wv.y*c1.w + wv.z*c2.w + wv.w*c3.w;
    }
    unsigned int hp0, lp0, hp1, lp1;
    split2(acc.x, acc.y, hp0, lp0);
    split2(acc.z, acc.w, hp1, lp1);
    *(uint2*)&sh[(size_t)n*CH + lane*4] = make_uint2(hp0, hp1);
    *(uint2*)&sl[(size_t)n*CH + lane*4] = make_uint2(lp0, lp1);
}

// ---------------------------------------------------------------------------
// Fallback GEMM out from PRE-SPLIT bf16 A (round-5 structure, grid (98,4)).
// ---------------------------------------------------------------------------
__global__ __launch_bounds__(256)
void gemm_out_bf16(const unsigned short* __restrict__ shp, // [m][k] bf16 hi
                   const unsigned short* __restrict__ slp, // [m][k] bf16 lo
                   const unsigned short* __restrict__ whi, // [256 n][256 k]
                   const unsigned short* __restrict__ wlo,
                   const float* __restrict__ bias,
                   const float* __restrict__ bn_g,
                   const float* __restrict__ bn_b,
                   const float* __restrict__ bn_mean,
                   const float* __restrict__ bn_var,
                   float* __restrict__ y)                  // [B,256,3136]
{
    const int m0 = blockIdx.x * 256;
    const int n0 = blockIdx.y * 64;
    const int t = threadIdx.x;
    const int lane = t & 63, wv = t >> 6;
    const int mblk = m0 + wv * 64;
    const int fm = lane & 15;
    const int q  = lane >> 4;

    f32x4 acc[4][4];
    const f32x4 zero = {0.0f, 0.0f, 0.0f, 0.0f};
    #pragma unroll
    for (int i = 0; i < 4; ++i)
        #pragma unroll
        for (int j = 0; j < 4; ++j) acc[i][j] = zero;

    const unsigned short *xrh[4], *xrl[4], *wrh[4], *wrl[4];
    #pragma unroll
    for (int mt = 0; mt < 4; ++mt) {
        xrh[mt] = shp + (size_t)(mblk + mt*16 + fm) * CH + q * 8;
        xrl[mt] = slp + (size_t)(mblk + mt*16 + fm) * CH + q * 8;
    }
    #pragma unroll
    for (int nt = 0; nt < 4; ++nt) {
        wrh[nt] = whi + (size_t)(n0 + nt*16 + fm) * CH + q * 8;
        wrl[nt] = wlo + (size_t)(n0 + nt*16 + fm) * CH + q * 8;
    }

    for (int k0 = 0; k0 < CH; k0 += 32) {
        s16x8 wh[4], wl[4], ah[4], al[4];
        #pragma unroll
        for (int nt = 0; nt < 4; ++nt) {
            wh[nt] = *(const s16x8*)(wrh[nt] + k0);
            wl[nt] = *(const s16x8*)(wrl[nt] + k0);
        }
        #pragma unroll
        for (int mt = 0; mt < 4; ++mt) {
            ah[mt] = *(const s16x8*)(xrh[mt] + k0);
            al[mt] = *(const s16x8*)(xrl[mt] + k0);
        }
        #pragma unroll
        for (int nt = 0; nt < 4; ++nt)
            #pragma unroll
            for (int mt = 0; mt < 4; ++mt) {
                acc[nt][mt] = __builtin_amdgcn_mfma_f32_16x16x32_bf16(wh[nt], ah[mt], acc[nt][mt], 0, 0, 0);
                acc[nt][mt] = __builtin_amdgcn_mfma_f32_16x16x32_bf16(wh[nt], al[mt], acc[nt][mt], 0, 0, 0);
                acc[nt][mt] = __builtin_amdgcn_mfma_f32_16x16x32_bf16(wl[nt], ah[mt], acc[nt][mt], 0, 0, 0);
            }
    }

    #pragma unroll
    for (int nt = 0; nt < 4; ++nt) {
        #pragma unroll
        for (int r = 0; r < 4; ++r) {
            const int n = n0 + nt*16 + q*4 + r;
            const float sc = bn_g[n] * rsqrtf(bn_var[n] + 1e-5f);
            const float sb = bn_b[n] - bn_mean[n] * sc;
            const float bs = bias[n];
            #pragma unroll
            for (int mt = 0; mt < 4; ++mt) {
                const int mm = mblk + mt*16;
                const size_t base = (size_t)(mm / HW) * CH * HW + (mm % HW);
                float val = (acc[nt][mt][r] + bs) * sc + sb;
                y[base + (size_t)n * HW + fm] = val / (1.0f + expf(-val));
            }
        }
    }
}

extern "C" void kernel_launch(void* const* d_in, const int* in_sizes, int n_in,
                              void* d_out, int out_size, void* d_ws, size_t ws_size,
                              hipStream_t stream) {
    const float* x      = (const float*)d_in[0];
    const float* w_in   = (const float*)d_in[1];
    const float* b_in   = (const float*)d_in[2];
    const float* dw_w   = (const float*)d_in[3];
    const float* dw_b   = (const float*)d_in[4];
    const float* ln_g   = (const float*)d_in[5];
    const float* ln_b   = (const float*)d_in[6];
    const float* w_off  = (const float*)d_in[7];
    const float* b_off  = (const float*)d_in[8];
    const float* w_mask = (const float*)d_in[9];
    const float* b_mask = (const float*)d_in[10];
    const float* w_out  = (const float*)d_in[11];
    const float* b_out  = (const float*)d_in[12];
    const float* bn_g   = (const float*)d_in[13];
    const float* bn_b   = (const float*)d_in[14];
    const float* bn_mean= (const float*)d_in[15];
    const float* bn_var = (const float*)d_in[16];
    float* out = (float*)d_out;

    const size_t SZ = (size_t)MTOT * CH;                 // elements
    // Layout: v | xt_hi,xt_lo | fh,fl | omb | weights | bcat
    const size_t need_new =
        4 * SZ * sizeof(float)
        + 6 * (size_t)CH * CH * sizeof(unsigned short)
        + CH * sizeof(float);

    if (ws_size >= need_new) {
        // -------- main path --------
        float* ws = (float*)d_ws;
        float* v    = ws;                                          // SZ f32
        unsigned short* xt_hi = (unsigned short*)(v + SZ);         // SZ us
        unsigned short* xt_lo = xt_hi + SZ;                        // SZ us
        unsigned short* fh    = xt_lo + SZ;                        // SZ us
        unsigned short* fl    = fh + SZ;                           // SZ us
        float* omb  = (float*)(fl + SZ);                           // SZ f32
        unsigned short* wt_hi  = (unsigned short*)(omb + SZ);
        unsigned short* wt_lo  = wt_hi + CH * CH;
        unsigned short* wt2_hi = wt_lo + CH * CH;
        unsigned short* wt2_lo = wt2_hi + CH * CH;
        unsigned short* wt3_hi = wt2_lo + CH * CH;
        unsigned short* wt3_lo = wt3_hi + CH * CH;
        float* bcat = (float*)(wt3_lo + CH * CH);                  // 256 f32
        // sh/sl overlay xt region (xt consumed by dual GEMM + dw beforehand).
        unsigned short* sh = xt_hi;
        unsigned short* sl = xt_lo;

        wt_split_kernel<<<dim3(4, 4), dim3(256), 0, stream>>>(w_out, wt_hi, wt_lo);
        wt_split_kernel<<<dim3(4, 4), dim3(256), 0, stream>>>(w_in, wt3_hi, wt3_lo);
        wt2_split_kernel<<<dim3(16), dim3(256), 0, stream>>>(
            w_off, w_mask, b_off, b_mask, wt2_hi, wt2_lo, bcat);
        xt_split_kernel<<<dim3(HW/64, CH/64, BATCH), dim3(256), 0, stream>>>(x, xt_hi, xt_lo);
        dw_ln_gelu_nhwc_split<<<dim3(MTOT/POSB), dim3(256), 0, stream>>>(
            xt_hi, xt_lo, dw_w, dw_b, ln_g, ln_b, fh, fl);
        // Both middle projections in ONE dispatch, LDS-staged 128x128 tiles:
        gemm128_dual<<<dim3(2 * NBLK128), dim3(256), 0, stream>>>(
            xt_hi, xt_lo, wt3_hi, wt3_lo, b_in, v,
            fh, fl, wt2_hi, wt2_lo, bcat, omb);
        sample_kernel_omb_split<<<dim3(MTOT/POSB), dim3(256), 0, stream>>>(v, omb, sh, sl);
        gemm_out_128x64<<<dim3(NBLKOUT), dim3(128), 0, stream>>>(
            sh, sl, wt_hi, wt_lo, b_out, bn_g, bn_b, bn_mean, bn_var, out);
    } else {
        // -------- fallback: round-5 verified path --------
        float* ws = (float*)d_ws;
        float* v    = ws;
        unsigned short* xt_hi = (unsigned short*)(v + SZ);
        unsigned short* xt_lo = xt_hi + SZ;
        unsigned short* fh    = xt_lo + SZ;
        unsigned short* fl    = fh + SZ;
        float* omb  = (float*)(fl + SZ);
        unsigned short* wt_hi  = (unsigned short*)(omb + SZ);
        unsigned short* wt_lo  = wt_hi + CH * CH;
        unsigned short* wt2_hi = wt_lo + CH * CH;
        unsigned short* wt2_lo = wt2_hi + CH * CH;
        unsigned short* wt3_hi = wt2_lo + CH * CH;
        unsigned short* wt3_lo = wt3_hi + CH * CH;
        float* bcat = (float*)(wt3_lo + CH * CH);
        unsigned short* sh = xt_hi;
        unsigned short* sl = xt_lo;

        wt_split_kernel<<<dim3(4, 4), dim3(256), 0, stream>>>(w_out, wt_hi, wt_lo);
        wt_split_kernel<<<dim3(4, 4), dim3(256), 0, stream>>>(w_in, wt3_hi, wt3_lo);
        wt2_split_kernel<<<dim3(16), dim3(256), 0, stream>>>(
            w_off, w_mask, b_off, b_mask, wt2_hi, wt2_lo, bcat);
        xt_split_kernel<<<dim3(HW/64, CH/64, BATCH), dim3(256), 0, stream>>>(x, xt_hi, xt_lo);
        gemm_in_mfma<<<dim3(MTOT/256, CH/64), dim3(256), 0, stream>>>(
            xt_hi, xt_lo, wt3_hi, wt3_lo, b_in, v);
        dw_ln_gelu_nhwc_split<<<dim3(MTOT/POSB), dim3(256), 0, stream>>>(
            xt_hi, xt_lo, dw_w, dw_b, ln_g, ln_b, fh, fl);
        gemm_in_mfma<<<dim3(MTOT/256, CH/64), dim3(256), 0, stream>>>(
            fh, fl, wt2_hi, wt2_lo, bcat, omb);
        sample_kernel_omb_split<<<dim3(MTOT/POSB), dim3(256), 0, stream>>>(v, omb, sh, sl);
        gemm_out_bf16<<<dim3(MTOT/256, CH/64), dim3(256), 0, stream>>>(
            sh, sl, wt_hi, wt_lo, b_out, bn_g, bn_b, bn_mean, bn_var, out);
    }
}

// Round 10
// 232.448 us; speedup vs baseline: 1.0071x; 1.0071x over previous
//
#include <hip/hip_runtime.h>
#include <math.h>

// Problem constants
#define BATCH 8
#define CH    256
#define HDIM  56
#define WDIM  56
#define HW    (HDIM*WDIM)          // 3136
#define MTOT  (BATCH*HW)           // 25088
#define GRP   8
#define GC    32
#define NP    9                    // K*K
#define NOFF  (GRP*NP*2)           // 144
#define NMSK  (GRP*NP)             // 72
#define NTOT  (NOFF+NMSK)          // 216
#define POSB  4                    // positions per sample block
#define NBLK128 ((MTOT/128)*2)     // 392: 196 m-tiles x 2 n-tiles
#define NBLKOUT ((MTOT/64)*2)      // 784: 392 m-tiles(64) x 2 n-tiles(128)

typedef float f32x4 __attribute__((ext_vector_type(4)));
typedef short s16x8 __attribute__((ext_vector_type(8)));

// split a,b into packed bf16 hi (truncation) and bf16 lo (exact remainder, truncated)
__device__ inline void split2(float a, float b, unsigned int& hp, unsigned int& lp)
{
    const unsigned int ua = __float_as_uint(a), ub = __float_as_uint(b);
    hp = (ub & 0xffff0000u) | (ua >> 16);
    const float ha = __uint_as_float(ua & 0xffff0000u);
    const float hb = __uint_as_float(ub & 0xffff0000u);
    const unsigned int la = __float_as_uint(a - ha), lb = __float_as_uint(b - hb);
    lp = (lb & 0xffff0000u) | (la >> 16);
}

// async global(16B/lane) -> LDS (wave-uniform base + lane*16)
__device__ __forceinline__ void gld_lds16(const unsigned short* g, unsigned short* l)
{
    __builtin_amdgcn_global_load_lds(
        (const __attribute__((address_space(1))) unsigned int*)g,
        (__attribute__((address_space(3))) unsigned int*)l, 16, 0, 0);
}

// ---------------------------------------------------------------------------
// Transpose + split x (NCHW) -> xt_hi/xt_lo [m][k] bf16. 64x64 LDS tiles.
// ---------------------------------------------------------------------------
__global__ __launch_bounds__(256)
void xt_split_kernel(const float* __restrict__ x,
                     unsigned short* __restrict__ hi,
                     unsigned short* __restrict__ lo)
{
    __shared__ float lds[64][68];
    const int hw0 = blockIdx.x * 64;       // 49 tiles (3136/64)
    const int k0  = blockIdx.y * 64;       // 4 tiles
    const int b   = blockIdx.z;            // 8
    const int t = threadIdx.x;
    #pragma unroll
    for (int p = 0; p < 4; ++p) {
        const int kr = (t >> 4) + p * 16;
        const int hc = (t & 15) * 4;
        *(float4*)&lds[kr][hc] =
            *(const float4*)(x + ((size_t)b * CH + k0 + kr) * HW + hw0 + hc);
    }
    __syncthreads();
    const int ml = t >> 2;             // m-row 0..63
    const int kc = (t & 3) * 16;       // k base 0,16,32,48
    unsigned int hbuf[8], lbuf[8];
    #pragma unroll
    for (int j = 0; j < 16; j += 2)
        split2(lds[kc + j][ml], lds[kc + j + 1][ml], hbuf[j >> 1], lbuf[j >> 1]);
    const size_t row = (size_t)(b * HW + hw0 + ml) * CH + k0 + kc;
    *(uint4*)&hi[row]     = *(uint4*)&hbuf[0];
    *(uint4*)&hi[row + 8] = *(uint4*)&hbuf[4];
    *(uint4*)&lo[row]     = *(uint4*)&lbuf[0];
    *(uint4*)&lo[row + 8] = *(uint4*)&lbuf[4];
}

// ---------------------------------------------------------------------------
// m97-style GEMM body: 128x128 tile, 4 waves (2m x 2n quadrants), BK=32,
// single-buffered LDS, 2-barrier k-loop, global_load_lds width-16 staging.
// Slot swizzle (slot ^= (row>>1)&3) applied on BOTH sides. (round-8 verified)
// ---------------------------------------------------------------------------
__device__ __forceinline__ void gemm128_body(
    const unsigned short* __restrict__ ahi,
    const unsigned short* __restrict__ alo,
    const unsigned short* __restrict__ whi,
    const unsigned short* __restrict__ wlo,
    unsigned short* sAh, unsigned short* sAl,
    unsigned short* sBh, unsigned short* sBl,
    int m0, int n0g, int t, f32x4 (&acc)[4][4])
{
    const int lane = t & 63, wv4 = t >> 6;
    const int wm = wv4 & 1, wn = wv4 >> 1;
    const int fm = lane & 15, q = lane >> 4;

    // staging decomposition (per issue i: 256 thr x 16B = 64 rows)
    int srow[2], sgs[2], slb[2];
    #pragma unroll
    for (int i = 0; i < 2; ++i) {
        const int u = i * 256 + t;
        srow[i] = u >> 2;
        const int ss = u & 3;
        sgs[i] = ss ^ ((srow[i] >> 1) & 3);      // pre-swizzled source slot
        slb[i] = i * 2048 + wv4 * 512;           // wave-uniform LDS base (shorts)
    }

    for (int kk = 0; kk < 8; ++kk) {
        const int k0 = kk * 32;
        #pragma unroll
        for (int i = 0; i < 2; ++i) {
            const size_t ga = (size_t)(m0 + srow[i]) * CH + k0 + sgs[i] * 8;
            const size_t gb = (size_t)(n0g + srow[i]) * CH + k0 + sgs[i] * 8;
            gld_lds16(ahi + ga, sAh + slb[i]);
            gld_lds16(alo + ga, sAl + slb[i]);
            gld_lds16(whi + gb, sBh + slb[i]);
            gld_lds16(wlo + gb, sBl + slb[i]);
        }
        __syncthreads();                          // vmcnt(0) drain + barrier

        s16x8 ah[4], al[4], wh[4], wl[4];
        #pragma unroll
        for (int i = 0; i < 4; ++i) {
            const int ar = wm * 64 + i * 16 + fm;
            const int as = (q ^ ((ar >> 1) & 3)) * 8;
            ah[i] = *(const s16x8*)&sAh[ar * 32 + as];
            al[i] = *(const s16x8*)&sAl[ar * 32 + as];
            const int br = wn * 64 + i * 16 + fm;
            const int bs = (q ^ ((br >> 1) & 3)) * 8;
            wh[i] = *(const s16x8*)&sBh[br * 32 + bs];
            wl[i] = *(const s16x8*)&sBl[br * 32 + bs];
        }
        #pragma unroll
        for (int nt = 0; nt < 4; ++nt)
            #pragma unroll
            for (int mt = 0; mt < 4; ++mt) {
                acc[nt][mt] = __builtin_amdgcn_mfma_f32_16x16x32_bf16(wh[nt], ah[mt], acc[nt][mt], 0, 0, 0);
                acc[nt][mt] = __builtin_amdgcn_mfma_f32_16x16x32_bf16(wh[nt], al[mt], acc[nt][mt], 0, 0, 0);
                acc[nt][mt] = __builtin_amdgcn_mfma_f32_16x16x32_bf16(wl[nt], ah[mt], acc[nt][mt], 0, 0, 0);
            }
        __syncthreads();                          // before next-stage overwrite
    }
}

// ---------------------------------------------------------------------------
// DUAL GEMM (both middle projections), 128x128 tiles, LDS-staged.
// bid<NBLK128: v = xt @ w_in; else: omb = f @ wt2. ~HBM roofline (round 8).
// 784 blocks x 4 waves = 12.25 waves/CU: the proven concurrency regime.
// ---------------------------------------------------------------------------
__global__ __launch_bounds__(256)
void gemm128_dual(const unsigned short* __restrict__ ahi1,
                  const unsigned short* __restrict__ alo1,
                  const unsigned short* __restrict__ whi1,
                  const unsigned short* __restrict__ wlo1,
                  const float* __restrict__ bias1,
                  float* __restrict__ out1,
                  const unsigned short* __restrict__ ahi2,
                  const unsigned short* __restrict__ alo2,
                  const unsigned short* __restrict__ whi2,
                  const unsigned short* __restrict__ wlo2,
                  const float* __restrict__ bias2,
                  float* __restrict__ out2)
{
    __shared__ unsigned short sAh[128*32], sAl[128*32], sBh[128*32], sBl[128*32];

    const int half = blockIdx.x >= NBLK128;
    const int lbid = blockIdx.x - (half ? NBLK128 : 0);
    const unsigned short* ahi = half ? ahi2 : ahi1;
    const unsigned short* alo = half ? alo2 : alo1;
    const unsigned short* whi = half ? whi2 : whi1;
    const unsigned short* wlo = half ? wlo2 : wlo1;
    const float* bias = half ? bias2 : bias1;
    float* out = half ? out2 : out1;

    const int sw = (lbid & 7) * (NBLK128 / 8) + (lbid >> 3);   // bijective, 392=8*49
    const int m0 = (sw >> 1) * 128;
    const int n0g = (sw & 1) * 128;
    const int t = threadIdx.x;
    const int lane = t & 63, wv4 = t >> 6;
    const int wm = wv4 & 1, wn = wv4 >> 1;
    const int fm = lane & 15, q = lane >> 4;

    f32x4 acc[4][4];
    const f32x4 zero = {0.0f, 0.0f, 0.0f, 0.0f};
    #pragma unroll
    for (int i = 0; i < 4; ++i)
        #pragma unroll
        for (int j = 0; j < 4; ++j) acc[i][j] = zero;

    gemm128_body(ahi, alo, whi, wlo, sAh, sAl, sBh, sBl, m0, n0g, t, acc);

    #pragma unroll
    for (int nt = 0; nt < 4; ++nt) {
        const int n = n0g + wn*64 + nt*16 + q*4;
        const float4 b4 = *(const float4*)&bias[n];
        #pragma unroll
        for (int mt = 0; mt < 4; ++mt) {
            const int mm = m0 + wm*64 + mt*16 + fm;
            f32x4 o = acc[nt][mt];
            o[0] += b4.x; o[1] += b4.y; o[2] += b4.z; o[3] += b4.w;
            *(f32x4*)&out[(size_t)mm * CH + n] = o;
        }
    }
}

// ---------------------------------------------------------------------------
// Output GEMM, 64m x 128n tiles, 256 threads (4 waves = 2m-halves x
// 2n-halves; per-wave 32m x 64n, acc[4][2]). Grid 784 x 4 waves =
// 12.25 waves/CU -- EXACTLY the dual kernel's proven concurrency regime
// (round-9 lesson: the lever is waves/CU, not blocks/CU; 6.1 waves/CU
// left this GEMM 3x off roofline in both round-8 and round-9 shapes).
// Same staging idiom + k-order + 3-MFMA chain -> bit-identical math.
// ---------------------------------------------------------------------------
__global__ __launch_bounds__(256)
void gemm_out_64x128(const unsigned short* __restrict__ ahi,
                     const unsigned short* __restrict__ alo,
                     const unsigned short* __restrict__ whi,
                     const unsigned short* __restrict__ wlo,
                     const float* __restrict__ bias,
                     const float* __restrict__ bn_g,
                     const float* __restrict__ bn_b,
                     const float* __restrict__ bn_mean,
                     const float* __restrict__ bn_var,
                     float* __restrict__ y)                  // [B,256,3136]
{
    __shared__ unsigned short sAh[64*32], sAl[64*32], sBh[128*32], sBl[128*32];

    const int sw = (blockIdx.x & 7) * (NBLKOUT / 8) + (blockIdx.x >> 3); // 784=8*98
    const int m0  = (sw >> 1) * 64;            // 392 m-tiles of 64
    const int n0g = (sw & 1) * 128;            // 2 n-tiles of 128
    const int t = threadIdx.x;
    const int lane = t & 63, wv4 = t >> 6;
    const int wm = wv4 >> 1, wn = wv4 & 1;     // 2m-halves(32) x 2n-halves(64)
    const int fm = lane & 15, q = lane >> 4;

    f32x4 acc[4][2];                           // [nt 0..3][mt 0..1]
    const f32x4 zero = {0.0f, 0.0f, 0.0f, 0.0f};
    #pragma unroll
    for (int i = 0; i < 4; ++i)
        #pragma unroll
        for (int j = 0; j < 2; ++j) acc[i][j] = zero;

    // staging: A = 1 issue (256 thr x 16B = 64 rows x 64B), B = 2 issues.
    // Linear LDS dest (u*16B), pre-swizzled global source slot, XOR on read.
    const int arow0 = t >> 2;
    const int asl0  = (t & 3) ^ ((arow0 >> 1) & 3);
    const int albase0 = wv4 * 512;             // shorts; wave-uniform
    int brow[2], bsl[2], blbase[2];
    #pragma unroll
    for (int i = 0; i < 2; ++i) {
        const int u = i * 256 + t;
        brow[i] = u >> 2;
        bsl[i] = (u & 3) ^ ((brow[i] >> 1) & 3);
        blbase[i] = i * 2048 + wv4 * 512;
    }

    for (int kk = 0; kk < 8; ++kk) {
        const int k0 = kk * 32;
        {
            const size_t ga = (size_t)(m0 + arow0) * CH + k0 + asl0 * 8;
            gld_lds16(ahi + ga, sAh + albase0);
            gld_lds16(alo + ga, sAl + albase0);
        }
        #pragma unroll
        for (int i = 0; i < 2; ++i) {
            const size_t gb = (size_t)(n0g + brow[i]) * CH + k0 + bsl[i] * 8;
            gld_lds16(whi + gb, sBh + blbase[i]);
            gld_lds16(wlo + gb, sBl + blbase[i]);
        }
        __syncthreads();

        s16x8 ah[2], al[2], wh[4], wl[4];
        #pragma unroll
        for (int i = 0; i < 2; ++i) {
            const int ar = wm * 32 + i * 16 + fm;
            const int as = (q ^ ((ar >> 1) & 3)) * 8;
            ah[i] = *(const s16x8*)&sAh[ar * 32 + as];
            al[i] = *(const s16x8*)&sAl[ar * 32 + as];
        }
        #pragma unroll
        for (int i = 0; i < 4; ++i) {
            const int br = wn * 64 + i * 16 + fm;
            const int bs = (q ^ ((br >> 1) & 3)) * 8;
            wh[i] = *(const s16x8*)&sBh[br * 32 + bs];
            wl[i] = *(const s16x8*)&sBl[br * 32 + bs];
        }
        #pragma unroll
        for (int nt = 0; nt < 4; ++nt)
            #pragma unroll
            for (int mt = 0; mt < 2; ++mt) {
                acc[nt][mt] = __builtin_amdgcn_mfma_f32_16x16x32_bf16(wh[nt], ah[mt], acc[nt][mt], 0, 0, 0);
                acc[nt][mt] = __builtin_amdgcn_mfma_f32_16x16x32_bf16(wh[nt], al[mt], acc[nt][mt], 0, 0, 0);
                acc[nt][mt] = __builtin_amdgcn_mfma_f32_16x16x32_bf16(wl[nt], ah[mt], acc[nt][mt], 0, 0, 0);
            }
        __syncthreads();
    }

    #pragma unroll
    for (int nt = 0; nt < 4; ++nt) {
        #pragma unroll
        for (int r = 0; r < 4; ++r) {
            const int n = n0g + wn*64 + nt*16 + q*4 + r;
            const float sc = bn_g[n] * rsqrtf(bn_var[n] + 1e-5f);
            const float sb = bn_b[n] - bn_mean[n] * sc;
            const float bs = bias[n];
            #pragma unroll
            for (int mt = 0; mt < 2; ++mt) {
                const int mm = m0 + wm*32 + mt*16 + fm;
                const int bimg = mm / HW, hw = mm % HW;
                float val = (acc[nt][mt][r] + bs) * sc + sb;
                y[(size_t)bimg * CH * HW + (size_t)n * HW + hw] = val / (1.0f + expf(-val));
            }
        }
    }
}

// ---------------------------------------------------------------------------
// Fallback GEMM (proven round-4 structure): 256m x 64n blocks, grid (98,4).
// ---------------------------------------------------------------------------
__global__ __launch_bounds__(256)
void gemm_in_mfma(const unsigned short* __restrict__ xhi, // [m][k]
                  const unsigned short* __restrict__ xlo,
                  const unsigned short* __restrict__ whi, // [n][k]
                  const unsigned short* __restrict__ wlo,
                  const float* __restrict__ bias,
                  float* __restrict__ v)                  // [MTOT,256]
{
    const int m0 = blockIdx.x * 256;
    const int n0 = blockIdx.y * 64;
    const int t = threadIdx.x;
    const int lane = t & 63, wv = t >> 6;
    const int mblk = m0 + wv * 64;
    const int fm = lane & 15;
    const int q  = lane >> 4;

    f32x4 acc[4][4];              // [nt][mt]
    const f32x4 zero = {0.0f, 0.0f, 0.0f, 0.0f};
    #pragma unroll
    for (int i = 0; i < 4; ++i)
        #pragma unroll
        for (int j = 0; j < 4; ++j) acc[i][j] = zero;

    const unsigned short *xrh[4], *xrl[4], *wrh[4], *wrl[4];
    #pragma unroll
    for (int mt = 0; mt < 4; ++mt) {
        xrh[mt] = xhi + (size_t)(mblk + mt*16 + fm) * CH + q * 8;
        xrl[mt] = xlo + (size_t)(mblk + mt*16 + fm) * CH + q * 8;
    }
    #pragma unroll
    for (int nt = 0; nt < 4; ++nt) {
        wrh[nt] = whi + (size_t)(n0 + nt*16 + fm) * CH + q * 8;
        wrl[nt] = wlo + (size_t)(n0 + nt*16 + fm) * CH + q * 8;
    }

    for (int k0 = 0; k0 < CH; k0 += 32) {
        s16x8 wh[4], wl[4], ah[4], al[4];
        #pragma unroll
        for (int nt = 0; nt < 4; ++nt) {
            wh[nt] = *(const s16x8*)(wrh[nt] + k0);
            wl[nt] = *(const s16x8*)(wrl[nt] + k0);
        }
        #pragma unroll
        for (int mt = 0; mt < 4; ++mt) {
            ah[mt] = *(const s16x8*)(xrh[mt] + k0);
            al[mt] = *(const s16x8*)(xrl[mt] + k0);
        }
        #pragma unroll
        for (int nt = 0; nt < 4; ++nt)
            #pragma unroll
            for (int mt = 0; mt < 4; ++mt) {
                acc[nt][mt] = __builtin_amdgcn_mfma_f32_16x16x32_bf16(wh[nt], ah[mt], acc[nt][mt], 0, 0, 0);
                acc[nt][mt] = __builtin_amdgcn_mfma_f32_16x16x32_bf16(wh[nt], al[mt], acc[nt][mt], 0, 0, 0);
                acc[nt][mt] = __builtin_amdgcn_mfma_f32_16x16x32_bf16(wl[nt], ah[mt], acc[nt][mt], 0, 0, 0);
            }
    }

    #pragma unroll
    for (int nt = 0; nt < 4; ++nt) {
        const float4 b4 = *(const float4*)&bias[n0 + nt*16 + q*4];
        #pragma unroll
        for (int mt = 0; mt < 4; ++mt) {
            f32x4 o = acc[nt][mt];
            o[0] += b4.x; o[1] += b4.y; o[2] += b4.z; o[3] += b4.w;
            *(f32x4*)&v[(size_t)(mblk + mt*16 + fm) * CH + n0 + nt*16 + q*4] = o;
        }
    }
}

// ---------------------------------------------------------------------------
// Per-position-wave depthwise 3x3 + bias + LN + GELU from NHWC bf16 hi/lo xt,
// output stored PRE-SPLIT as bf16 hi/lo. One wave per position.
// ---------------------------------------------------------------------------
__global__ __launch_bounds__(256)
void dw_ln_gelu_nhwc_split(const unsigned short* __restrict__ xhi,
                           const unsigned short* __restrict__ xlo,
                           const float* __restrict__ dw_w,   // [256][9]
                           const float* __restrict__ dw_b,
                           const float* __restrict__ ln_g,
                           const float* __restrict__ ln_b,
                           unsigned short* __restrict__ fh,  // [MTOT][256]
                           unsigned short* __restrict__ fl)  // [MTOT][256]
{
    __shared__ float wt[NP][CH];                       // transposed dw weights
    __shared__ float lbias[CH], lgam[CH], lbet[CH];

    const int t = threadIdx.x;
    {
        const float* wp = dw_w + t * NP;
        #pragma unroll
        for (int p = 0; p < NP; ++p) wt[p][t] = wp[p];
        lbias[t] = dw_b[t]; lgam[t] = ln_g[t]; lbet[t] = ln_b[t];
    }
    __syncthreads();

    const int nblk = MTOT / POSB;          // 6272
    const int per  = nblk / 8;             // 784
    const int bid  = blockIdx.x;
    const int sw   = (bid & 7) * per + (bid >> 3);
    const int q    = t >> 6, lane = t & 63;
    const int n    = sw * POSB + q;
    const int b    = n / HW;
    const int hw   = n % HW;
    const int h    = hw / WDIM, w = hw % WDIM;
    const int c4   = lane * 4;
    const size_t base = (size_t)b * HW * CH + c4;

    float ax = 0.0f, ay = 0.0f, az = 0.0f, aw = 0.0f;
    #pragma unroll
    for (int p = 0; p < NP; ++p) {
        const int hh = h + p / 3 - 1;
        const int ww = w + p % 3 - 1;
        if ((unsigned)hh >= (unsigned)HDIM || (unsigned)ww >= (unsigned)WDIM)
            continue;                       // wave-uniform branch (h,w per-wave)
        const size_t idx = base + (size_t)(hh * WDIM + ww) * CH;
        const ushort4 uh = *(const ushort4*)(xhi + idx);
        const ushort4 ul = *(const ushort4*)(xlo + idx);
        const float4 wv = *(const float4*)&wt[p][c4];
        ax = fmaf(__uint_as_float((unsigned)uh.x << 16), wv.x,
             fmaf(__uint_as_float((unsigned)ul.x << 16), wv.x, ax));
        ay = fmaf(__uint_as_float((unsigned)uh.y << 16), wv.y,
             fmaf(__uint_as_float((unsigned)ul.y << 16), wv.y, ay));
        az = fmaf(__uint_as_float((unsigned)uh.z << 16), wv.z,
             fmaf(__uint_as_float((unsigned)ul.z << 16), wv.z, az));
        aw = fmaf(__uint_as_float((unsigned)uh.w << 16), wv.w,
             fmaf(__uint_as_float((unsigned)ul.w << 16), wv.w, aw));
    }
    {
        const float4 b4 = *(const float4*)&lbias[c4];
        ax += b4.x; ay += b4.y; az += b4.z; aw += b4.w;
    }

    // LayerNorm over the wave's 256 channel values: in-wave butterfly.
    float s1 = ax + ay + az + aw;
    float s2 = ax*ax + ay*ay + az*az + aw*aw;
    #pragma unroll
    for (int off = 32; off > 0; off >>= 1) {
        s1 += __shfl_xor(s1, off);
        s2 += __shfl_xor(s2, off);
    }
    const float mean = s1 * (1.0f / 256.0f);
    const float rstd = rsqrtf(s2 * (1.0f / 256.0f) - mean * mean + 1e-5f);

    const float4 g4 = *(const float4*)&lgam[c4];
    const float4 e4 = *(const float4*)&lbet[c4];
    const float x0 = (ax - mean) * rstd * g4.x + e4.x;
    const float x1 = (ay - mean) * rstd * g4.y + e4.y;
    const float x2 = (az - mean) * rstd * g4.z + e4.z;
    const float x3 = (aw - mean) * rstd * g4.w + e4.w;
    const float o0 = 0.5f * x0 * (1.0f + erff(x0 * 0.70710678118654752f));
    const float o1 = 0.5f * x1 * (1.0f + erff(x1 * 0.70710678118654752f));
    const float o2 = 0.5f * x2 * (1.0f + erff(x2 * 0.70710678118654752f));
    const float o3 = 0.5f * x3 * (1.0f + erff(x3 * 0.70710678118654752f));

    unsigned int hp0, lp0, hp1, lp1;
    split2(o0, o1, hp0, lp0);
    split2(o2, o3, hp1, lp1);
    *(uint2*)&fh[(size_t)n * CH + c4] = make_uint2(hp0, hp1);
    *(uint2*)&fl[(size_t)n * CH + c4] = make_uint2(lp0, lp1);
}

// ---------------------------------------------------------------------------
// Transpose + hi/lo bf16 split of a [256k][256n] fp32 weight -> [n][k] bf16.
// ---------------------------------------------------------------------------
__global__ __launch_bounds__(256)
void wt_split_kernel(const float* __restrict__ w,
                     unsigned short* __restrict__ hi,
                     unsigned short* __restrict__ lo)
{
    __shared__ float lds[64][68];
    const int kt = blockIdx.x * 64, nt = blockIdx.y * 64;
    const int t = threadIdx.x;
    #pragma unroll
    for (int p = 0; p < 4; ++p) {
        const int kr = (t >> 4) + p * 16, nc = (t & 15) * 4;
        *(float4*)&lds[kr][nc] = *(const float4*)(w + (size_t)(kt + kr) * CH + nt + nc);
    }
    __syncthreads();
    const int nl = t >> 2, kc = (t & 3) * 16;
    #pragma unroll
    for (int j = 0; j < 16; j += 2) {
        const float f0 = lds[kc + j][nl], f1 = lds[kc + j + 1][nl];
        unsigned int hp, lp;
        split2(f0, f1, hp, lp);
        *(unsigned int*)&hi[(size_t)(nt + nl) * CH + kt + kc + j] = hp;
        *(unsigned int*)&lo[(size_t)(nt + nl) * CH + kt + kc + j] = lp;
    }
}

// ---------------------------------------------------------------------------
// Transpose + split of [w_off | w_mask] -> wt2_hi/lo [256 n_pad][256 k] bf16.
// Also builds bcat[256] = [b_off | b_mask | 0] (block 0 only).
// ---------------------------------------------------------------------------
__global__ __launch_bounds__(256)
void wt2_split_kernel(const float* __restrict__ w_off,   // [256][144]
                      const float* __restrict__ w_mask,  // [256][72]
                      const float* __restrict__ b_off,
                      const float* __restrict__ b_mask,
                      unsigned short* __restrict__ hi,
                      unsigned short* __restrict__ lo,
                      float* __restrict__ bcat)          // [256]
{
    const int n = threadIdx.x;
    if (blockIdx.x == 0) {
        bcat[n] = (n < NOFF) ? b_off[n] : ((n < NTOT) ? b_mask[n - NOFF] : 0.0f);
    }
    const int k0 = blockIdx.x * 16;
    #pragma unroll
    for (int j = 0; j < 16; j += 2) {
        const int k = k0 + j;
        float f0 = 0.0f, f1 = 0.0f;
        if (n < NOFF) {
            f0 = w_off[(size_t)k * NOFF + n];
            f1 = w_off[(size_t)(k + 1) * NOFF + n];
        } else if (n < NTOT) {
            f0 = w_mask[(size_t)k * NMSK + (n - NOFF)];
            f1 = w_mask[(size_t)(k + 1) * NMSK + (n - NOFF)];
        }
        unsigned int hp, lp;
        split2(f0, f1, hp, lp);
        *(unsigned int*)&hi[(size_t)n * CH + k] = hp;
        *(unsigned int*)&lo[(size_t)n * CH + k] = lp;
    }
}

// ---------------------------------------------------------------------------
// Deformable sampling reading the padded omb [MTOT][256] rows
// (cols 0..143 offsets, 144..215 mask logits). Output s PRE-SPLIT bf16 hi/lo.
// ---------------------------------------------------------------------------
__global__ __launch_bounds__(256)
void sample_kernel_omb_split(const float* __restrict__ v,
                             const float* __restrict__ omb,
                             unsigned short* __restrict__ sh,  // [MTOT][256]
                             unsigned short* __restrict__ sl)  // [MTOT][256]
{
    __shared__ alignas(16) float loff[POSB][NOFF];
    __shared__ alignas(16) float lmsk[POSB][NMSK];
    __shared__ alignas(16) float wtab[POSB][GRP*NP][4];
    __shared__ alignas(16) int   itab[POSB][GRP*NP][4];

    const int nblk = MTOT / POSB;            // 6272
    const int per  = nblk / 8;               // 784
    const int bid  = blockIdx.x;
    const int sw   = (bid % 8) * per + (bid / 8);
    const int n0 = sw * POSB;
    const int t = threadIdx.x;

    if (t < POSB * (NOFF/4)) {
        const int q = t / (NOFF/4), r = t % (NOFF/4);
        *(float4*)&loff[q][r*4] = *(const float4*)&omb[(size_t)(n0+q)*CH + r*4];
    } else if (t < POSB * (NOFF/4) + POSB * (NMSK/4)) {
        const int u = t - POSB * (NOFF/4);
        const int q = u / (NMSK/4), r = u % (NMSK/4);
        *(float4*)&lmsk[q][r*4] = *(const float4*)&omb[(size_t)(n0+q)*CH + NOFF + r*4];
    }
    __syncthreads();

    if (t < POSB * GRP) {
        const int q = t >> 3, g = t & 7;
        float* mm = &lmsk[q][g * NP];
        float mx = -1e30f;
        #pragma unroll
        for (int p = 0; p < NP; ++p) mx = fmaxf(mx, mm[p]);
        float sum = 0.0f;
        #pragma unroll
        for (int p = 0; p < NP; ++p) { const float e = __expf(mm[p] - mx); mm[p] = e; sum += e; }
        const float inv = 1.0f / sum;
        #pragma unroll
        for (int p = 0; p < NP; ++p) mm[p] *= inv;
    }
    __syncthreads();

    for (int u = t; u < POSB * GRP * NP; u += 256) {
        const int q = u / (GRP*NP), j = u % (GRP*NP);
        const int g = j / NP, p = j % NP;
        const int n = n0 + q;
        const int hw = n % HW;
        const int h = hw / WDIM, w = hw % WDIM;
        const float ox = loff[q][g*18 + p*2 + 0];
        const float oy = loff[q][g*18 + p*2 + 1];
        const float m  = lmsk[q][g*NP + p];
        const float px = (float)(w + p/3) + ox;
        const float py = (float)(h + p%3) + oy;
        const float fx = floorf(px), fy = floorf(py);
        const float wx = px - fx, wy = py - fy;
        const int x0 = (int)fx, y0 = (int)fy;
        const int x1 = x0 + 1, y1 = y0 + 1;
        const float vx0 = (x0 >= 1 && x0 < 57) ? 1.0f : 0.0f;
        const float vx1 = (x1 >= 1 && x1 < 57) ? 1.0f : 0.0f;
        const float vy0 = (y0 >= 1 && y0 < 57) ? 1.0f : 0.0f;
        const float vy1 = (y1 >= 1 && y1 < 57) ? 1.0f : 0.0f;
        const int x0c = min(max(x0, 1), 56), x1c = min(max(x1, 1), 56);
        const int y0c = min(max(y0, 1), 56), y1c = min(max(y1, 1), 56);
        wtab[q][j][0] = m * (1.0f-wx) * (1.0f-wy) * vx0 * vy0;
        wtab[q][j][1] = m * wx        * (1.0f-wy) * vx1 * vy0;
        wtab[q][j][2] = m * (1.0f-wx) * wy        * vx0 * vy1;
        wtab[q][j][3] = m * wx        * wy        * vx1 * vy1;
        itab[q][j][0] = ((y0c-1)*WDIM + (x0c-1)) * CH;
        itab[q][j][1] = ((y0c-1)*WDIM + (x1c-1)) * CH;
        itab[q][j][2] = ((y1c-1)*WDIM + (x0c-1)) * CH;
        itab[q][j][3] = ((y1c-1)*WDIM + (x1c-1)) * CH;
    }
    __syncthreads();

    const int q = t >> 6, lane = t & 63;
    const int n = n0 + q;
    const int b = n / HW;
    const int g = lane >> 3;
    const float* vb = v + (size_t)b*HW*CH + lane*4;
    float4 acc = {0.0f, 0.0f, 0.0f, 0.0f};
    #pragma unroll
    for (int p = 0; p < NP; ++p) {
        const int j = g*NP + p;
        const float4 wv = *(const float4*)&wtab[q][j][0];
        const int4  iv = *(const int4*)&itab[q][j][0];
        const float4 c0 = *(const float4*)(vb + iv.x);
        const float4 c1 = *(const float4*)(vb + iv.y);
        const float4 c2 = *(const float4*)(vb + iv.z);
        const float4 c3 = *(const float4*)(vb + iv.w);
        acc.x += wv.x*c0.x + wv.y*c1.x + wv.z*c2.x + wv.w*c3.x;
        acc.y += wv.x*c0.y + wv.y*c1.y + wv.z*c2.y + wv.w*c3.y;
        acc.z += wv.x*c0.z + wv.y*c1.z + wv.z*c2.z + wv.w*c3.z;
        acc.w += wv.x*c0.w + wv.y*c1.w + wv.z*c2.w + wv.w*c3.w;
    }
    unsigned int hp0, lp0, hp1, lp1;
    split2(acc.x, acc.y, hp0, lp0);
    split2(acc.z, acc.w, hp1, lp1);
    *(uint2*)&sh[(size_t)n*CH + lane*4] = make_uint2(hp0, hp1);
    *(uint2*)&sl[(size_t)n*CH + lane*4] = make_uint2(lp0, lp1);
}

// ---------------------------------------------------------------------------
// Fallback GEMM out from PRE-SPLIT bf16 A (round-5 structure, grid (98,4)).
// ---------------------------------------------------------------------------
__global__ __launch_bounds__(256)
void gemm_out_bf16(const unsigned short* __restrict__ shp, // [m][k] bf16 hi
                   const unsigned short* __restrict__ slp, // [m][k] bf16 lo
                   const unsigned short* __restrict__ whi, // [256 n][256 k]
                   const unsigned short* __restrict__ wlo,
                   const float* __restrict__ bias,
                   const float* __restrict__ bn_g,
                   const float* __restrict__ bn_b,
                   const float* __restrict__ bn_mean,
                   const float* __restrict__ bn_var,
                   float* __restrict__ y)                  // [B,256,3136]
{
    const int m0 = blockIdx.x * 256;
    const int n0 = blockIdx.y * 64;
    const int t = threadIdx.x;
    const int lane = t & 63, wv = t >> 6;
    const int mblk = m0 + wv * 64;
    const int fm = lane & 15;
    const int q  = lane >> 4;

    f32x4 acc[4][4];
    const f32x4 zero = {0.0f, 0.0f, 0.0f, 0.0f};
    #pragma unroll
    for (int i = 0; i < 4; ++i)
        #pragma unroll
        for (int j = 0; j < 4; ++j) acc[i][j] = zero;

    const unsigned short *xrh[4], *xrl[4], *wrh[4], *wrl[4];
    #pragma unroll
    for (int mt = 0; mt < 4; ++mt) {
        xrh[mt] = shp + (size_t)(mblk + mt*16 + fm) * CH + q * 8;
        xrl[mt] = slp + (size_t)(mblk + mt*16 + fm) * CH + q * 8;
    }
    #pragma unroll
    for (int nt = 0; nt < 4; ++nt) {
        wrh[nt] = whi + (size_t)(n0 + nt*16 + fm) * CH + q * 8;
        wrl[nt] = wlo + (size_t)(n0 + nt*16 + fm) * CH + q * 8;
    }

    for (int k0 = 0; k0 < CH; k0 += 32) {
        s16x8 wh[4], wl[4], ah[4], al[4];
        #pragma unroll
        for (int nt = 0; nt < 4; ++nt) {
            wh[nt] = *(const s16x8*)(wrh[nt] + k0);
            wl[nt] = *(const s16x8*)(wrl[nt] + k0);
        }
        #pragma unroll
        for (int mt = 0; mt < 4; ++mt) {
            ah[mt] = *(const s16x8*)(xrh[mt] + k0);
            al[mt] = *(const s16x8*)(xrl[mt] + k0);
        }
        #pragma unroll
        for (int nt = 0; nt < 4; ++nt)
            #pragma unroll
            for (int mt = 0; mt < 4; ++mt) {
                acc[nt][mt] = __builtin_amdgcn_mfma_f32_16x16x32_bf16(wh[nt], ah[mt], acc[nt][mt], 0, 0, 0);
                acc[nt][mt] = __builtin_amdgcn_mfma_f32_16x16x32_bf16(wh[nt], al[mt], acc[nt][mt], 0, 0, 0);
                acc[nt][mt] = __builtin_amdgcn_mfma_f32_16x16x32_bf16(wl[nt], ah[mt], acc[nt][mt], 0, 0, 0);
            }
    }

    #pragma unroll
    for (int nt = 0; nt < 4; ++nt) {
        #pragma unroll
        for (int r = 0; r < 4; ++r) {
            const int n = n0 + nt*16 + q*4 + r;
            const float sc = bn_g[n] * rsqrtf(bn_var[n] + 1e-5f);
            const float sb = bn_b[n] - bn_mean[n] * sc;
            const float bs = bias[n];
            #pragma unroll
            for (int mt = 0; mt < 4; ++mt) {
                const int mm = mblk + mt*16;
                const size_t base = (size_t)(mm / HW) * CH * HW + (mm % HW);
                float val = (acc[nt][mt][r] + bs) * sc + sb;
                y[base + (size_t)n * HW + fm] = val / (1.0f + expf(-val));
            }
        }
    }
}

extern "C" void kernel_launch(void* const* d_in, const int* in_sizes, int n_in,
                              void* d_out, int out_size, void* d_ws, size_t ws_size,
                              hipStream_t stream) {
    const float* x      = (const float*)d_in[0];
    const float* w_in   = (const float*)d_in[1];
    const float* b_in   = (const float*)d_in[2];
    const float* dw_w   = (const float*)d_in[3];
    const float* dw_b   = (const float*)d_in[4];
    const float* ln_g   = (const float*)d_in[5];
    const float* ln_b   = (const float*)d_in[6];
    const float* w_off  = (const float*)d_in[7];
    const float* b_off  = (const float*)d_in[8];
    const float* w_mask = (const float*)d_in[9];
    const float* b_mask = (const float*)d_in[10];
    const float* w_out  = (const float*)d_in[11];
    const float* b_out  = (const float*)d_in[12];
    const float* bn_g   = (const float*)d_in[13];
    const float* bn_b   = (const float*)d_in[14];
    const float* bn_mean= (const float*)d_in[15];
    const float* bn_var = (const float*)d_in[16];
    float* out = (float*)d_out;

    const size_t SZ = (size_t)MTOT * CH;                 // elements
    // Layout: v | xt_hi,xt_lo | fh,fl | omb | weights | bcat
    const size_t need_new =
        4 * SZ * sizeof(float)
        + 6 * (size_t)CH * CH * sizeof(unsigned short)
        + CH * sizeof(float);

    if (ws_size >= need_new) {
        // -------- main path --------
        float* ws = (float*)d_ws;
        float* v    = ws;                                          // SZ f32
        unsigned short* xt_hi = (unsigned short*)(v + SZ);         // SZ us
        unsigned short* xt_lo = xt_hi + SZ;                        // SZ us
        unsigned short* fh    = xt_lo + SZ;                        // SZ us
        unsigned short* fl    = fh + SZ;                           // SZ us
        float* omb  = (float*)(fl + SZ);                           // SZ f32
        unsigned short* wt_hi  = (unsigned short*)(omb + SZ);
        unsigned short* wt_lo  = wt_hi + CH * CH;
        unsigned short* wt2_hi = wt_lo + CH * CH;
        unsigned short* wt2_lo = wt2_hi + CH * CH;
        unsigned short* wt3_hi = wt2_lo + CH * CH;
        unsigned short* wt3_lo = wt3_hi + CH * CH;
        float* bcat = (float*)(wt3_lo + CH * CH);                  // 256 f32
        // sh/sl overlay xt region (xt consumed by dual GEMM + dw beforehand).
        unsigned short* sh = xt_hi;
        unsigned short* sl = xt_lo;

        wt_split_kernel<<<dim3(4, 4), dim3(256), 0, stream>>>(w_out, wt_hi, wt_lo);
        wt_split_kernel<<<dim3(4, 4), dim3(256), 0, stream>>>(w_in, wt3_hi, wt3_lo);
        wt2_split_kernel<<<dim3(16), dim3(256), 0, stream>>>(
            w_off, w_mask, b_off, b_mask, wt2_hi, wt2_lo, bcat);
        xt_split_kernel<<<dim3(HW/64, CH/64, BATCH), dim3(256), 0, stream>>>(x, xt_hi, xt_lo);
        dw_ln_gelu_nhwc_split<<<dim3(MTOT/POSB), dim3(256), 0, stream>>>(
            xt_hi, xt_lo, dw_w, dw_b, ln_g, ln_b, fh, fl);
        // Both middle projections in ONE dispatch, LDS-staged 128x128 tiles:
        gemm128_dual<<<dim3(2 * NBLK128), dim3(256), 0, stream>>>(
            xt_hi, xt_lo, wt3_hi, wt3_lo, b_in, v,
            fh, fl, wt2_hi, wt2_lo, bcat, omb);
        sample_kernel_omb_split<<<dim3(MTOT/POSB), dim3(256), 0, stream>>>(v, omb, sh, sl);
        gemm_out_64x128<<<dim3(NBLKOUT), dim3(256), 0, stream>>>(
            sh, sl, wt_hi, wt_lo, b_out, bn_g, bn_b, bn_mean, bn_var, out);
    } else {
        // -------- fallback: round-5 verified path --------
        float* ws = (float*)d_ws;
        float* v    = ws;
        unsigned short* xt_hi = (unsigned short*)(v + SZ);
        unsigned short* xt_lo = xt_hi + SZ;
        unsigned short* fh    = xt_lo + SZ;
        unsigned short* fl    = fh + SZ;
        float* omb  = (float*)(fl + SZ);
        unsigned short* wt_hi  = (unsigned short*)(omb + SZ);
        unsigned short* wt_lo  = wt_hi + CH * CH;
        unsigned short* wt2_hi = wt_lo + CH * CH;
        unsigned short* wt2_lo = wt2_hi + CH * CH;
        unsigned short* wt3_hi = wt2_lo + CH * CH;
        unsigned short* wt3_lo = wt3_hi + CH * CH;
        float* bcat = (float*)(wt3_lo + CH * CH);
        unsigned short* sh = xt_hi;
        unsigned short* sl = xt_lo;

        wt_split_kernel<<<dim3(4, 4), dim3(256), 0, stream>>>(w_out, wt_hi, wt_lo);
        wt_split_kernel<<<dim3(4, 4), dim3(256), 0, stream>>>(w_in, wt3_hi, wt3_lo);
        wt2_split_kernel<<<dim3(16), dim3(256), 0, stream>>>(
            w_off, w_mask, b_off, b_mask, wt2_hi, wt2_lo, bcat);
        xt_split_kernel<<<dim3(HW/64, CH/64, BATCH), dim3(256), 0, stream>>>(x, xt_hi, xt_lo);
        gemm_in_mfma<<<dim3(MTOT/256, CH/64), dim3(256), 0, stream>>>(
            xt_hi, xt_lo, wt3_hi, wt3_lo, b_in, v);
        dw_ln_gelu_nhwc_split<<<dim3(MTOT/POSB), dim3(256), 0, stream>>>(
            xt_hi, xt_lo, dw_w, dw_b, ln_g, ln_b, fh, fl);
        gemm_in_mfma<<<dim3(MTOT/256, CH/64), dim3(256), 0, stream>>>(
            fh, fl, wt2_hi, wt2_lo, bcat, omb);
        sample_kernel_omb_split<<<dim3(MTOT/POSB), dim3(256), 0, stream>>>(v, omb, sh, sl);
        gemm_out_bf16<<<dim3(MTOT/256, CH/64), dim3(256), 0, stream>>>(
            sh, sl, wt_hi, wt_lo, b_out, bn_g, bn_b, bn_mean, bn_var, out);
    }
}

// Round 11
// 229.329 us; speedup vs baseline: 1.0208x; 1.0136x over previous
//
#include <hip/hip_runtime.h>
#include <math.h>

// Problem constants
#define BATCH 8
#define CH    256
#define HDIM  56
#define WDIM  56
#define HW    (HDIM*WDIM)          // 3136
#define MTOT  (BATCH*HW)           // 25088
#define GRP   8
#define GC    32
#define NP    9                    // K*K
#define NOFF  (GRP*NP*2)           // 144
#define NMSK  (GRP*NP)             // 72
#define NTOT  (NOFF+NMSK)          // 216
#define POSB  4                    // positions per sample block
#define DWBLK (MTOT/POSB)          // 6272
#define XTBLK (49*4*8)             // 1568 xt-split blocks
#define NBLKG ((MTOT/64)*2)        // 784: 392 m-tiles(64) x 2 n-tiles(128)

typedef float f32x4 __attribute__((ext_vector_type(4)));
typedef short s16x8 __attribute__((ext_vector_type(8)));

// split a,b into packed bf16 hi (truncation) and bf16 lo (exact remainder, truncated)
__device__ inline void split2(float a, float b, unsigned int& hp, unsigned int& lp)
{
    const unsigned int ua = __float_as_uint(a), ub = __float_as_uint(b);
    hp = (ub & 0xffff0000u) | (ua >> 16);
    const float ha = __uint_as_float(ua & 0xffff0000u);
    const float hb = __uint_as_float(ub & 0xffff0000u);
    const unsigned int la = __float_as_uint(a - ha), lb = __float_as_uint(b - hb);
    lp = (lb & 0xffff0000u) | (la >> 16);
}

// async global(16B/lane) -> LDS (wave-uniform base + lane*16)
__device__ __forceinline__ void gld_lds16(const unsigned short* g, unsigned short* l)
{
    __builtin_amdgcn_global_load_lds(
        (const __attribute__((address_space(1))) unsigned int*)g,
        (__attribute__((address_space(3))) unsigned int*)l, 16, 0, 0);
}

// ---------------------------------------------------------------------------
// 64m x 128n LDS-staged GEMM body (r10-verified structure): 4 waves =
// 2m-halves x 2n-halves, per-wave 32m x 64n, acc[4][2]. global_load_lds
// width-16 staging, slot swizzle on both sides, 2-barrier k-loop.
// ---------------------------------------------------------------------------
__device__ __forceinline__ void gemm64x128_body(
    const unsigned short* __restrict__ ahi,
    const unsigned short* __restrict__ alo,
    const unsigned short* __restrict__ whi,
    const unsigned short* __restrict__ wlo,
    unsigned short* sAh, unsigned short* sAl,
    unsigned short* sBh, unsigned short* sBl,
    int m0, int n0g, int t, f32x4 (&acc)[4][2])
{
    const int lane = t & 63, wv4 = t >> 6;
    const int wm = wv4 >> 1;
    const int wn = wv4 & 1;
    const int fm = lane & 15, q = lane >> 4;

    const int arow0 = t >> 2;
    const int asl0  = (t & 3) ^ ((arow0 >> 1) & 3);
    const int albase0 = wv4 * 512;             // shorts; wave-uniform
    int brow[2], bsl[2], blbase[2];
    #pragma unroll
    for (int i = 0; i < 2; ++i) {
        const int u = i * 256 + t;
        brow[i] = u >> 2;
        bsl[i] = (u & 3) ^ ((brow[i] >> 1) & 3);
        blbase[i] = i * 2048 + wv4 * 512;
    }

    for (int kk = 0; kk < 8; ++kk) {
        const int k0 = kk * 32;
        {
            const size_t ga = (size_t)(m0 + arow0) * CH + k0 + asl0 * 8;
            gld_lds16(ahi + ga, sAh + albase0);
            gld_lds16(alo + ga, sAl + albase0);
        }
        #pragma unroll
        for (int i = 0; i < 2; ++i) {
            const size_t gb = (size_t)(n0g + brow[i]) * CH + k0 + bsl[i] * 8;
            gld_lds16(whi + gb, sBh + blbase[i]);
            gld_lds16(wlo + gb, sBl + blbase[i]);
        }
        __syncthreads();

        s16x8 ah[2], al[2], wh[4], wl[4];
        #pragma unroll
        for (int i = 0; i < 2; ++i) {
            const int ar = wm * 32 + i * 16 + fm;
            const int as = (q ^ ((ar >> 1) & 3)) * 8;
            ah[i] = *(const s16x8*)&sAh[ar * 32 + as];
            al[i] = *(const s16x8*)&sAl[ar * 32 + as];
        }
        #pragma unroll
        for (int i = 0; i < 4; ++i) {
            const int br = wn * 64 + i * 16 + fm;
            const int bs = (q ^ ((br >> 1) & 3)) * 8;
            wh[i] = *(const s16x8*)&sBh[br * 32 + bs];
            wl[i] = *(const s16x8*)&sBl[br * 32 + bs];
        }
        #pragma unroll
        for (int nt = 0; nt < 4; ++nt)
            #pragma unroll
            for (int mt = 0; mt < 2; ++mt) {
                acc[nt][mt] = __builtin_amdgcn_mfma_f32_16x16x32_bf16(wh[nt], ah[mt], acc[nt][mt], 0, 0, 0);
                acc[nt][mt] = __builtin_amdgcn_mfma_f32_16x16x32_bf16(wh[nt], al[mt], acc[nt][mt], 0, 0, 0);
                acc[nt][mt] = __builtin_amdgcn_mfma_f32_16x16x32_bf16(wl[nt], ah[mt], acc[nt][mt], 0, 0, 0);
            }
        __syncthreads();
    }
}

// ---------------------------------------------------------------------------
// dw (per-position wave) body, reading NHWC bf16 hi/lo xt -> pre-split fh/fl.
// LDS pointers passed in (aliased smem in the combined kernel).
// ---------------------------------------------------------------------------
__device__ __forceinline__ void dw_body(
    const unsigned short* __restrict__ xhi,
    const unsigned short* __restrict__ xlo,
    const float* __restrict__ dw_w,
    const float* __restrict__ dw_b,
    const float* __restrict__ ln_g,
    const float* __restrict__ ln_b,
    unsigned short* __restrict__ fh,
    unsigned short* __restrict__ fl,
    float* wt, float* lbias, float* lgam, float* lbet,
    int bid, int t)
{
    {
        const float* wp = dw_w + t * NP;
        #pragma unroll
        for (int p = 0; p < NP; ++p) wt[p * CH + t] = wp[p];
        lbias[t] = dw_b[t]; lgam[t] = ln_g[t]; lbet[t] = ln_b[t];
    }
    __syncthreads();

    const int per = DWBLK / 8;             // 784
    const int sw  = (bid & 7) * per + (bid >> 3);
    const int q   = t >> 6, lane = t & 63;
    const int n   = sw * POSB + q;
    const int b   = n / HW;
    const int hw  = n % HW;
    const int h   = hw / WDIM, w = hw % WDIM;
    const int c4  = lane * 4;
    const size_t base = (size_t)b * HW * CH + c4;

    float ax = 0.0f, ay = 0.0f, az = 0.0f, aw = 0.0f;
    #pragma unroll
    for (int p = 0; p < NP; ++p) {
        const int hh = h + p / 3 - 1;
        const int ww = w + p % 3 - 1;
        if ((unsigned)hh >= (unsigned)HDIM || (unsigned)ww >= (unsigned)WDIM)
            continue;                       // wave-uniform branch (h,w per-wave)
        const size_t idx = base + (size_t)(hh * WDIM + ww) * CH;
        const ushort4 uh = *(const ushort4*)(xhi + idx);
        const ushort4 ul = *(const ushort4*)(xlo + idx);
        const float4 wv = *(const float4*)&wt[p * CH + c4];
        ax = fmaf(__uint_as_float((unsigned)uh.x << 16), wv.x,
             fmaf(__uint_as_float((unsigned)ul.x << 16), wv.x, ax));
        ay = fmaf(__uint_as_float((unsigned)uh.y << 16), wv.y,
             fmaf(__uint_as_float((unsigned)ul.y << 16), wv.y, ay));
        az = fmaf(__uint_as_float((unsigned)uh.z << 16), wv.z,
             fmaf(__uint_as_float((unsigned)ul.z << 16), wv.z, az));
        aw = fmaf(__uint_as_float((unsigned)uh.w << 16), wv.w,
             fmaf(__uint_as_float((unsigned)ul.w << 16), wv.w, aw));
    }
    {
        const float4 b4 = *(const float4*)&lbias[c4];
        ax += b4.x; ay += b4.y; az += b4.z; aw += b4.w;
    }

    float s1 = ax + ay + az + aw;
    float s2 = ax*ax + ay*ay + az*az + aw*aw;
    #pragma unroll
    for (int off = 32; off > 0; off >>= 1) {
        s1 += __shfl_xor(s1, off);
        s2 += __shfl_xor(s2, off);
    }
    const float mean = s1 * (1.0f / 256.0f);
    const float rstd = rsqrtf(s2 * (1.0f / 256.0f) - mean * mean + 1e-5f);

    const float4 g4 = *(const float4*)&lgam[c4];
    const float4 e4 = *(const float4*)&lbet[c4];
    const float x0 = (ax - mean) * rstd * g4.x + e4.x;
    const float x1 = (ay - mean) * rstd * g4.y + e4.y;
    const float x2 = (az - mean) * rstd * g4.z + e4.z;
    const float x3 = (aw - mean) * rstd * g4.w + e4.w;
    const float o0 = 0.5f * x0 * (1.0f + erff(x0 * 0.70710678118654752f));
    const float o1 = 0.5f * x1 * (1.0f + erff(x1 * 0.70710678118654752f));
    const float o2 = 0.5f * x2 * (1.0f + erff(x2 * 0.70710678118654752f));
    const float o3 = 0.5f * x3 * (1.0f + erff(x3 * 0.70710678118654752f));

    unsigned int hp0, lp0, hp1, lp1;
    split2(o0, o1, hp0, lp0);
    split2(o2, o3, hp1, lp1);
    *(uint2*)&fh[(size_t)n * CH + c4] = make_uint2(hp0, hp1);
    *(uint2*)&fl[(size_t)n * CH + c4] = make_uint2(lp0, lp1);
}

// ---------------------------------------------------------------------------
// PREP: xt_split (1568 blocks) + wt_split(w_out) + wt_split(w_in) +
// wt2_split(+bcat), fused by block-uniform bid branch. One dispatch.
// ---------------------------------------------------------------------------
__global__ __launch_bounds__(256)
void prep_kernel(const float* __restrict__ x,
                 unsigned short* __restrict__ xt_hi,
                 unsigned short* __restrict__ xt_lo,
                 const float* __restrict__ w_out,
                 unsigned short* __restrict__ wt_hi,
                 unsigned short* __restrict__ wt_lo,
                 const float* __restrict__ w_in,
                 unsigned short* __restrict__ wt3_hi,
                 unsigned short* __restrict__ wt3_lo,
                 const float* __restrict__ w_off,
                 const float* __restrict__ w_mask,
                 const float* __restrict__ b_off,
                 const float* __restrict__ b_mask,
                 unsigned short* __restrict__ wt2_hi,
                 unsigned short* __restrict__ wt2_lo,
                 float* __restrict__ bcat)
{
    __shared__ float lds[64][68];
    const int bid = blockIdx.x;
    const int t = threadIdx.x;

    if (bid < XTBLK) {
        // xt_split: NCHW -> [m][k] bf16 hi/lo, 64x64 tiles
        const int hw0 = (bid % 49) * 64;
        const int k0  = ((bid / 49) % 4) * 64;
        const int b   = bid / 196;
        #pragma unroll
        for (int p = 0; p < 4; ++p) {
            const int kr = (t >> 4) + p * 16;
            const int hc = (t & 15) * 4;
            *(float4*)&lds[kr][hc] =
                *(const float4*)(x + ((size_t)b * CH + k0 + kr) * HW + hw0 + hc);
        }
        __syncthreads();
        const int ml = t >> 2;
        const int kc = (t & 3) * 16;
        unsigned int hbuf[8], lbuf[8];
        #pragma unroll
        for (int j = 0; j < 16; j += 2)
            split2(lds[kc + j][ml], lds[kc + j + 1][ml], hbuf[j >> 1], lbuf[j >> 1]);
        const size_t row = (size_t)(b * HW + hw0 + ml) * CH + k0 + kc;
        *(uint4*)&xt_hi[row]     = *(uint4*)&hbuf[0];
        *(uint4*)&xt_hi[row + 8] = *(uint4*)&hbuf[4];
        *(uint4*)&xt_lo[row]     = *(uint4*)&lbuf[0];
        *(uint4*)&xt_lo[row + 8] = *(uint4*)&lbuf[4];
    } else if (bid < XTBLK + 32) {
        // wt_split for w_out (16 blocks) then w_in (16 blocks)
        const int u = bid - XTBLK;
        const float* w = (u < 16) ? w_out : w_in;
        unsigned short* hi = (u < 16) ? wt_hi : wt3_hi;
        unsigned short* lo = (u < 16) ? wt_lo : wt3_lo;
        const int uu = u & 15;
        const int kt = (uu & 3) * 64, nt = (uu >> 2) * 64;
        #pragma unroll
        for (int p = 0; p < 4; ++p) {
            const int kr = (t >> 4) + p * 16, nc = (t & 15) * 4;
            *(float4*)&lds[kr][nc] = *(const float4*)(w + (size_t)(kt + kr) * CH + nt + nc);
        }
        __syncthreads();
        const int nl = t >> 2, kc = (t & 3) * 16;
        #pragma unroll
        for (int j = 0; j < 16; j += 2) {
            const float f0 = lds[kc + j][nl], f1 = lds[kc + j + 1][nl];
            unsigned int hp, lp;
            split2(f0, f1, hp, lp);
            *(unsigned int*)&hi[(size_t)(nt + nl) * CH + kt + kc + j] = hp;
            *(unsigned int*)&lo[(size_t)(nt + nl) * CH + kt + kc + j] = lp;
        }
    } else {
        // wt2_split (16 blocks) + bcat on first
        const int u = bid - XTBLK - 32;    // 0..15
        const int n = t;
        if (u == 0) {
            bcat[n] = (n < NOFF) ? b_off[n] : ((n < NTOT) ? b_mask[n - NOFF] : 0.0f);
        }
        const int k0 = u * 16;
        #pragma unroll
        for (int j = 0; j < 16; j += 2) {
            const int k = k0 + j;
            float f0 = 0.0f, f1 = 0.0f;
            if (n < NOFF) {
                f0 = w_off[(size_t)k * NOFF + n];
                f1 = w_off[(size_t)(k + 1) * NOFF + n];
            } else if (n < NTOT) {
                f0 = w_mask[(size_t)k * NMSK + (n - NOFF)];
                f1 = w_mask[(size_t)(k + 1) * NMSK + (n - NOFF)];
            }
            unsigned int hp, lp;
            split2(f0, f1, hp, lp);
            *(unsigned int*)&wt2_hi[(size_t)n * CH + k] = hp;
            *(unsigned int*)&wt2_lo[(size_t)n * CH + k] = lp;
        }
    }
}

// ---------------------------------------------------------------------------
// Co-dispatch: dw (blocks 0..6271) || v-projection GEMM (blocks 6272..7055).
// The two are independent (both read only xt + weights); the GEMM hides in
// dw's tail. Aliased LDS union (24.5 KB).
// ---------------------------------------------------------------------------
__global__ __launch_bounds__(256)
void dw_and_gemm_v(const unsigned short* __restrict__ xhi,
                   const unsigned short* __restrict__ xlo,
                   const float* __restrict__ dw_w,
                   const float* __restrict__ dw_b,
                   const float* __restrict__ ln_g,
                   const float* __restrict__ ln_b,
                   unsigned short* __restrict__ fh,
                   unsigned short* __restrict__ fl,
                   const unsigned short* __restrict__ whi,  // wt3 (w_in^T)
                   const unsigned short* __restrict__ wlo,
                   const float* __restrict__ bias,          // b_in
                   float* __restrict__ v)
{
    __shared__ alignas(16) char smem[24576];
    const int bid = blockIdx.x;
    const int t = threadIdx.x;

    if (bid < DWBLK) {
        float* wt    = (float*)smem;                 // [NP][CH] 9216 B
        float* lbias = (float*)(smem + NP * CH * 4); // 1024 B each
        float* lgam  = lbias + CH;
        float* lbet  = lgam + CH;
        dw_body(xhi, xlo, dw_w, dw_b, ln_g, ln_b, fh, fl,
                wt, lbias, lgam, lbet, bid, t);
    } else {
        unsigned short* sAh = (unsigned short*)smem;     // 4 KB
        unsigned short* sAl = sAh + 64 * 32;             // 4 KB
        unsigned short* sBh = sAl + 64 * 32;             // 8 KB
        unsigned short* sBl = sBh + 128 * 32;            // 8 KB
        const int lbid = bid - DWBLK;                    // 0..783
        const int sw = (lbid & 7) * (NBLKG / 8) + (lbid >> 3);
        const int m0  = (sw >> 1) * 64;
        const int n0g = (sw & 1) * 128;
        const int lane = t & 63, wv4 = t >> 6;
        const int wm = wv4 >> 1, wn = wv4 & 1;
        const int fm = lane & 15, q = lane >> 4;

        f32x4 acc[4][2];
        const f32x4 zero = {0.0f, 0.0f, 0.0f, 0.0f};
        #pragma unroll
        for (int i = 0; i < 4; ++i)
            #pragma unroll
            for (int j = 0; j < 2; ++j) acc[i][j] = zero;

        gemm64x128_body(xhi, xlo, whi, wlo, sAh, sAl, sBh, sBl, m0, n0g, t, acc);

        #pragma unroll
        for (int nt = 0; nt < 4; ++nt) {
            const int n = n0g + wn*64 + nt*16 + q*4;
            const float4 b4 = *(const float4*)&bias[n];
            #pragma unroll
            for (int mt = 0; mt < 2; ++mt) {
                const int mm = m0 + wm*32 + mt*16 + fm;
                f32x4 o = acc[nt][mt];
                o[0] += b4.x; o[1] += b4.y; o[2] += b4.z; o[3] += b4.w;
                *(f32x4*)&v[(size_t)mm * CH + n] = o;
            }
        }
    }
}

// ---------------------------------------------------------------------------
// omb projection GEMM: 64m x 128n tiles, 784 blocks x 4 waves = 12.25
// waves/CU (the proven-roofline regime). f32 output with bcat bias.
// ---------------------------------------------------------------------------
__global__ __launch_bounds__(256)
void gemm_omb(const unsigned short* __restrict__ ahi,   // fh
              const unsigned short* __restrict__ alo,   // fl
              const unsigned short* __restrict__ whi,   // wt2
              const unsigned short* __restrict__ wlo,
              const float* __restrict__ bias,           // bcat
              float* __restrict__ omb)
{
    __shared__ unsigned short sAh[64*32], sAl[64*32], sBh[128*32], sBl[128*32];

    const int sw = (blockIdx.x & 7) * (NBLKG / 8) + (blockIdx.x >> 3);
    const int m0  = (sw >> 1) * 64;
    const int n0g = (sw & 1) * 128;
    const int t = threadIdx.x;
    const int lane = t & 63, wv4 = t >> 6;
    const int wm = wv4 >> 1, wn = wv4 & 1;
    const int fm = lane & 15, q = lane >> 4;

    f32x4 acc[4][2];
    const f32x4 zero = {0.0f, 0.0f, 0.0f, 0.0f};
    #pragma unroll
    for (int i = 0; i < 4; ++i)
        #pragma unroll
        for (int j = 0; j < 2; ++j) acc[i][j] = zero;

    gemm64x128_body(ahi, alo, whi, wlo, sAh, sAl, sBh, sBl, m0, n0g, t, acc);

    #pragma unroll
    for (int nt = 0; nt < 4; ++nt) {
        const int n = n0g + wn*64 + nt*16 + q*4;
        const float4 b4 = *(const float4*)&bias[n];
        #pragma unroll
        for (int mt = 0; mt < 2; ++mt) {
            const int mm = m0 + wm*32 + mt*16 + fm;
            f32x4 o = acc[nt][mt];
            o[0] += b4.x; o[1] += b4.y; o[2] += b4.z; o[3] += b4.w;
            *(f32x4*)&omb[(size_t)mm * CH + n] = o;
        }
    }
}

// ---------------------------------------------------------------------------
// Output GEMM, 64m x 128n tiles (r10-verified): BN+SiLU NCHW epilogue.
// ---------------------------------------------------------------------------
__global__ __launch_bounds__(256)
void gemm_out_64x128(const unsigned short* __restrict__ ahi,
                     const unsigned short* __restrict__ alo,
                     const unsigned short* __restrict__ whi,
                     const unsigned short* __restrict__ wlo,
                     const float* __restrict__ bias,
                     const float* __restrict__ bn_g,
                     const float* __restrict__ bn_b,
                     const float* __restrict__ bn_mean,
                     const float* __restrict__ bn_var,
                     float* __restrict__ y)                  // [B,256,3136]
{
    __shared__ unsigned short sAh[64*32], sAl[64*32], sBh[128*32], sBl[128*32];

    const int sw = (blockIdx.x & 7) * (NBLKG / 8) + (blockIdx.x >> 3);
    const int m0  = (sw >> 1) * 64;
    const int n0g = (sw & 1) * 128;
    const int t = threadIdx.x;
    const int lane = t & 63, wv4 = t >> 6;
    const int wm = wv4 >> 1, wn = wv4 & 1;
    const int fm = lane & 15, q = lane >> 4;

    f32x4 acc[4][2];
    const f32x4 zero = {0.0f, 0.0f, 0.0f, 0.0f};
    #pragma unroll
    for (int i = 0; i < 4; ++i)
        #pragma unroll
        for (int j = 0; j < 2; ++j) acc[i][j] = zero;

    gemm64x128_body(ahi, alo, whi, wlo, sAh, sAl, sBh, sBl, m0, n0g, t, acc);

    #pragma unroll
    for (int nt = 0; nt < 4; ++nt) {
        #pragma unroll
        for (int r = 0; r < 4; ++r) {
            const int n = n0g + wn*64 + nt*16 + q*4 + r;
            const float sc = bn_g[n] * rsqrtf(bn_var[n] + 1e-5f);
            const float sb = bn_b[n] - bn_mean[n] * sc;
            const float bs = bias[n];
            #pragma unroll
            for (int mt = 0; mt < 2; ++mt) {
                const int mm = m0 + wm*32 + mt*16 + fm;
                const int bimg = mm / HW, hw = mm % HW;
                float val = (acc[nt][mt][r] + bs) * sc + sb;
                y[(size_t)bimg * CH * HW + (size_t)n * HW + hw] = val / (1.0f + expf(-val));
            }
        }
    }
}

// ---------------------------------------------------------------------------
// Deformable sampling reading the padded omb [MTOT][256] rows
// (cols 0..143 offsets, 144..215 mask logits). Output s PRE-SPLIT bf16 hi/lo.
// ---------------------------------------------------------------------------
__global__ __launch_bounds__(256)
void sample_kernel_omb_split(const float* __restrict__ v,
                             const float* __restrict__ omb,
                             unsigned short* __restrict__ sh,  // [MTOT][256]
                             unsigned short* __restrict__ sl)  // [MTOT][256]
{
    __shared__ alignas(16) float loff[POSB][NOFF];
    __shared__ alignas(16) float lmsk[POSB][NMSK];
    __shared__ alignas(16) float wtab[POSB][GRP*NP][4];
    __shared__ alignas(16) int   itab[POSB][GRP*NP][4];

    const int per  = DWBLK / 8;              // 784
    const int bid  = blockIdx.x;
    const int sw   = (bid % 8) * per + (bid / 8);
    const int n0 = sw * POSB;
    const int t = threadIdx.x;

    if (t < POSB * (NOFF/4)) {
        const int q = t / (NOFF/4), r = t % (NOFF/4);
        *(float4*)&loff[q][r*4] = *(const float4*)&omb[(size_t)(n0+q)*CH + r*4];
    } else if (t < POSB * (NOFF/4) + POSB * (NMSK/4)) {
        const int u = t - POSB * (NOFF/4);
        const int q = u / (NMSK/4), r = u % (NMSK/4);
        *(float4*)&lmsk[q][r*4] = *(const float4*)&omb[(size_t)(n0+q)*CH + NOFF + r*4];
    }
    __syncthreads();

    if (t < POSB * GRP) {
        const int q = t >> 3, g = t & 7;
        float* mm = &lmsk[q][g * NP];
        float mx = -1e30f;
        #pragma unroll
        for (int p = 0; p < NP; ++p) mx = fmaxf(mx, mm[p]);
        float sum = 0.0f;
        #pragma unroll
        for (int p = 0; p < NP; ++p) { const float e = __expf(mm[p] - mx); mm[p] = e; sum += e; }
        const float inv = 1.0f / sum;
        #pragma unroll
        for (int p = 0; p < NP; ++p) mm[p] *= inv;
    }
    __syncthreads();

    for (int u = t; u < POSB * GRP * NP; u += 256) {
        const int q = u / (GRP*NP), j = u % (GRP*NP);
        const int g = j / NP, p = j % NP;
        const int n = n0 + q;
        const int hw = n % HW;
        const int h = hw / WDIM, w = hw % WDIM;
        const float ox = loff[q][g*18 + p*2 + 0];
        const float oy = loff[q][g*18 + p*2 + 1];
        const float m  = lmsk[q][g*NP + p];
        const float px = (float)(w + p/3) + ox;
        const float py = (float)(h + p%3) + oy;
        const float fx = floorf(px), fy = floorf(py);
        const float wx = px - fx, wy = py - fy;
        const int x0 = (int)fx, y0 = (int)fy;
        const int x1 = x0 + 1, y1 = y0 + 1;
        const float vx0 = (x0 >= 1 && x0 < 57) ? 1.0f : 0.0f;
        const float vx1 = (x1 >= 1 && x1 < 57) ? 1.0f : 0.0f;
        const float vy0 = (y0 >= 1 && y0 < 57) ? 1.0f : 0.0f;
        const float vy1 = (y1 >= 1 && y1 < 57) ? 1.0f : 0.0f;
        const int x0c = min(max(x0, 1), 56), x1c = min(max(x1, 1), 56);
        const int y0c = min(max(y0, 1), 56), y1c = min(max(y1, 1), 56);
        wtab[q][j][0] = m * (1.0f-wx) * (1.0f-wy) * vx0 * vy0;
        wtab[q][j][1] = m * wx        * (1.0f-wy) * vx1 * vy0;
        wtab[q][j][2] = m * (1.0f-wx) * wy        * vx0 * vy1;
        wtab[q][j][3] = m * wx        * wy        * vx1 * vy1;
        itab[q][j][0] = ((y0c-1)*WDIM + (x0c-1)) * CH;
        itab[q][j][1] = ((y0c-1)*WDIM + (x1c-1)) * CH;
        itab[q][j][2] = ((y1c-1)*WDIM + (x0c-1)) * CH;
        itab[q][j][3] = ((y1c-1)*WDIM + (x1c-1)) * CH;
    }
    __syncthreads();

    const int q = t >> 6, lane = t & 63;
    const int n = n0 + q;
    const int b = n / HW;
    const int g = lane >> 3;
    const float* vb = v + (size_t)b*HW*CH + lane*4;
    float4 acc = {0.0f, 0.0f, 0.0f, 0.0f};
    #pragma unroll
    for (int p = 0; p < NP; ++p) {
        const int j = g*NP + p;
        const float4 wv = *(const float4*)&wtab[q][j][0];
        const int4  iv = *(const int4*)&itab[q][j][0];
        const float4 c0 = *(const float4*)(vb + iv.x);
        const float4 c1 = *(const float4*)(vb + iv.y);
        const float4 c2 = *(const float4*)(vb + iv.z);
        const float4 c3 = *(const float4*)(vb + iv.w);
        acc.x += wv.x*c0.x + wv.y*c1.x + wv.z*c2.x + wv.w*c3.x;
        acc.y += wv.x*c0.y + wv.y*c1.y + wv.z*c2.y + wv.w*c3.y;
        acc.z += wv.x*c0.z + wv.y*c1.z + wv.z*c2.z + wv.w*c3.z;
        acc.w += wv.x*c0.w + wv.y*c1.w + wv.z*c2.w + wv.w*c3.w;
    }
    unsigned int hp0, lp0, hp1, lp1;
    split2(acc.x, acc.y, hp0, lp0);
    split2(acc.z, acc.w, hp1, lp1);
    *(uint2*)&sh[(size_t)n*CH + lane*4] = make_uint2(hp0, hp1);
    *(uint2*)&sl[(size_t)n*CH + lane*4] = make_uint2(lp0, lp1);
}

// ===================== FALLBACK KERNELS (round-5 verified) =====================
__global__ __launch_bounds__(256)
void xt_split_kernel(const float* __restrict__ x,
                     unsigned short* __restrict__ hi,
                     unsigned short* __restrict__ lo)
{
    __shared__ float lds[64][68];
    const int hw0 = blockIdx.x * 64;
    const int k0  = blockIdx.y * 64;
    const int b   = blockIdx.z;
    const int t = threadIdx.x;
    #pragma unroll
    for (int p = 0; p < 4; ++p) {
        const int kr = (t >> 4) + p * 16;
        const int hc = (t & 15) * 4;
        *(float4*)&lds[kr][hc] =
            *(const float4*)(x + ((size_t)b * CH + k0 + kr) * HW + hw0 + hc);
    }
    __syncthreads();
    const int ml = t >> 2;
    const int kc = (t & 3) * 16;
    unsigned int hbuf[8], lbuf[8];
    #pragma unroll
    for (int j = 0; j < 16; j += 2)
        split2(lds[kc + j][ml], lds[kc + j + 1][ml], hbuf[j >> 1], lbuf[j >> 1]);
    const size_t row = (size_t)(b * HW + hw0 + ml) * CH + k0 + kc;
    *(uint4*)&hi[row]     = *(uint4*)&hbuf[0];
    *(uint4*)&hi[row + 8] = *(uint4*)&hbuf[4];
    *(uint4*)&lo[row]     = *(uint4*)&lbuf[0];
    *(uint4*)&lo[row + 8] = *(uint4*)&lbuf[4];
}

__global__ __launch_bounds__(256)
void wt_split_kernel(const float* __restrict__ w,
                     unsigned short* __restrict__ hi,
                     unsigned short* __restrict__ lo)
{
    __shared__ float lds[64][68];
    const int kt = blockIdx.x * 64, nt = blockIdx.y * 64;
    const int t = threadIdx.x;
    #pragma unroll
    for (int p = 0; p < 4; ++p) {
        const int kr = (t >> 4) + p * 16, nc = (t & 15) * 4;
        *(float4*)&lds[kr][nc] = *(const float4*)(w + (size_t)(kt + kr) * CH + nt + nc);
    }
    __syncthreads();
    const int nl = t >> 2, kc = (t & 3) * 16;
    #pragma unroll
    for (int j = 0; j < 16; j += 2) {
        const float f0 = lds[kc + j][nl], f1 = lds[kc + j + 1][nl];
        unsigned int hp, lp;
        split2(f0, f1, hp, lp);
        *(unsigned int*)&hi[(size_t)(nt + nl) * CH + kt + kc + j] = hp;
        *(unsigned int*)&lo[(size_t)(nt + nl) * CH + kt + kc + j] = lp;
    }
}

__global__ __launch_bounds__(256)
void wt2_split_kernel(const float* __restrict__ w_off,
                      const float* __restrict__ w_mask,
                      const float* __restrict__ b_off,
                      const float* __restrict__ b_mask,
                      unsigned short* __restrict__ hi,
                      unsigned short* __restrict__ lo,
                      float* __restrict__ bcat)
{
    const int n = threadIdx.x;
    if (blockIdx.x == 0) {
        bcat[n] = (n < NOFF) ? b_off[n] : ((n < NTOT) ? b_mask[n - NOFF] : 0.0f);
    }
    const int k0 = blockIdx.x * 16;
    #pragma unroll
    for (int j = 0; j < 16; j += 2) {
        const int k = k0 + j;
        float f0 = 0.0f, f1 = 0.0f;
        if (n < NOFF) {
            f0 = w_off[(size_t)k * NOFF + n];
            f1 = w_off[(size_t)(k + 1) * NOFF + n];
        } else if (n < NTOT) {
            f0 = w_mask[(size_t)k * NMSK + (n - NOFF)];
            f1 = w_mask[(size_t)(k + 1) * NMSK + (n - NOFF)];
        }
        unsigned int hp, lp;
        split2(f0, f1, hp, lp);
        *(unsigned int*)&hi[(size_t)n * CH + k] = hp;
        *(unsigned int*)&lo[(size_t)n * CH + k] = lp;
    }
}

__global__ __launch_bounds__(256)
void gemm_in_mfma(const unsigned short* __restrict__ xhi,
                  const unsigned short* __restrict__ xlo,
                  const unsigned short* __restrict__ whi,
                  const unsigned short* __restrict__ wlo,
                  const float* __restrict__ bias,
                  float* __restrict__ v)
{
    const int m0 = blockIdx.x * 256;
    const int n0 = blockIdx.y * 64;
    const int t = threadIdx.x;
    const int lane = t & 63, wv = t >> 6;
    const int mblk = m0 + wv * 64;
    const int fm = lane & 15;
    const int q  = lane >> 4;

    f32x4 acc[4][4];
    const f32x4 zero = {0.0f, 0.0f, 0.0f, 0.0f};
    #pragma unroll
    for (int i = 0; i < 4; ++i)
        #pragma unroll
        for (int j = 0; j < 4; ++j) acc[i][j] = zero;

    const unsigned short *xrh[4], *xrl[4], *wrh[4], *wrl[4];
    #pragma unroll
    for (int mt = 0; mt < 4; ++mt) {
        xrh[mt] = xhi + (size_t)(mblk + mt*16 + fm) * CH + q * 8;
        xrl[mt] = xlo + (size_t)(mblk + mt*16 + fm) * CH + q * 8;
    }
    #pragma unroll
    for (int nt = 0; nt < 4; ++nt) {
        wrh[nt] = whi + (size_t)(n0 + nt*16 + fm) * CH + q * 8;
        wrl[nt] = wlo + (size_t)(n0 + nt*16 + fm) * CH + q * 8;
    }

    for (int k0 = 0; k0 < CH; k0 += 32) {
        s16x8 wh[4], wl[4], ah[4], al[4];
        #pragma unroll
        for (int nt = 0; nt < 4; ++nt) {
            wh[nt] = *(const s16x8*)(wrh[nt] + k0);
            wl[nt] = *(const s16x8*)(wrl[nt] + k0);
        }
        #pragma unroll
        for (int mt = 0; mt < 4; ++mt) {
            ah[mt] = *(const s16x8*)(xrh[mt] + k0);
            al[mt] = *(const s16x8*)(xrl[mt] + k0);
        }
        #pragma unroll
        for (int nt = 0; nt < 4; ++nt)
            #pragma unroll
            for (int mt = 0; mt < 4; ++mt) {
                acc[nt][mt] = __builtin_amdgcn_mfma_f32_16x16x32_bf16(wh[nt], ah[mt], acc[nt][mt], 0, 0, 0);
                acc[nt][mt] = __builtin_amdgcn_mfma_f32_16x16x32_bf16(wh[nt], al[mt], acc[nt][mt], 0, 0, 0);
                acc[nt][mt] = __builtin_amdgcn_mfma_f32_16x16x32_bf16(wl[nt], ah[mt], acc[nt][mt], 0, 0, 0);
            }
    }

    #pragma unroll
    for (int nt = 0; nt < 4; ++nt) {
        const float4 b4 = *(const float4*)&bias[n0 + nt*16 + q*4];
        #pragma unroll
        for (int mt = 0; mt < 4; ++mt) {
            f32x4 o = acc[nt][mt];
            o[0] += b4.x; o[1] += b4.y; o[2] += b4.z; o[3] += b4.w;
            *(f32x4*)&v[(size_t)(mblk + mt*16 + fm) * CH + n0 + nt*16 + q*4] = o;
        }
    }
}

__global__ __launch_bounds__(256)
void dw_ln_gelu_nhwc_split(const unsigned short* __restrict__ xhi,
                           const unsigned short* __restrict__ xlo,
                           const float* __restrict__ dw_w,
                           const float* __restrict__ dw_b,
                           const float* __restrict__ ln_g,
                           const float* __restrict__ ln_b,
                           unsigned short* __restrict__ fh,
                           unsigned short* __restrict__ fl)
{
    __shared__ float wt[NP][CH];
    __shared__ float lbias[CH], lgam[CH], lbet[CH];
    const int t = threadIdx.x;
    {
        const float* wp = dw_w + t * NP;
        #pragma unroll
        for (int p = 0; p < NP; ++p) wt[p][t] = wp[p];
        lbias[t] = dw_b[t]; lgam[t] = ln_g[t]; lbet[t] = ln_b[t];
    }
    __syncthreads();

    const int per  = DWBLK / 8;
    const int bid  = blockIdx.x;
    const int sw   = (bid & 7) * per + (bid >> 3);
    const int q    = t >> 6, lane = t & 63;
    const int n    = sw * POSB + q;
    const int b    = n / HW;
    const int hw   = n % HW;
    const int h    = hw / WDIM, w = hw % WDIM;
    const int c4   = lane * 4;
    const size_t base = (size_t)b * HW * CH + c4;

    float ax = 0.0f, ay = 0.0f, az = 0.0f, aw = 0.0f;
    #pragma unroll
    for (int p = 0; p < NP; ++p) {
        const int hh = h + p / 3 - 1;
        const int ww = w + p % 3 - 1;
        if ((unsigned)hh >= (unsigned)HDIM || (unsigned)ww >= (unsigned)WDIM)
            continue;
        const size_t idx = base + (size_t)(hh * WDIM + ww) * CH;
        const ushort4 uh = *(const ushort4*)(xhi + idx);
        const ushort4 ul = *(const ushort4*)(xlo + idx);
        const float4 wv = *(const float4*)&wt[p][c4];
        ax = fmaf(__uint_as_float((unsigned)uh.x << 16), wv.x,
             fmaf(__uint_as_float((unsigned)ul.x << 16), wv.x, ax));
        ay = fmaf(__uint_as_float((unsigned)uh.y << 16), wv.y,
             fmaf(__uint_as_float((unsigned)ul.y << 16), wv.y, ay));
        az = fmaf(__uint_as_float((unsigned)uh.z << 16), wv.z,
             fmaf(__uint_as_float((unsigned)ul.z << 16), wv.z, az));
        aw = fmaf(__uint_as_float((unsigned)uh.w << 16), wv.w,
             fmaf(__uint_as_float((unsigned)ul.w << 16), wv.w, aw));
    }
    {
        const float4 b4 = *(const float4*)&lbias[c4];
        ax += b4.x; ay += b4.y; az += b4.z; aw += b4.w;
    }
    float s1 = ax + ay + az + aw;
    float s2 = ax*ax + ay*ay + az*az + aw*aw;
    #pragma unroll
    for (int off = 32; off > 0; off >>= 1) {
        s1 += __shfl_xor(s1, off);
        s2 += __shfl_xor(s2, off);
    }
    const float mean = s1 * (1.0f / 256.0f);
    const float rstd = rsqrtf(s2 * (1.0f / 256.0f) - mean * mean + 1e-5f);
    const float4 g4 = *(const float4*)&lgam[c4];
    const float4 e4 = *(const float4*)&lbet[c4];
    const float x0 = (ax - mean) * rstd * g4.x + e4.x;
    const float x1 = (ay - mean) * rstd * g4.y + e4.y;
    const float x2 = (az - mean) * rstd * g4.z + e4.z;
    const float x3 = (aw - mean) * rstd * g4.w + e4.w;
    const float o0 = 0.5f * x0 * (1.0f + erff(x0 * 0.70710678118654752f));
    const float o1 = 0.5f * x1 * (1.0f + erff(x1 * 0.70710678118654752f));
    const float o2 = 0.5f * x2 * (1.0f + erff(x2 * 0.70710678118654752f));
    const float o3 = 0.5f * x3 * (1.0f + erff(x3 * 0.70710678118654752f));
    unsigned int hp0, lp0, hp1, lp1;
    split2(o0, o1, hp0, lp0);
    split2(o2, o3, hp1, lp1);
    *(uint2*)&fh[(size_t)n * CH + c4] = make_uint2(hp0, hp1);
    *(uint2*)&fl[(size_t)n * CH + c4] = make_uint2(lp0, lp1);
}

__global__ __launch_bounds__(256)
void gemm_out_bf16(const unsigned short* __restrict__ shp,
                   const unsigned short* __restrict__ slp,
                   const unsigned short* __restrict__ whi,
                   const unsigned short* __restrict__ wlo,
                   const float* __restrict__ bias,
                   const float* __restrict__ bn_g,
                   const float* __restrict__ bn_b,
                   const float* __restrict__ bn_mean,
                   const float* __restrict__ bn_var,
                   float* __restrict__ y)
{
    const int m0 = blockIdx.x * 256;
    const int n0 = blockIdx.y * 64;
    const int t = threadIdx.x;
    const int lane = t & 63, wv = t >> 6;
    const int mblk = m0 + wv * 64;
    const int fm = lane & 15;
    const int q  = lane >> 4;

    f32x4 acc[4][4];
    const f32x4 zero = {0.0f, 0.0f, 0.0f, 0.0f};
    #pragma unroll
    for (int i = 0; i < 4; ++i)
        #pragma unroll
        for (int j = 0; j < 4; ++j) acc[i][j] = zero;

    const unsigned short *xrh[4], *xrl[4], *wrh[4], *wrl[4];
    #pragma unroll
    for (int mt = 0; mt < 4; ++mt) {
        xrh[mt] = shp + (size_t)(mblk + mt*16 + fm) * CH + q * 8;
        xrl[mt] = slp + (size_t)(mblk + mt*16 + fm) * CH + q * 8;
    }
    #pragma unroll
    for (int nt = 0; nt < 4; ++nt) {
        wrh[nt] = whi + (size_t)(n0 + nt*16 + fm) * CH + q * 8;
        wrl[nt] = wlo + (size_t)(n0 + nt*16 + fm) * CH + q * 8;
    }

    for (int k0 = 0; k0 < CH; k0 += 32) {
        s16x8 wh[4], wl[4], ah[4], al[4];
        #pragma unroll
        for (int nt = 0; nt < 4; ++nt) {
            wh[nt] = *(const s16x8*)(wrh[nt] + k0);
            wl[nt] = *(const s16x8*)(wrl[nt] + k0);
        }
        #pragma unroll
        for (int mt = 0; mt < 4; ++mt) {
            ah[mt] = *(const s16x8*)(xrh[mt] + k0);
            al[mt] = *(const s16x8*)(xrl[mt] + k0);
        }
        #pragma unroll
        for (int nt = 0; nt < 4; ++nt)
            #pragma unroll
            for (int mt = 0; mt < 4; ++mt) {
                acc[nt][mt] = __builtin_amdgcn_mfma_f32_16x16x32_bf16(wh[nt], ah[mt], acc[nt][mt], 0, 0, 0);
                acc[nt][mt] = __builtin_amdgcn_mfma_f32_16x16x32_bf16(wh[nt], al[mt], acc[nt][mt], 0, 0, 0);
                acc[nt][mt] = __builtin_amdgcn_mfma_f32_16x16x32_bf16(wl[nt], ah[mt], acc[nt][mt], 0, 0, 0);
            }
    }

    #pragma unroll
    for (int nt = 0; nt < 4; ++nt) {
        #pragma unroll
        for (int r = 0; r < 4; ++r) {
            const int n = n0 + nt*16 + q*4 + r;
            const float sc = bn_g[n] * rsqrtf(bn_var[n] + 1e-5f);
            const float sb = bn_b[n] - bn_mean[n] * sc;
            const float bs = bias[n];
            #pragma unroll
            for (int mt = 0; mt < 4; ++mt) {
                const int mm = mblk + mt*16;
                const size_t base = (size_t)(mm / HW) * CH * HW + (mm % HW);
                float val = (acc[nt][mt][r] + bs) * sc + sb;
                y[base + (size_t)n * HW + fm] = val / (1.0f + expf(-val));
            }
        }
    }
}

extern "C" void kernel_launch(void* const* d_in, const int* in_sizes, int n_in,
                              void* d_out, int out_size, void* d_ws, size_t ws_size,
                              hipStream_t stream) {
    const float* x      = (const float*)d_in[0];
    const float* w_in   = (const float*)d_in[1];
    const float* b_in   = (const float*)d_in[2];
    const float* dw_w   = (const float*)d_in[3];
    const float* dw_b   = (const float*)d_in[4];
    const float* ln_g   = (const float*)d_in[5];
    const float* ln_b   = (const float*)d_in[6];
    const float* w_off  = (const float*)d_in[7];
    const float* b_off  = (const float*)d_in[8];
    const float* w_mask = (const float*)d_in[9];
    const float* b_mask = (const float*)d_in[10];
    const float* w_out  = (const float*)d_in[11];
    const float* b_out  = (const float*)d_in[12];
    const float* bn_g   = (const float*)d_in[13];
    const float* bn_b   = (const float*)d_in[14];
    const float* bn_mean= (const float*)d_in[15];
    const float* bn_var = (const float*)d_in[16];
    float* out = (float*)d_out;

    const size_t SZ = (size_t)MTOT * CH;                 // elements
    // Layout: v | xt_hi,xt_lo | fh,fl | omb | weights | bcat
    const size_t need_new =
        4 * SZ * sizeof(float)
        + 6 * (size_t)CH * CH * sizeof(unsigned short)
        + CH * sizeof(float);

    if (ws_size >= need_new) {
        // -------- main path: 5 dispatches --------
        float* ws = (float*)d_ws;
        float* v    = ws;                                          // SZ f32
        unsigned short* xt_hi = (unsigned short*)(v + SZ);         // SZ us
        unsigned short* xt_lo = xt_hi + SZ;                        // SZ us
        unsigned short* fh    = xt_lo + SZ;                        // SZ us
        unsigned short* fl    = fh + SZ;                           // SZ us
        float* omb  = (float*)(fl + SZ);                           // SZ f32
        unsigned short* wt_hi  = (unsigned short*)(omb + SZ);
        unsigned short* wt_lo  = wt_hi + CH * CH;
        unsigned short* wt2_hi = wt_lo + CH * CH;
        unsigned short* wt2_lo = wt2_hi + CH * CH;
        unsigned short* wt3_hi = wt2_lo + CH * CH;
        unsigned short* wt3_lo = wt3_hi + CH * CH;
        float* bcat = (float*)(wt3_lo + CH * CH);                  // 256 f32
        // sh/sl overlay xt region (xt fully consumed before sample writes).
        unsigned short* sh = xt_hi;
        unsigned short* sl = xt_lo;

        prep_kernel<<<dim3(XTBLK + 48), dim3(256), 0, stream>>>(
            x, xt_hi, xt_lo, w_out, wt_hi, wt_lo, w_in, wt3_hi, wt3_lo,
            w_off, w_mask, b_off, b_mask, wt2_hi, wt2_lo, bcat);
        dw_and_gemm_v<<<dim3(DWBLK + NBLKG), dim3(256), 0, stream>>>(
            xt_hi, xt_lo, dw_w, dw_b, ln_g, ln_b, fh, fl,
            wt3_hi, wt3_lo, b_in, v);
        gemm_omb<<<dim3(NBLKG), dim3(256), 0, stream>>>(
            fh, fl, wt2_hi, wt2_lo, bcat, omb);
        sample_kernel_omb_split<<<dim3(DWBLK), dim3(256), 0, stream>>>(v, omb, sh, sl);
        gemm_out_64x128<<<dim3(NBLKG), dim3(256), 0, stream>>>(
            sh, sl, wt_hi, wt_lo, b_out, bn_g, bn_b, bn_mean, bn_var, out);
    } else {
        // -------- fallback: round-5 verified path --------
        float* ws = (float*)d_ws;
        float* v    = ws;
        unsigned short* xt_hi = (unsigned short*)(v + SZ);
        unsigned short* xt_lo = xt_hi + SZ;
        unsigned short* fh    = xt_lo + SZ;
        unsigned short* fl    = fh + SZ;
        float* omb  = (float*)(fl + SZ);
        unsigned short* wt_hi  = (unsigned short*)(omb + SZ);
        unsigned short* wt_lo  = wt_hi + CH * CH;
        unsigned short* wt2_hi = wt_lo + CH * CH;
        unsigned short* wt2_lo = wt2_hi + CH * CH;
        unsigned short* wt3_hi = wt2_lo + CH * CH;
        unsigned short* wt3_lo = wt3_hi + CH * CH;
        float* bcat = (float*)(wt3_lo + CH * CH);
        unsigned short* sh = xt_hi;
        unsigned short* sl = xt_lo;

        wt_split_kernel<<<dim3(4, 4), dim3(256), 0, stream>>>(w_out, wt_hi, wt_lo);
        wt_split_kernel<<<dim3(4, 4), dim3(256), 0, stream>>>(w_in, wt3_hi, wt3_lo);
        wt2_split_kernel<<<dim3(16), dim3(256), 0, stream>>>(
            w_off, w_mask, b_off, b_mask, wt2_hi, wt2_lo, bcat);
        xt_split_kernel<<<dim3(HW/64, CH/64, BATCH), dim3(256), 0, stream>>>(x, xt_hi, xt_lo);
        gemm_in_mfma<<<dim3(MTOT/256, CH/64), dim3(256), 0, stream>>>(
            xt_hi, xt_lo, wt3_hi, wt3_lo, b_in, v);
        dw_ln_gelu_nhwc_split<<<dim3(DWBLK), dim3(256), 0, stream>>>(
            xt_hi, xt_lo, dw_w, dw_b, ln_g, ln_b, fh, fl);
        gemm_in_mfma<<<dim3(MTOT/256, CH/64), dim3(256), 0, stream>>>(
            fh, fl, wt2_hi, wt2_lo, bcat, omb);
        sample_kernel_omb_split<<<dim3(DWBLK), dim3(256), 0, stream>>>(v, omb, sh, sl);
        gemm_out_bf16<<<dim3(MTOT/256, CH/64), dim3(256), 0, stream>>>(
            sh, sl, wt_hi, wt_lo, b_out, bn_g, bn_b, bn_mean, bn_var, out);
    }
}

// Round 12
// 224.268 us; speedup vs baseline: 1.0438x; 1.0226x over previous
//
#include <hip/hip_runtime.h>
#include <math.h>

// Problem constants
#define BATCH 8
#define CH    256
#define HDIM  56
#define WDIM  56
#define HW    (HDIM*WDIM)          // 3136
#define MTOT  (BATCH*HW)           // 25088
#define GRP   8
#define GC    32
#define NP    9                    // K*K
#define NOFF  (GRP*NP*2)           // 144
#define NMSK  (GRP*NP)             // 72
#define NTOT  (NOFF+NMSK)          // 216
#define POSB  4                    // positions per sample block
#define DWBLK (MTOT/POSB)          // 6272
#define XTBLK (49*4*8)             // 1568 xt-split blocks
#define NBLKG ((MTOT/64)*2)        // 784: 392 m-tiles(64) x 2 n-tiles(128)

typedef float f32x4 __attribute__((ext_vector_type(4)));
typedef short s16x8 __attribute__((ext_vector_type(8)));

// split a,b into packed bf16 hi (truncation) and bf16 lo (exact remainder, truncated)
__device__ inline void split2(float a, float b, unsigned int& hp, unsigned int& lp)
{
    const unsigned int ua = __float_as_uint(a), ub = __float_as_uint(b);
    hp = (ub & 0xffff0000u) | (ua >> 16);
    const float ha = __uint_as_float(ua & 0xffff0000u);
    const float hb = __uint_as_float(ub & 0xffff0000u);
    const unsigned int la = __float_as_uint(a - ha), lb = __float_as_uint(b - hb);
    lp = (lb & 0xffff0000u) | (la >> 16);
}

// async global(16B/lane) -> LDS (wave-uniform base + lane*16)
__device__ __forceinline__ void gld_lds16(const unsigned short* g, unsigned short* l)
{
    __builtin_amdgcn_global_load_lds(
        (const __attribute__((address_space(1))) unsigned int*)g,
        (__attribute__((address_space(3))) unsigned int*)l, 16, 0, 0);
}

// ---------------------------------------------------------------------------
// 64m x 128n LDS-staged GEMM body (r10/r11-verified): 4 waves = 2m x 2n,
// per-wave 32m x 64n, acc[4][2]. global_load_lds width-16 staging, slot
// swizzle on both sides, 2-barrier k-loop.
// ---------------------------------------------------------------------------
__device__ __forceinline__ void gemm64x128_body(
    const unsigned short* __restrict__ ahi,
    const unsigned short* __restrict__ alo,
    const unsigned short* __restrict__ whi,
    const unsigned short* __restrict__ wlo,
    unsigned short* sAh, unsigned short* sAl,
    unsigned short* sBh, unsigned short* sBl,
    int m0, int n0g, int t, f32x4 (&acc)[4][2])
{
    const int lane = t & 63, wv4 = t >> 6;
    const int wm = wv4 >> 1;
    const int wn = wv4 & 1;
    const int fm = lane & 15, q = lane >> 4;

    const int arow0 = t >> 2;
    const int asl0  = (t & 3) ^ ((arow0 >> 1) & 3);
    const int albase0 = wv4 * 512;             // shorts; wave-uniform
    int brow[2], bsl[2], blbase[2];
    #pragma unroll
    for (int i = 0; i < 2; ++i) {
        const int u = i * 256 + t;
        brow[i] = u >> 2;
        bsl[i] = (u & 3) ^ ((brow[i] >> 1) & 3);
        blbase[i] = i * 2048 + wv4 * 512;
    }

    for (int kk = 0; kk < 8; ++kk) {
        const int k0 = kk * 32;
        {
            const size_t ga = (size_t)(m0 + arow0) * CH + k0 + asl0 * 8;
            gld_lds16(ahi + ga, sAh + albase0);
            gld_lds16(alo + ga, sAl + albase0);
        }
        #pragma unroll
        for (int i = 0; i < 2; ++i) {
            const size_t gb = (size_t)(n0g + brow[i]) * CH + k0 + bsl[i] * 8;
            gld_lds16(whi + gb, sBh + blbase[i]);
            gld_lds16(wlo + gb, sBl + blbase[i]);
        }
        __syncthreads();

        s16x8 ah[2], al[2], wh[4], wl[4];
        #pragma unroll
        for (int i = 0; i < 2; ++i) {
            const int ar = wm * 32 + i * 16 + fm;
            const int as = (q ^ ((ar >> 1) & 3)) * 8;
            ah[i] = *(const s16x8*)&sAh[ar * 32 + as];
            al[i] = *(const s16x8*)&sAl[ar * 32 + as];
        }
        #pragma unroll
        for (int i = 0; i < 4; ++i) {
            const int br = wn * 64 + i * 16 + fm;
            const int bs = (q ^ ((br >> 1) & 3)) * 8;
            wh[i] = *(const s16x8*)&sBh[br * 32 + bs];
            wl[i] = *(const s16x8*)&sBl[br * 32 + bs];
        }
        #pragma unroll
        for (int nt = 0; nt < 4; ++nt)
            #pragma unroll
            for (int mt = 0; mt < 2; ++mt) {
                acc[nt][mt] = __builtin_amdgcn_mfma_f32_16x16x32_bf16(wh[nt], ah[mt], acc[nt][mt], 0, 0, 0);
                acc[nt][mt] = __builtin_amdgcn_mfma_f32_16x16x32_bf16(wh[nt], al[mt], acc[nt][mt], 0, 0, 0);
                acc[nt][mt] = __builtin_amdgcn_mfma_f32_16x16x32_bf16(wl[nt], ah[mt], acc[nt][mt], 0, 0, 0);
            }
        __syncthreads();
    }
}

// ---------------------------------------------------------------------------
// PREP: xt_split (1568 blocks) + wt_split(w_out) + wt_split(w_in) +
// wt2_split(+bcat), fused by block-uniform bid branch. (r11-verified)
// ---------------------------------------------------------------------------
__global__ __launch_bounds__(256)
void prep_kernel(const float* __restrict__ x,
                 unsigned short* __restrict__ xt_hi,
                 unsigned short* __restrict__ xt_lo,
                 const float* __restrict__ w_out,
                 unsigned short* __restrict__ wt_hi,
                 unsigned short* __restrict__ wt_lo,
                 const float* __restrict__ w_in,
                 unsigned short* __restrict__ wt3_hi,
                 unsigned short* __restrict__ wt3_lo,
                 const float* __restrict__ w_off,
                 const float* __restrict__ w_mask,
                 const float* __restrict__ b_off,
                 const float* __restrict__ b_mask,
                 unsigned short* __restrict__ wt2_hi,
                 unsigned short* __restrict__ wt2_lo,
                 float* __restrict__ bcat)
{
    __shared__ float lds[64][68];
    const int bid = blockIdx.x;
    const int t = threadIdx.x;

    if (bid < XTBLK) {
        const int hw0 = (bid % 49) * 64;
        const int k0  = ((bid / 49) % 4) * 64;
        const int b   = bid / 196;
        #pragma unroll
        for (int p = 0; p < 4; ++p) {
            const int kr = (t >> 4) + p * 16;
            const int hc = (t & 15) * 4;
            *(float4*)&lds[kr][hc] =
                *(const float4*)(x + ((size_t)b * CH + k0 + kr) * HW + hw0 + hc);
        }
        __syncthreads();
        const int ml = t >> 2;
        const int kc = (t & 3) * 16;
        unsigned int hbuf[8], lbuf[8];
        #pragma unroll
        for (int j = 0; j < 16; j += 2)
            split2(lds[kc + j][ml], lds[kc + j + 1][ml], hbuf[j >> 1], lbuf[j >> 1]);
        const size_t row = (size_t)(b * HW + hw0 + ml) * CH + k0 + kc;
        *(uint4*)&xt_hi[row]     = *(uint4*)&hbuf[0];
        *(uint4*)&xt_hi[row + 8] = *(uint4*)&hbuf[4];
        *(uint4*)&xt_lo[row]     = *(uint4*)&lbuf[0];
        *(uint4*)&xt_lo[row + 8] = *(uint4*)&lbuf[4];
    } else if (bid < XTBLK + 32) {
        const int u = bid - XTBLK;
        const float* w = (u < 16) ? w_out : w_in;
        unsigned short* hi = (u < 16) ? wt_hi : wt3_hi;
        unsigned short* lo = (u < 16) ? wt_lo : wt3_lo;
        const int uu = u & 15;
        const int kt = (uu & 3) * 64, nt = (uu >> 2) * 64;
        #pragma unroll
        for (int p = 0; p < 4; ++p) {
            const int kr = (t >> 4) + p * 16, nc = (t & 15) * 4;
            *(float4*)&lds[kr][nc] = *(const float4*)(w + (size_t)(kt + kr) * CH + nt + nc);
        }
        __syncthreads();
        const int nl = t >> 2, kc = (t & 3) * 16;
        #pragma unroll
        for (int j = 0; j < 16; j += 2) {
            const float f0 = lds[kc + j][nl], f1 = lds[kc + j + 1][nl];
            unsigned int hp, lp;
            split2(f0, f1, hp, lp);
            *(unsigned int*)&hi[(size_t)(nt + nl) * CH + kt + kc + j] = hp;
            *(unsigned int*)&lo[(size_t)(nt + nl) * CH + kt + kc + j] = lp;
        }
    } else {
        const int u = bid - XTBLK - 32;    // 0..15
        const int n = t;
        if (u == 0) {
            bcat[n] = (n < NOFF) ? b_off[n] : ((n < NTOT) ? b_mask[n - NOFF] : 0.0f);
        }
        const int k0 = u * 16;
        #pragma unroll
        for (int j = 0; j < 16; j += 2) {
            const int k = k0 + j;
            float f0 = 0.0f, f1 = 0.0f;
            if (n < NOFF) {
                f0 = w_off[(size_t)k * NOFF + n];
                f1 = w_off[(size_t)(k + 1) * NOFF + n];
            } else if (n < NTOT) {
                f0 = w_mask[(size_t)k * NMSK + (n - NOFF)];
                f1 = w_mask[(size_t)(k + 1) * NMSK + (n - NOFF)];
            }
            unsigned int hp, lp;
            split2(f0, f1, hp, lp);
            *(unsigned int*)&wt2_hi[(size_t)n * CH + k] = hp;
            *(unsigned int*)&wt2_lo[(size_t)n * CH + k] = lp;
        }
    }
}

// ---------------------------------------------------------------------------
// dw solo (r5-verified structure): per-position wave, NHWC bf16 hi/lo xt ->
// pre-split fh/fl. 12.3 KB LDS for best occupancy (r11 lesson: the 24.5 KB
// union of the co-dispatch degraded it).
// ---------------------------------------------------------------------------
__global__ __launch_bounds__(256)
void dw_ln_gelu_nhwc_split(const unsigned short* __restrict__ xhi,
                           const unsigned short* __restrict__ xlo,
                           const float* __restrict__ dw_w,
                           const float* __restrict__ dw_b,
                           const float* __restrict__ ln_g,
                           const float* __restrict__ ln_b,
                           unsigned short* __restrict__ fh,
                           unsigned short* __restrict__ fl)
{
    __shared__ float wt[NP][CH];
    __shared__ float lbias[CH], lgam[CH], lbet[CH];
    const int t = threadIdx.x;
    {
        const float* wp = dw_w + t * NP;
        #pragma unroll
        for (int p = 0; p < NP; ++p) wt[p][t] = wp[p];
        lbias[t] = dw_b[t]; lgam[t] = ln_g[t]; lbet[t] = ln_b[t];
    }
    __syncthreads();

    const int per  = DWBLK / 8;
    const int bid  = blockIdx.x;
    const int sw   = (bid & 7) * per + (bid >> 3);
    const int q    = t >> 6, lane = t & 63;
    const int n    = sw * POSB + q;
    const int b    = n / HW;
    const int hw   = n % HW;
    const int h    = hw / WDIM, w = hw % WDIM;
    const int c4   = lane * 4;
    const size_t base = (size_t)b * HW * CH + c4;

    float ax = 0.0f, ay = 0.0f, az = 0.0f, aw = 0.0f;
    #pragma unroll
    for (int p = 0; p < NP; ++p) {
        const int hh = h + p / 3 - 1;
        const int ww = w + p % 3 - 1;
        if ((unsigned)hh >= (unsigned)HDIM || (unsigned)ww >= (unsigned)WDIM)
            continue;                       // wave-uniform branch (h,w per-wave)
        const size_t idx = base + (size_t)(hh * WDIM + ww) * CH;
        const ushort4 uh = *(const ushort4*)(xhi + idx);
        const ushort4 ul = *(const ushort4*)(xlo + idx);
        const float4 wv = *(const float4*)&wt[p][c4];
        ax = fmaf(__uint_as_float((unsigned)uh.x << 16), wv.x,
             fmaf(__uint_as_float((unsigned)ul.x << 16), wv.x, ax));
        ay = fmaf(__uint_as_float((unsigned)uh.y << 16), wv.y,
             fmaf(__uint_as_float((unsigned)ul.y << 16), wv.y, ay));
        az = fmaf(__uint_as_float((unsigned)uh.z << 16), wv.z,
             fmaf(__uint_as_float((unsigned)ul.z << 16), wv.z, az));
        aw = fmaf(__uint_as_float((unsigned)uh.w << 16), wv.w,
             fmaf(__uint_as_float((unsigned)ul.w << 16), wv.w, aw));
    }
    {
        const float4 b4 = *(const float4*)&lbias[c4];
        ax += b4.x; ay += b4.y; az += b4.z; aw += b4.w;
    }
    float s1 = ax + ay + az + aw;
    float s2 = ax*ax + ay*ay + az*az + aw*aw;
    #pragma unroll
    for (int off = 32; off > 0; off >>= 1) {
        s1 += __shfl_xor(s1, off);
        s2 += __shfl_xor(s2, off);
    }
    const float mean = s1 * (1.0f / 256.0f);
    const float rstd = rsqrtf(s2 * (1.0f / 256.0f) - mean * mean + 1e-5f);
    const float4 g4 = *(const float4*)&lgam[c4];
    const float4 e4 = *(const float4*)&lbet[c4];
    const float x0 = (ax - mean) * rstd * g4.x + e4.x;
    const float x1 = (ay - mean) * rstd * g4.y + e4.y;
    const float x2 = (az - mean) * rstd * g4.z + e4.z;
    const float x3 = (aw - mean) * rstd * g4.w + e4.w;
    const float o0 = 0.5f * x0 * (1.0f + erff(x0 * 0.70710678118654752f));
    const float o1 = 0.5f * x1 * (1.0f + erff(x1 * 0.70710678118654752f));
    const float o2 = 0.5f * x2 * (1.0f + erff(x2 * 0.70710678118654752f));
    const float o3 = 0.5f * x3 * (1.0f + erff(x3 * 0.70710678118654752f));
    unsigned int hp0, lp0, hp1, lp1;
    split2(o0, o1, hp0, lp0);
    split2(o2, o3, hp1, lp1);
    *(uint2*)&fh[(size_t)n * CH + c4] = make_uint2(hp0, hp1);
    *(uint2*)&fl[(size_t)n * CH + c4] = make_uint2(lp0, lp1);
}

// ---------------------------------------------------------------------------
// DUAL GEMM after dw: both middle projections in ONE dispatch at the proven
// 12-waves/CU regime (1568 homogeneous blocks of the 64x128 body).
// bid<NBLKG: v = xt @ w_in; else: omb = f @ wt2.
// ---------------------------------------------------------------------------
__global__ __launch_bounds__(256)
void gemm_dual64(const unsigned short* __restrict__ ahi1,
                 const unsigned short* __restrict__ alo1,
                 const unsigned short* __restrict__ whi1,
                 const unsigned short* __restrict__ wlo1,
                 const float* __restrict__ bias1,
                 float* __restrict__ out1,
                 const unsigned short* __restrict__ ahi2,
                 const unsigned short* __restrict__ alo2,
                 const unsigned short* __restrict__ whi2,
                 const unsigned short* __restrict__ wlo2,
                 const float* __restrict__ bias2,
                 float* __restrict__ out2)
{
    __shared__ unsigned short sAh[64*32], sAl[64*32], sBh[128*32], sBl[128*32];

    const int half = blockIdx.x >= NBLKG;
    const int lbid = blockIdx.x - (half ? NBLKG : 0);
    const unsigned short* ahi = half ? ahi2 : ahi1;
    const unsigned short* alo = half ? alo2 : alo1;
    const unsigned short* whi = half ? whi2 : whi1;
    const unsigned short* wlo = half ? wlo2 : wlo1;
    const float* bias = half ? bias2 : bias1;
    float* out = half ? out2 : out1;

    const int sw = (lbid & 7) * (NBLKG / 8) + (lbid >> 3);   // bijective 784=8*98
    const int m0  = (sw >> 1) * 64;
    const int n0g = (sw & 1) * 128;
    const int t = threadIdx.x;
    const int lane = t & 63, wv4 = t >> 6;
    const int wm = wv4 >> 1, wn = wv4 & 1;
    const int fm = lane & 15, q = lane >> 4;

    f32x4 acc[4][2];
    const f32x4 zero = {0.0f, 0.0f, 0.0f, 0.0f};
    #pragma unroll
    for (int i = 0; i < 4; ++i)
        #pragma unroll
        for (int j = 0; j < 2; ++j) acc[i][j] = zero;

    gemm64x128_body(ahi, alo, whi, wlo, sAh, sAl, sBh, sBl, m0, n0g, t, acc);

    #pragma unroll
    for (int nt = 0; nt < 4; ++nt) {
        const int n = n0g + wn*64 + nt*16 + q*4;
        const float4 b4 = *(const float4*)&bias[n];
        #pragma unroll
        for (int mt = 0; mt < 2; ++mt) {
            const int mm = m0 + wm*32 + mt*16 + fm;
            f32x4 o = acc[nt][mt];
            o[0] += b4.x; o[1] += b4.y; o[2] += b4.z; o[3] += b4.w;
            *(f32x4*)&out[(size_t)mm * CH + n] = o;
        }
    }
}

// ---------------------------------------------------------------------------
// Output GEMM, 64m x 128n tiles (r10-verified): BN+SiLU NCHW epilogue.
// ---------------------------------------------------------------------------
__global__ __launch_bounds__(256)
void gemm_out_64x128(const unsigned short* __restrict__ ahi,
                     const unsigned short* __restrict__ alo,
                     const unsigned short* __restrict__ whi,
                     const unsigned short* __restrict__ wlo,
                     const float* __restrict__ bias,
                     const float* __restrict__ bn_g,
                     const float* __restrict__ bn_b,
                     const float* __restrict__ bn_mean,
                     const float* __restrict__ bn_var,
                     float* __restrict__ y)                  // [B,256,3136]
{
    __shared__ unsigned short sAh[64*32], sAl[64*32], sBh[128*32], sBl[128*32];

    const int sw = (blockIdx.x & 7) * (NBLKG / 8) + (blockIdx.x >> 3);
    const int m0  = (sw >> 1) * 64;
    const int n0g = (sw & 1) * 128;
    const int t = threadIdx.x;
    const int lane = t & 63, wv4 = t >> 6;
    const int wm = wv4 >> 1, wn = wv4 & 1;
    const int fm = lane & 15, q = lane >> 4;

    f32x4 acc[4][2];
    const f32x4 zero = {0.0f, 0.0f, 0.0f, 0.0f};
    #pragma unroll
    for (int i = 0; i < 4; ++i)
        #pragma unroll
        for (int j = 0; j < 2; ++j) acc[i][j] = zero;

    gemm64x128_body(ahi, alo, whi, wlo, sAh, sAl, sBh, sBl, m0, n0g, t, acc);

    #pragma unroll
    for (int nt = 0; nt < 4; ++nt) {
        #pragma unroll
        for (int r = 0; r < 4; ++r) {
            const int n = n0g + wn*64 + nt*16 + q*4 + r;
            const float sc = bn_g[n] * rsqrtf(bn_var[n] + 1e-5f);
            const float sb = bn_b[n] - bn_mean[n] * sc;
            const float bs = bias[n];
            #pragma unroll
            for (int mt = 0; mt < 2; ++mt) {
                const int mm = m0 + wm*32 + mt*16 + fm;
                const int bimg = mm / HW, hw = mm % HW;
                float val = (acc[nt][mt][r] + bs) * sc + sb;
                y[(size_t)bimg * CH * HW + (size_t)n * HW + hw] = val / (1.0f + expf(-val));
            }
        }
    }
}

// ---------------------------------------------------------------------------
// Deformable sampling reading the padded omb [MTOT][256] rows
// (cols 0..143 offsets, 144..215 mask logits). Output s PRE-SPLIT bf16 hi/lo.
// ---------------------------------------------------------------------------
__global__ __launch_bounds__(256)
void sample_kernel_omb_split(const float* __restrict__ v,
                             const float* __restrict__ omb,
                             unsigned short* __restrict__ sh,  // [MTOT][256]
                             unsigned short* __restrict__ sl)  // [MTOT][256]
{
    __shared__ alignas(16) float loff[POSB][NOFF];
    __shared__ alignas(16) float lmsk[POSB][NMSK];
    __shared__ alignas(16) float wtab[POSB][GRP*NP][4];
    __shared__ alignas(16) int   itab[POSB][GRP*NP][4];

    const int per  = DWBLK / 8;              // 784
    const int bid  = blockIdx.x;
    const int sw   = (bid % 8) * per + (bid / 8);
    const int n0 = sw * POSB;
    const int t = threadIdx.x;

    if (t < POSB * (NOFF/4)) {
        const int q = t / (NOFF/4), r = t % (NOFF/4);
        *(float4*)&loff[q][r*4] = *(const float4*)&omb[(size_t)(n0+q)*CH + r*4];
    } else if (t < POSB * (NOFF/4) + POSB * (NMSK/4)) {
        const int u = t - POSB * (NOFF/4);
        const int q = u / (NMSK/4), r = u % (NMSK/4);
        *(float4*)&lmsk[q][r*4] = *(const float4*)&omb[(size_t)(n0+q)*CH + NOFF + r*4];
    }
    __syncthreads();

    if (t < POSB * GRP) {
        const int q = t >> 3, g = t & 7;
        float* mm = &lmsk[q][g * NP];
        float mx = -1e30f;
        #pragma unroll
        for (int p = 0; p < NP; ++p) mx = fmaxf(mx, mm[p]);
        float sum = 0.0f;
        #pragma unroll
        for (int p = 0; p < NP; ++p) { const float e = __expf(mm[p] - mx); mm[p] = e; sum += e; }
        const float inv = 1.0f / sum;
        #pragma unroll
        for (int p = 0; p < NP; ++p) mm[p] *= inv;
    }
    __syncthreads();

    for (int u = t; u < POSB * GRP * NP; u += 256) {
        const int q = u / (GRP*NP), j = u % (GRP*NP);
        const int g = j / NP, p = j % NP;
        const int n = n0 + q;
        const int hw = n % HW;
        const int h = hw / WDIM, w = hw % WDIM;
        const float ox = loff[q][g*18 + p*2 + 0];
        const float oy = loff[q][g*18 + p*2 + 1];
        const float m  = lmsk[q][g*NP + p];
        const float px = (float)(w + p/3) + ox;
        const float py = (float)(h + p%3) + oy;
        const float fx = floorf(px), fy = floorf(py);
        const float wx = px - fx, wy = py - fy;
        const int x0 = (int)fx, y0 = (int)fy;
        const int x1 = x0 + 1, y1 = y0 + 1;
        const float vx0 = (x0 >= 1 && x0 < 57) ? 1.0f : 0.0f;
        const float vx1 = (x1 >= 1 && x1 < 57) ? 1.0f : 0.0f;
        const float vy0 = (y0 >= 1 && y0 < 57) ? 1.0f : 0.0f;
        const float vy1 = (y1 >= 1 && y1 < 57) ? 1.0f : 0.0f;
        const int x0c = min(max(x0, 1), 56), x1c = min(max(x1, 1), 56);
        const int y0c = min(max(y0, 1), 56), y1c = min(max(y1, 1), 56);
        wtab[q][j][0] = m * (1.0f-wx) * (1.0f-wy) * vx0 * vy0;
        wtab[q][j][1] = m * wx        * (1.0f-wy) * vx1 * vy0;
        wtab[q][j][2] = m * (1.0f-wx) * wy        * vx0 * vy1;
        wtab[q][j][3] = m * wx        * wy        * vx1 * vy1;
        itab[q][j][0] = ((y0c-1)*WDIM + (x0c-1)) * CH;
        itab[q][j][1] = ((y0c-1)*WDIM + (x1c-1)) * CH;
        itab[q][j][2] = ((y1c-1)*WDIM + (x0c-1)) * CH;
        itab[q][j][3] = ((y1c-1)*WDIM + (x1c-1)) * CH;
    }
    __syncthreads();

    const int q = t >> 6, lane = t & 63;
    const int n = n0 + q;
    const int b = n / HW;
    const int g = lane >> 3;
    const float* vb = v + (size_t)b*HW*CH + lane*4;
    float4 acc = {0.0f, 0.0f, 0.0f, 0.0f};
    #pragma unroll
    for (int p = 0; p < NP; ++p) {
        const int j = g*NP + p;
        const float4 wv = *(const float4*)&wtab[q][j][0];
        const int4  iv = *(const int4*)&itab[q][j][0];
        const float4 c0 = *(const float4*)(vb + iv.x);
        const float4 c1 = *(const float4*)(vb + iv.y);
        const float4 c2 = *(const float4*)(vb + iv.z);
        const float4 c3 = *(const float4*)(vb + iv.w);
        acc.x += wv.x*c0.x + wv.y*c1.x + wv.z*c2.x + wv.w*c3.x;
        acc.y += wv.x*c0.y + wv.y*c1.y + wv.z*c2.y + wv.w*c3.y;
        acc.z += wv.x*c0.z + wv.y*c1.z + wv.z*c2.z + wv.w*c3.z;
        acc.w += wv.x*c0.w + wv.y*c1.w + wv.z*c2.w + wv.w*c3.w;
    }
    unsigned int hp0, lp0, hp1, lp1;
    split2(acc.x, acc.y, hp0, lp0);
    split2(acc.z, acc.w, hp1, lp1);
    *(uint2*)&sh[(size_t)n*CH + lane*4] = make_uint2(hp0, hp1);
    *(uint2*)&sl[(size_t)n*CH + lane*4] = make_uint2(lp0, lp1);
}

// ===================== FALLBACK KERNELS (round-5 verified) =====================
__global__ __launch_bounds__(256)
void xt_split_kernel(const float* __restrict__ x,
                     unsigned short* __restrict__ hi,
                     unsigned short* __restrict__ lo)
{
    __shared__ float lds[64][68];
    const int hw0 = blockIdx.x * 64;
    const int k0  = blockIdx.y * 64;
    const int b   = blockIdx.z;
    const int t = threadIdx.x;
    #pragma unroll
    for (int p = 0; p < 4; ++p) {
        const int kr = (t >> 4) + p * 16;
        const int hc = (t & 15) * 4;
        *(float4*)&lds[kr][hc] =
            *(const float4*)(x + ((size_t)b * CH + k0 + kr) * HW + hw0 + hc);
    }
    __syncthreads();
    const int ml = t >> 2;
    const int kc = (t & 3) * 16;
    unsigned int hbuf[8], lbuf[8];
    #pragma unroll
    for (int j = 0; j < 16; j += 2)
        split2(lds[kc + j][ml], lds[kc + j + 1][ml], hbuf[j >> 1], lbuf[j >> 1]);
    const size_t row = (size_t)(b * HW + hw0 + ml) * CH + k0 + kc;
    *(uint4*)&hi[row]     = *(uint4*)&hbuf[0];
    *(uint4*)&hi[row + 8] = *(uint4*)&hbuf[4];
    *(uint4*)&lo[row]     = *(uint4*)&lbuf[0];
    *(uint4*)&lo[row + 8] = *(uint4*)&lbuf[4];
}

__global__ __launch_bounds__(256)
void wt_split_kernel(const float* __restrict__ w,
                     unsigned short* __restrict__ hi,
                     unsigned short* __restrict__ lo)
{
    __shared__ float lds[64][68];
    const int kt = blockIdx.x * 64, nt = blockIdx.y * 64;
    const int t = threadIdx.x;
    #pragma unroll
    for (int p = 0; p < 4; ++p) {
        const int kr = (t >> 4) + p * 16, nc = (t & 15) * 4;
        *(float4*)&lds[kr][nc] = *(const float4*)(w + (size_t)(kt + kr) * CH + nt + nc);
    }
    __syncthreads();
    const int nl = t >> 2, kc = (t & 3) * 16;
    #pragma unroll
    for (int j = 0; j < 16; j += 2) {
        const float f0 = lds[kc + j][nl], f1 = lds[kc + j + 1][nl];
        unsigned int hp, lp;
        split2(f0, f1, hp, lp);
        *(unsigned int*)&hi[(size_t)(nt + nl) * CH + kt + kc + j] = hp;
        *(unsigned int*)&lo[(size_t)(nt + nl) * CH + kt + kc + j] = lp;
    }
}

__global__ __launch_bounds__(256)
void wt2_split_kernel(const float* __restrict__ w_off,
                      const float* __restrict__ w_mask,
                      const float* __restrict__ b_off,
                      const float* __restrict__ b_mask,
                      unsigned short* __restrict__ hi,
                      unsigned short* __restrict__ lo,
                      float* __restrict__ bcat)
{
    const int n = threadIdx.x;
    if (blockIdx.x == 0) {
        bcat[n] = (n < NOFF) ? b_off[n] : ((n < NTOT) ? b_mask[n - NOFF] : 0.0f);
    }
    const int k0 = blockIdx.x * 16;
    #pragma unroll
    for (int j = 0; j < 16; j += 2) {
        const int k = k0 + j;
        float f0 = 0.0f, f1 = 0.0f;
        if (n < NOFF) {
            f0 = w_off[(size_t)k * NOFF + n];
            f1 = w_off[(size_t)(k + 1) * NOFF + n];
        } else if (n < NTOT) {
            f0 = w_mask[(size_t)k * NMSK + (n - NOFF)];
            f1 = w_mask[(size_t)(k + 1) * NMSK + (n - NOFF)];
        }
        unsigned int hp, lp;
        split2(f0, f1, hp, lp);
        *(unsigned int*)&hi[(size_t)n * CH + k] = hp;
        *(unsigned int*)&lo[(size_t)n * CH + k] = lp;
    }
}

__global__ __launch_bounds__(256)
void gemm_in_mfma(const unsigned short* __restrict__ xhi,
                  const unsigned short* __restrict__ xlo,
                  const unsigned short* __restrict__ whi,
                  const unsigned short* __restrict__ wlo,
                  const float* __restrict__ bias,
                  float* __restrict__ v)
{
    const int m0 = blockIdx.x * 256;
    const int n0 = blockIdx.y * 64;
    const int t = threadIdx.x;
    const int lane = t & 63, wv = t >> 6;
    const int mblk = m0 + wv * 64;
    const int fm = lane & 15;
    const int q  = lane >> 4;

    f32x4 acc[4][4];
    const f32x4 zero = {0.0f, 0.0f, 0.0f, 0.0f};
    #pragma unroll
    for (int i = 0; i < 4; ++i)
        #pragma unroll
        for (int j = 0; j < 4; ++j) acc[i][j] = zero;

    const unsigned short *xrh[4], *xrl[4], *wrh[4], *wrl[4];
    #pragma unroll
    for (int mt = 0; mt < 4; ++mt) {
        xrh[mt] = xhi + (size_t)(mblk + mt*16 + fm) * CH + q * 8;
        xrl[mt] = xlo + (size_t)(mblk + mt*16 + fm) * CH + q * 8;
    }
    #pragma unroll
    for (int nt = 0; nt < 4; ++nt) {
        wrh[nt] = whi + (size_t)(n0 + nt*16 + fm) * CH + q * 8;
        wrl[nt] = wlo + (size_t)(n0 + nt*16 + fm) * CH + q * 8;
    }

    for (int k0 = 0; k0 < CH; k0 += 32) {
        s16x8 wh[4], wl[4], ah[4], al[4];
        #pragma unroll
        for (int nt = 0; nt < 4; ++nt) {
            wh[nt] = *(const s16x8*)(wrh[nt] + k0);
            wl[nt] = *(const s16x8*)(wrl[nt] + k0);
        }
        #pragma unroll
        for (int mt = 0; mt < 4; ++mt) {
            ah[mt] = *(const s16x8*)(xrh[mt] + k0);
            al[mt] = *(const s16x8*)(xrl[mt] + k0);
        }
        #pragma unroll
        for (int nt = 0; nt < 4; ++nt)
            #pragma unroll
            for (int mt = 0; mt < 4; ++mt) {
                acc[nt][mt] = __builtin_amdgcn_mfma_f32_16x16x32_bf16(wh[nt], ah[mt], acc[nt][mt], 0, 0, 0);
                acc[nt][mt] = __builtin_amdgcn_mfma_f32_16x16x32_bf16(wh[nt], al[mt], acc[nt][mt], 0, 0, 0);
                acc[nt][mt] = __builtin_amdgcn_mfma_f32_16x16x32_bf16(wl[nt], ah[mt], acc[nt][mt], 0, 0, 0);
            }
    }

    #pragma unroll
    for (int nt = 0; nt < 4; ++nt) {
        const float4 b4 = *(const float4*)&bias[n0 + nt*16 + q*4];
        #pragma unroll
        for (int mt = 0; mt < 4; ++mt) {
            f32x4 o = acc[nt][mt];
            o[0] += b4.x; o[1] += b4.y; o[2] += b4.z; o[3] += b4.w;
            *(f32x4*)&v[(size_t)(mblk + mt*16 + fm) * CH + n0 + nt*16 + q*4] = o;
        }
    }
}

__global__ __launch_bounds__(256)
void gemm_out_bf16(const unsigned short* __restrict__ shp,
                   const unsigned short* __restrict__ slp,
                   const unsigned short* __restrict__ whi,
                   const unsigned short* __restrict__ wlo,
                   const float* __restrict__ bias,
                   const float* __restrict__ bn_g,
                   const float* __restrict__ bn_b,
                   const float* __restrict__ bn_mean,
                   const float* __restrict__ bn_var,
                   float* __restrict__ y)
{
    const int m0 = blockIdx.x * 256;
    const int n0 = blockIdx.y * 64;
    const int t = threadIdx.x;
    const int lane = t & 63, wv = t >> 6;
    const int mblk = m0 + wv * 64;
    const int fm = lane & 15;
    const int q  = lane >> 4;

    f32x4 acc[4][4];
    const f32x4 zero = {0.0f, 0.0f, 0.0f, 0.0f};
    #pragma unroll
    for (int i = 0; i < 4; ++i)
        #pragma unroll
        for (int j = 0; j < 4; ++j) acc[i][j] = zero;

    const unsigned short *xrh[4], *xrl[4], *wrh[4], *wrl[4];
    #pragma unroll
    for (int mt = 0; mt < 4; ++mt) {
        xrh[mt] = shp + (size_t)(mblk + mt*16 + fm) * CH + q * 8;
        xrl[mt] = slp + (size_t)(mblk + mt*16 + fm) * CH + q * 8;
    }
    #pragma unroll
    for (int nt = 0; nt < 4; ++nt) {
        wrh[nt] = whi + (size_t)(n0 + nt*16 + fm) * CH + q * 8;
        wrl[nt] = wlo + (size_t)(n0 + nt*16 + fm) * CH + q * 8;
    }

    for (int k0 = 0; k0 < CH; k0 += 32) {
        s16x8 wh[4], wl[4], ah[4], al[4];
        #pragma unroll
        for (int nt = 0; nt < 4; ++nt) {
            wh[nt] = *(const s16x8*)(wrh[nt] + k0);
            wl[nt] = *(const s16x8*)(wrl[nt] + k0);
        }
        #pragma unroll
        for (int mt = 0; mt < 4; ++mt) {
            ah[mt] = *(const s16x8*)(xrh[mt] + k0);
            al[mt] = *(const s16x8*)(xrl[mt] + k0);
        }
        #pragma unroll
        for (int nt = 0; nt < 4; ++nt)
            #pragma unroll
            for (int mt = 0; mt < 4; ++mt) {
                acc[nt][mt] = __builtin_amdgcn_mfma_f32_16x16x32_bf16(wh[nt], ah[mt], acc[nt][mt], 0, 0, 0);
                acc[nt][mt] = __builtin_amdgcn_mfma_f32_16x16x32_bf16(wh[nt], al[mt], acc[nt][mt], 0, 0, 0);
                acc[nt][mt] = __builtin_amdgcn_mfma_f32_16x16x32_bf16(wl[nt], ah[mt], acc[nt][mt], 0, 0, 0);
            }
    }

    #pragma unroll
    for (int nt = 0; nt < 4; ++nt) {
        #pragma unroll
        for (int r = 0; r < 4; ++r) {
            const int n = n0 + nt*16 + q*4 + r;
            const float sc = bn_g[n] * rsqrtf(bn_var[n] + 1e-5f);
            const float sb = bn_b[n] - bn_mean[n] * sc;
            const float bs = bias[n];
            #pragma unroll
            for (int mt = 0; mt < 4; ++mt) {
                const int mm = mblk + mt*16;
                const size_t base = (size_t)(mm / HW) * CH * HW + (mm % HW);
                float val = (acc[nt][mt][r] + bs) * sc + sb;
                y[base + (size_t)n * HW + fm] = val / (1.0f + expf(-val));
            }
        }
    }
}

extern "C" void kernel_launch(void* const* d_in, const int* in_sizes, int n_in,
                              void* d_out, int out_size, void* d_ws, size_t ws_size,
                              hipStream_t stream) {
    const float* x      = (const float*)d_in[0];
    const float* w_in   = (const float*)d_in[1];
    const float* b_in   = (const float*)d_in[2];
    const float* dw_w   = (const float*)d_in[3];
    const float* dw_b   = (const float*)d_in[4];
    const float* ln_g   = (const float*)d_in[5];
    const float* ln_b   = (const float*)d_in[6];
    const float* w_off  = (const float*)d_in[7];
    const float* b_off  = (const float*)d_in[8];
    const float* w_mask = (const float*)d_in[9];
    const float* b_mask = (const float*)d_in[10];
    const float* w_out  = (const float*)d_in[11];
    const float* b_out  = (const float*)d_in[12];
    const float* bn_g   = (const float*)d_in[13];
    const float* bn_b   = (const float*)d_in[14];
    const float* bn_mean= (const float*)d_in[15];
    const float* bn_var = (const float*)d_in[16];
    float* out = (float*)d_out;

    const size_t SZ = (size_t)MTOT * CH;                 // elements
    // Layout: v | xt_hi,xt_lo | fh,fl | omb | weights | bcat
    const size_t need_new =
        4 * SZ * sizeof(float)
        + 6 * (size_t)CH * CH * sizeof(unsigned short)
        + CH * sizeof(float);

    if (ws_size >= need_new) {
        // -------- main path: 5 dispatches --------
        float* ws = (float*)d_ws;
        float* v    = ws;                                          // SZ f32
        unsigned short* xt_hi = (unsigned short*)(v + SZ);         // SZ us
        unsigned short* xt_lo = xt_hi + SZ;                        // SZ us
        unsigned short* fh    = xt_lo + SZ;                        // SZ us
        unsigned short* fl    = fh + SZ;                           // SZ us
        float* omb  = (float*)(fl + SZ);                           // SZ f32
        unsigned short* wt_hi  = (unsigned short*)(omb + SZ);
        unsigned short* wt_lo  = wt_hi + CH * CH;
        unsigned short* wt2_hi = wt_lo + CH * CH;
        unsigned short* wt2_lo = wt2_hi + CH * CH;
        unsigned short* wt3_hi = wt2_lo + CH * CH;
        unsigned short* wt3_lo = wt3_hi + CH * CH;
        float* bcat = (float*)(wt3_lo + CH * CH);                  // 256 f32
        // sh/sl overlay xt region (xt fully consumed before sample writes).
        unsigned short* sh = xt_hi;
        unsigned short* sl = xt_lo;

        prep_kernel<<<dim3(XTBLK + 48), dim3(256), 0, stream>>>(
            x, xt_hi, xt_lo, w_out, wt_hi, wt_lo, w_in, wt3_hi, wt3_lo,
            w_off, w_mask, b_off, b_mask, wt2_hi, wt2_lo, bcat);
        dw_ln_gelu_nhwc_split<<<dim3(DWBLK), dim3(256), 0, stream>>>(
            xt_hi, xt_lo, dw_w, dw_b, ln_g, ln_b, fh, fl);
        // Both middle projections in ONE dispatch at the proven regime:
        gemm_dual64<<<dim3(2 * NBLKG), dim3(256), 0, stream>>>(
            xt_hi, xt_lo, wt3_hi, wt3_lo, b_in, v,
            fh, fl, wt2_hi, wt2_lo, bcat, omb);
        sample_kernel_omb_split<<<dim3(DWBLK), dim3(256), 0, stream>>>(v, omb, sh, sl);
        gemm_out_64x128<<<dim3(NBLKG), dim3(256), 0, stream>>>(
            sh, sl, wt_hi, wt_lo, b_out, bn_g, bn_b, bn_mean, bn_var, out);
    } else {
        // -------- fallback: round-5 verified path --------
        float* ws = (float*)d_ws;
        float* v    = ws;
        unsigned short* xt_hi = (unsigned short*)(v + SZ);
        unsigned short* xt_lo = xt_hi + SZ;
        unsigned short* fh    = xt_lo + SZ;
        unsigned short* fl    = fh + SZ;
        float* omb  = (float*)(fl + SZ);
        unsigned short* wt_hi  = (unsigned short*)(omb + SZ);
        unsigned short* wt_lo  = wt_hi + CH * CH;
        unsigned short* wt2_hi = wt_lo + CH * CH;
        unsigned short* wt2_lo = wt2_hi + CH * CH;
        unsigned short* wt3_hi = wt2_lo + CH * CH;
        unsigned short* wt3_lo = wt3_hi + CH * CH;
        float* bcat = (float*)(wt3_lo + CH * CH);
        unsigned short* sh = xt_hi;
        unsigned short* sl = xt_lo;

        wt_split_kernel<<<dim3(4, 4), dim3(256), 0, stream>>>(w_out, wt_hi, wt_lo);
        wt_split_kernel<<<dim3(4, 4), dim3(256), 0, stream>>>(w_in, wt3_hi, wt3_lo);
        wt2_split_kernel<<<dim3(16), dim3(256), 0, stream>>>(
            w_off, w_mask, b_off, b_mask, wt2_hi, wt2_lo, bcat);
        xt_split_kernel<<<dim3(HW/64, CH/64, BATCH), dim3(256), 0, stream>>>(x, xt_hi, xt_lo);
        gemm_in_mfma<<<dim3(MTOT/256, CH/64), dim3(256), 0, stream>>>(
            xt_hi, xt_lo, wt3_hi, wt3_lo, b_in, v);
        dw_ln_gelu_nhwc_split<<<dim3(DWBLK), dim3(256), 0, stream>>>(
            xt_hi, xt_lo, dw_w, dw_b, ln_g, ln_b, fh, fl);
        gemm_in_mfma<<<dim3(MTOT/256, CH/64), dim3(256), 0, stream>>>(
            fh, fl, wt2_hi, wt2_lo, bcat, omb);
        sample_kernel_omb_split<<<dim3(DWBLK), dim3(256), 0, stream>>>(v, omb, sh, sl);
        gemm_out_bf16<<<dim3(MTOT/256, CH/64), dim3(256), 0, stream>>>(
            sh, sl, wt_hi, wt_lo, b_out, bn_g, bn_b, bn_mean, bn_var, out);
    }
}

// Round 13
// 224.102 us; speedup vs baseline: 1.0446x; 1.0007x over previous
//
#include <hip/hip_runtime.h>
#include <math.h>

// Problem constants
#define BATCH 8
#define CH    256
#define HDIM  56
#define WDIM  56
#define HW    (HDIM*WDIM)          // 3136
#define MTOT  (BATCH*HW)           // 25088
#define GRP   8
#define GC    32
#define NP    9                    // K*K
#define NOFF  (GRP*NP*2)           // 144
#define NMSK  (GRP*NP)             // 72
#define NTOT  (NOFF+NMSK)          // 216
#define POSB  4                    // positions per sample block
#define DWBLK (MTOT/POSB)          // 6272 (fallback dw / sample grid)
#define DW2BLK (MTOT/8)            // 3136 (main-path dw: 8 pos/block)
#define XTBLK (49*4*8)             // 1568 xt-split blocks
#define NBLKG ((MTOT/64)*2)        // 784: 392 m-tiles(64) x 2 n-tiles(128)

typedef float f32x4 __attribute__((ext_vector_type(4)));
typedef short s16x8 __attribute__((ext_vector_type(8)));

// split a,b into packed bf16 hi (truncation) and bf16 lo (exact remainder, truncated)
__device__ inline void split2(float a, float b, unsigned int& hp, unsigned int& lp)
{
    const unsigned int ua = __float_as_uint(a), ub = __float_as_uint(b);
    hp = (ub & 0xffff0000u) | (ua >> 16);
    const float ha = __uint_as_float(ua & 0xffff0000u);
    const float hb = __uint_as_float(ub & 0xffff0000u);
    const unsigned int la = __float_as_uint(a - ha), lb = __float_as_uint(b - hb);
    lp = (lb & 0xffff0000u) | (la >> 16);
}

// async global(16B/lane) -> LDS (wave-uniform base + lane*16)
__device__ __forceinline__ void gld_lds16(const unsigned short* g, unsigned short* l)
{
    __builtin_amdgcn_global_load_lds(
        (const __attribute__((address_space(1))) unsigned int*)g,
        (__attribute__((address_space(3))) unsigned int*)l, 16, 0, 0);
}

// ---------------------------------------------------------------------------
// 64m x 128n LDS-staged GEMM body (r10/r11-verified): 4 waves = 2m x 2n,
// per-wave 32m x 64n, acc[4][2]. global_load_lds width-16 staging, slot
// swizzle on both sides, 2-barrier k-loop.
// ---------------------------------------------------------------------------
__device__ __forceinline__ void gemm64x128_body(
    const unsigned short* __restrict__ ahi,
    const unsigned short* __restrict__ alo,
    const unsigned short* __restrict__ whi,
    const unsigned short* __restrict__ wlo,
    unsigned short* sAh, unsigned short* sAl,
    unsigned short* sBh, unsigned short* sBl,
    int m0, int n0g, int t, f32x4 (&acc)[4][2])
{
    const int lane = t & 63, wv4 = t >> 6;
    const int wm = wv4 >> 1;
    const int wn = wv4 & 1;
    const int fm = lane & 15, q = lane >> 4;

    const int arow0 = t >> 2;
    const int asl0  = (t & 3) ^ ((arow0 >> 1) & 3);
    const int albase0 = wv4 * 512;             // shorts; wave-uniform
    int brow[2], bsl[2], blbase[2];
    #pragma unroll
    for (int i = 0; i < 2; ++i) {
        const int u = i * 256 + t;
        brow[i] = u >> 2;
        bsl[i] = (u & 3) ^ ((brow[i] >> 1) & 3);
        blbase[i] = i * 2048 + wv4 * 512;
    }

    for (int kk = 0; kk < 8; ++kk) {
        const int k0 = kk * 32;
        {
            const size_t ga = (size_t)(m0 + arow0) * CH + k0 + asl0 * 8;
            gld_lds16(ahi + ga, sAh + albase0);
            gld_lds16(alo + ga, sAl + albase0);
        }
        #pragma unroll
        for (int i = 0; i < 2; ++i) {
            const size_t gb = (size_t)(n0g + brow[i]) * CH + k0 + bsl[i] * 8;
            gld_lds16(whi + gb, sBh + blbase[i]);
            gld_lds16(wlo + gb, sBl + blbase[i]);
        }
        __syncthreads();

        s16x8 ah[2], al[2], wh[4], wl[4];
        #pragma unroll
        for (int i = 0; i < 2; ++i) {
            const int ar = wm * 32 + i * 16 + fm;
            const int as = (q ^ ((ar >> 1) & 3)) * 8;
            ah[i] = *(const s16x8*)&sAh[ar * 32 + as];
            al[i] = *(const s16x8*)&sAl[ar * 32 + as];
        }
        #pragma unroll
        for (int i = 0; i < 4; ++i) {
            const int br = wn * 64 + i * 16 + fm;
            const int bs = (q ^ ((br >> 1) & 3)) * 8;
            wh[i] = *(const s16x8*)&sBh[br * 32 + bs];
            wl[i] = *(const s16x8*)&sBl[br * 32 + bs];
        }
        #pragma unroll
        for (int nt = 0; nt < 4; ++nt)
            #pragma unroll
            for (int mt = 0; mt < 2; ++mt) {
                acc[nt][mt] = __builtin_amdgcn_mfma_f32_16x16x32_bf16(wh[nt], ah[mt], acc[nt][mt], 0, 0, 0);
                acc[nt][mt] = __builtin_amdgcn_mfma_f32_16x16x32_bf16(wh[nt], al[mt], acc[nt][mt], 0, 0, 0);
                acc[nt][mt] = __builtin_amdgcn_mfma_f32_16x16x32_bf16(wl[nt], ah[mt], acc[nt][mt], 0, 0, 0);
            }
        __syncthreads();
    }
}

// ---------------------------------------------------------------------------
// PREP: xt_split (1568 blocks) + wt_split(w_out) + wt_split(w_in) +
// wt2_split(+bcat), fused by block-uniform bid branch. (r11-verified)
// ---------------------------------------------------------------------------
__global__ __launch_bounds__(256)
void prep_kernel(const float* __restrict__ x,
                 unsigned short* __restrict__ xt_hi,
                 unsigned short* __restrict__ xt_lo,
                 const float* __restrict__ w_out,
                 unsigned short* __restrict__ wt_hi,
                 unsigned short* __restrict__ wt_lo,
                 const float* __restrict__ w_in,
                 unsigned short* __restrict__ wt3_hi,
                 unsigned short* __restrict__ wt3_lo,
                 const float* __restrict__ w_off,
                 const float* __restrict__ w_mask,
                 const float* __restrict__ b_off,
                 const float* __restrict__ b_mask,
                 unsigned short* __restrict__ wt2_hi,
                 unsigned short* __restrict__ wt2_lo,
                 float* __restrict__ bcat)
{
    __shared__ float lds[64][68];
    const int bid = blockIdx.x;
    const int t = threadIdx.x;

    if (bid < XTBLK) {
        const int hw0 = (bid % 49) * 64;
        const int k0  = ((bid / 49) % 4) * 64;
        const int b   = bid / 196;
        #pragma unroll
        for (int p = 0; p < 4; ++p) {
            const int kr = (t >> 4) + p * 16;
            const int hc = (t & 15) * 4;
            *(float4*)&lds[kr][hc] =
                *(const float4*)(x + ((size_t)b * CH + k0 + kr) * HW + hw0 + hc);
        }
        __syncthreads();
        const int ml = t >> 2;
        const int kc = (t & 3) * 16;
        unsigned int hbuf[8], lbuf[8];
        #pragma unroll
        for (int j = 0; j < 16; j += 2)
            split2(lds[kc + j][ml], lds[kc + j + 1][ml], hbuf[j >> 1], lbuf[j >> 1]);
        const size_t row = (size_t)(b * HW + hw0 + ml) * CH + k0 + kc;
        *(uint4*)&xt_hi[row]     = *(uint4*)&hbuf[0];
        *(uint4*)&xt_hi[row + 8] = *(uint4*)&hbuf[4];
        *(uint4*)&xt_lo[row]     = *(uint4*)&lbuf[0];
        *(uint4*)&xt_lo[row + 8] = *(uint4*)&lbuf[4];
    } else if (bid < XTBLK + 32) {
        const int u = bid - XTBLK;
        const float* w = (u < 16) ? w_out : w_in;
        unsigned short* hi = (u < 16) ? wt_hi : wt3_hi;
        unsigned short* lo = (u < 16) ? wt_lo : wt3_lo;
        const int uu = u & 15;
        const int kt = (uu & 3) * 64, nt = (uu >> 2) * 64;
        #pragma unroll
        for (int p = 0; p < 4; ++p) {
            const int kr = (t >> 4) + p * 16, nc = (t & 15) * 4;
            *(float4*)&lds[kr][nc] = *(const float4*)(w + (size_t)(kt + kr) * CH + nt + nc);
        }
        __syncthreads();
        const int nl = t >> 2, kc = (t & 3) * 16;
        #pragma unroll
        for (int j = 0; j < 16; j += 2) {
            const float f0 = lds[kc + j][nl], f1 = lds[kc + j + 1][nl];
            unsigned int hp, lp;
            split2(f0, f1, hp, lp);
            *(unsigned int*)&hi[(size_t)(nt + nl) * CH + kt + kc + j] = hp;
            *(unsigned int*)&lo[(size_t)(nt + nl) * CH + kt + kc + j] = lp;
        }
    } else {
        const int u = bid - XTBLK - 32;    // 0..15
        const int n = t;
        if (u == 0) {
            bcat[n] = (n < NOFF) ? b_off[n] : ((n < NTOT) ? b_mask[n - NOFF] : 0.0f);
        }
        const int k0 = u * 16;
        #pragma unroll
        for (int j = 0; j < 16; j += 2) {
            const int k = k0 + j;
            float f0 = 0.0f, f1 = 0.0f;
            if (n < NOFF) {
                f0 = w_off[(size_t)k * NOFF + n];
                f1 = w_off[(size_t)(k + 1) * NOFF + n];
            } else if (n < NTOT) {
                f0 = w_mask[(size_t)k * NMSK + (n - NOFF)];
                f1 = w_mask[(size_t)(k + 1) * NMSK + (n - NOFF)];
            }
            unsigned int hp, lp;
            split2(f0, f1, hp, lp);
            *(unsigned int*)&wt2_hi[(size_t)n * CH + k] = hp;
            *(unsigned int*)&wt2_lo[(size_t)n * CH + k] = lp;
        }
    }
}

// ---------------------------------------------------------------------------
// dw, 2 positions per wave (8 per block, 3136 blocks): halves the per-
// position weight-staging overhead and gives each wave two independent
// load/VALU chains (ILP: loads of pos i+1 overlap GELU of pos i).
// Per-position math identical to r12 (bit-identical output).
// ---------------------------------------------------------------------------
__global__ __launch_bounds__(256)
void dw2_ln_gelu_split(const unsigned short* __restrict__ xhi,
                       const unsigned short* __restrict__ xlo,
                       const float* __restrict__ dw_w,
                       const float* __restrict__ dw_b,
                       const float* __restrict__ ln_g,
                       const float* __restrict__ ln_b,
                       unsigned short* __restrict__ fh,
                       unsigned short* __restrict__ fl)
{
    __shared__ float wt[NP][CH];
    __shared__ float lbias[CH], lgam[CH], lbet[CH];
    const int t = threadIdx.x;
    {
        const float* wp = dw_w + t * NP;
        #pragma unroll
        for (int p = 0; p < NP; ++p) wt[p][t] = wp[p];
        lbias[t] = dw_b[t]; lgam[t] = ln_g[t]; lbet[t] = ln_b[t];
    }
    __syncthreads();

    const int per  = DW2BLK / 8;           // 392
    const int bid  = blockIdx.x;
    const int sw   = (bid & 7) * per + (bid >> 3);
    const int wv   = t >> 6, lane = t & 63;
    const int c4   = lane * 4;
    const float4 b4 = *(const float4*)&lbias[c4];
    const float4 g4 = *(const float4*)&lgam[c4];
    const float4 e4 = *(const float4*)&lbet[c4];

    #pragma unroll
    for (int i = 0; i < 2; ++i) {
        const int n  = sw * 8 + wv * 2 + i;
        const int b  = n / HW;
        const int hw = n % HW;
        const int h  = hw / WDIM, w = hw % WDIM;
        const size_t base = (size_t)b * HW * CH + c4;

        float ax = 0.0f, ay = 0.0f, az = 0.0f, aw = 0.0f;
        #pragma unroll
        for (int p = 0; p < NP; ++p) {
            const int hh = h + p / 3 - 1;
            const int ww = w + p % 3 - 1;
            if ((unsigned)hh >= (unsigned)HDIM || (unsigned)ww >= (unsigned)WDIM)
                continue;                   // wave-uniform branch (h,w per-wave)
            const size_t idx = base + (size_t)(hh * WDIM + ww) * CH;
            const ushort4 uh = *(const ushort4*)(xhi + idx);
            const ushort4 ul = *(const ushort4*)(xlo + idx);
            const float4 wv4 = *(const float4*)&wt[p][c4];
            ax = fmaf(__uint_as_float((unsigned)uh.x << 16), wv4.x,
                 fmaf(__uint_as_float((unsigned)ul.x << 16), wv4.x, ax));
            ay = fmaf(__uint_as_float((unsigned)uh.y << 16), wv4.y,
                 fmaf(__uint_as_float((unsigned)ul.y << 16), wv4.y, ay));
            az = fmaf(__uint_as_float((unsigned)uh.z << 16), wv4.z,
                 fmaf(__uint_as_float((unsigned)ul.z << 16), wv4.z, az));
            aw = fmaf(__uint_as_float((unsigned)uh.w << 16), wv4.w,
                 fmaf(__uint_as_float((unsigned)ul.w << 16), wv4.w, aw));
        }
        ax += b4.x; ay += b4.y; az += b4.z; aw += b4.w;

        float s1 = ax + ay + az + aw;
        float s2 = ax*ax + ay*ay + az*az + aw*aw;
        #pragma unroll
        for (int off = 32; off > 0; off >>= 1) {
            s1 += __shfl_xor(s1, off);
            s2 += __shfl_xor(s2, off);
        }
        const float mean = s1 * (1.0f / 256.0f);
        const float rstd = rsqrtf(s2 * (1.0f / 256.0f) - mean * mean + 1e-5f);

        const float x0 = (ax - mean) * rstd * g4.x + e4.x;
        const float x1 = (ay - mean) * rstd * g4.y + e4.y;
        const float x2 = (az - mean) * rstd * g4.z + e4.z;
        const float x3 = (aw - mean) * rstd * g4.w + e4.w;
        const float o0 = 0.5f * x0 * (1.0f + erff(x0 * 0.70710678118654752f));
        const float o1 = 0.5f * x1 * (1.0f + erff(x1 * 0.70710678118654752f));
        const float o2 = 0.5f * x2 * (1.0f + erff(x2 * 0.70710678118654752f));
        const float o3 = 0.5f * x3 * (1.0f + erff(x3 * 0.70710678118654752f));

        unsigned int hp0, lp0, hp1, lp1;
        split2(o0, o1, hp0, lp0);
        split2(o2, o3, hp1, lp1);
        *(uint2*)&fh[(size_t)n * CH + c4] = make_uint2(hp0, hp1);
        *(uint2*)&fl[(size_t)n * CH + c4] = make_uint2(lp0, lp1);
    }
}

// ---------------------------------------------------------------------------
// DUAL GEMM after dw (r12-verified): both middle projections in ONE dispatch
// at the proven 12-waves/CU regime. bid<NBLKG: v = xt @ w_in; else: omb.
// ---------------------------------------------------------------------------
__global__ __launch_bounds__(256)
void gemm_dual64(const unsigned short* __restrict__ ahi1,
                 const unsigned short* __restrict__ alo1,
                 const unsigned short* __restrict__ whi1,
                 const unsigned short* __restrict__ wlo1,
                 const float* __restrict__ bias1,
                 float* __restrict__ out1,
                 const unsigned short* __restrict__ ahi2,
                 const unsigned short* __restrict__ alo2,
                 const unsigned short* __restrict__ whi2,
                 const unsigned short* __restrict__ wlo2,
                 const float* __restrict__ bias2,
                 float* __restrict__ out2)
{
    __shared__ unsigned short sAh[64*32], sAl[64*32], sBh[128*32], sBl[128*32];

    const int half = blockIdx.x >= NBLKG;
    const int lbid = blockIdx.x - (half ? NBLKG : 0);
    const unsigned short* ahi = half ? ahi2 : ahi1;
    const unsigned short* alo = half ? alo2 : alo1;
    const unsigned short* whi = half ? whi2 : whi1;
    const unsigned short* wlo = half ? wlo2 : wlo1;
    const float* bias = half ? bias2 : bias1;
    float* out = half ? out2 : out1;

    const int sw = (lbid & 7) * (NBLKG / 8) + (lbid >> 3);   // bijective 784=8*98
    const int m0  = (sw >> 1) * 64;
    const int n0g = (sw & 1) * 128;
    const int t = threadIdx.x;
    const int lane = t & 63, wv4 = t >> 6;
    const int wm = wv4 >> 1, wn = wv4 & 1;
    const int fm = lane & 15, q = lane >> 4;

    f32x4 acc[4][2];
    const f32x4 zero = {0.0f, 0.0f, 0.0f, 0.0f};
    #pragma unroll
    for (int i = 0; i < 4; ++i)
        #pragma unroll
        for (int j = 0; j < 2; ++j) acc[i][j] = zero;

    gemm64x128_body(ahi, alo, whi, wlo, sAh, sAl, sBh, sBl, m0, n0g, t, acc);

    #pragma unroll
    for (int nt = 0; nt < 4; ++nt) {
        const int n = n0g + wn*64 + nt*16 + q*4;
        const float4 b4 = *(const float4*)&bias[n];
        #pragma unroll
        for (int mt = 0; mt < 2; ++mt) {
            const int mm = m0 + wm*32 + mt*16 + fm;
            f32x4 o = acc[nt][mt];
            o[0] += b4.x; o[1] += b4.y; o[2] += b4.z; o[3] += b4.w;
            *(f32x4*)&out[(size_t)mm * CH + n] = o;
        }
    }
}

// ---------------------------------------------------------------------------
// Output GEMM, 64m x 128n tiles (r10-verified): BN+SiLU NCHW epilogue.
// ---------------------------------------------------------------------------
__global__ __launch_bounds__(256)
void gemm_out_64x128(const unsigned short* __restrict__ ahi,
                     const unsigned short* __restrict__ alo,
                     const unsigned short* __restrict__ whi,
                     const unsigned short* __restrict__ wlo,
                     const float* __restrict__ bias,
                     const float* __restrict__ bn_g,
                     const float* __restrict__ bn_b,
                     const float* __restrict__ bn_mean,
                     const float* __restrict__ bn_var,
                     float* __restrict__ y)                  // [B,256,3136]
{
    __shared__ unsigned short sAh[64*32], sAl[64*32], sBh[128*32], sBl[128*32];

    const int sw = (blockIdx.x & 7) * (NBLKG / 8) + (blockIdx.x >> 3);
    const int m0  = (sw >> 1) * 64;
    const int n0g = (sw & 1) * 128;
    const int t = threadIdx.x;
    const int lane = t & 63, wv4 = t >> 6;
    const int wm = wv4 >> 1, wn = wv4 & 1;
    const int fm = lane & 15, q = lane >> 4;

    f32x4 acc[4][2];
    const f32x4 zero = {0.0f, 0.0f, 0.0f, 0.0f};
    #pragma unroll
    for (int i = 0; i < 4; ++i)
        #pragma unroll
        for (int j = 0; j < 2; ++j) acc[i][j] = zero;

    gemm64x128_body(ahi, alo, whi, wlo, sAh, sAl, sBh, sBl, m0, n0g, t, acc);

    #pragma unroll
    for (int nt = 0; nt < 4; ++nt) {
        #pragma unroll
        for (int r = 0; r < 4; ++r) {
            const int n = n0g + wn*64 + nt*16 + q*4 + r;
            const float sc = bn_g[n] * rsqrtf(bn_var[n] + 1e-5f);
            const float sb = bn_b[n] - bn_mean[n] * sc;
            const float bs = bias[n];
            #pragma unroll
            for (int mt = 0; mt < 2; ++mt) {
                const int mm = m0 + wm*32 + mt*16 + fm;
                const int bimg = mm / HW, hw = mm % HW;
                float val = (acc[nt][mt][r] + bs) * sc + sb;
                y[(size_t)bimg * CH * HW + (size_t)n * HW + hw] = val / (1.0f + expf(-val));
            }
        }
    }
}

// ---------------------------------------------------------------------------
// Deformable sampling reading the padded omb [MTOT][256] rows
// (cols 0..143 offsets, 144..215 mask logits). Output s PRE-SPLIT bf16 hi/lo.
// ---------------------------------------------------------------------------
__global__ __launch_bounds__(256)
void sample_kernel_omb_split(const float* __restrict__ v,
                             const float* __restrict__ omb,
                             unsigned short* __restrict__ sh,  // [MTOT][256]
                             unsigned short* __restrict__ sl)  // [MTOT][256]
{
    __shared__ alignas(16) float loff[POSB][NOFF];
    __shared__ alignas(16) float lmsk[POSB][NMSK];
    __shared__ alignas(16) float wtab[POSB][GRP*NP][4];
    __shared__ alignas(16) int   itab[POSB][GRP*NP][4];

    const int per  = DWBLK / 8;              // 784
    const int bid  = blockIdx.x;
    const int sw   = (bid % 8) * per + (bid / 8);
    const int n0 = sw * POSB;
    const int t = threadIdx.x;

    if (t < POSB * (NOFF/4)) {
        const int q = t / (NOFF/4), r = t % (NOFF/4);
        *(float4*)&loff[q][r*4] = *(const float4*)&omb[(size_t)(n0+q)*CH + r*4];
    } else if (t < POSB * (NOFF/4) + POSB * (NMSK/4)) {
        const int u = t - POSB * (NOFF/4);
        const int q = u / (NMSK/4), r = u % (NMSK/4);
        *(float4*)&lmsk[q][r*4] = *(const float4*)&omb[(size_t)(n0+q)*CH + NOFF + r*4];
    }
    __syncthreads();

    if (t < POSB * GRP) {
        const int q = t >> 3, g = t & 7;
        float* mm = &lmsk[q][g * NP];
        float mx = -1e30f;
        #pragma unroll
        for (int p = 0; p < NP; ++p) mx = fmaxf(mx, mm[p]);
        float sum = 0.0f;
        #pragma unroll
        for (int p = 0; p < NP; ++p) { const float e = __expf(mm[p] - mx); mm[p] = e; sum += e; }
        const float inv = 1.0f / sum;
        #pragma unroll
        for (int p = 0; p < NP; ++p) mm[p] *= inv;
    }
    __syncthreads();

    for (int u = t; u < POSB * GRP * NP; u += 256) {
        const int q = u / (GRP*NP), j = u % (GRP*NP);
        const int g = j / NP, p = j % NP;
        const int n = n0 + q;
        const int hw = n % HW;
        const int h = hw / WDIM, w = hw % WDIM;
        const float ox = loff[q][g*18 + p*2 + 0];
        const float oy = loff[q][g*18 + p*2 + 1];
        const float m  = lmsk[q][g*NP + p];
        const float px = (float)(w + p/3) + ox;
        const float py = (float)(h + p%3) + oy;
        const float fx = floorf(px), fy = floorf(py);
        const float wx = px - fx, wy = py - fy;
        const int x0 = (int)fx, y0 = (int)fy;
        const int x1 = x0 + 1, y1 = y0 + 1;
        const float vx0 = (x0 >= 1 && x0 < 57) ? 1.0f : 0.0f;
        const float vx1 = (x1 >= 1 && x1 < 57) ? 1.0f : 0.0f;
        const float vy0 = (y0 >= 1 && y0 < 57) ? 1.0f : 0.0f;
        const float vy1 = (y1 >= 1 && y1 < 57) ? 1.0f : 0.0f;
        const int x0c = min(max(x0, 1), 56), x1c = min(max(x1, 1), 56);
        const int y0c = min(max(y0, 1), 56), y1c = min(max(y1, 1), 56);
        wtab[q][j][0] = m * (1.0f-wx) * (1.0f-wy) * vx0 * vy0;
        wtab[q][j][1] = m * wx        * (1.0f-wy) * vx1 * vy0;
        wtab[q][j][2] = m * (1.0f-wx) * wy        * vx0 * vy1;
        wtab[q][j][3] = m * wx        * wy        * vx1 * vy1;
        itab[q][j][0] = ((y0c-1)*WDIM + (x0c-1)) * CH;
        itab[q][j][1] = ((y0c-1)*WDIM + (x1c-1)) * CH;
        itab[q][j][2] = ((y1c-1)*WDIM + (x0c-1)) * CH;
        itab[q][j][3] = ((y1c-1)*WDIM + (x1c-1)) * CH;
    }
    __syncthreads();

    const int q = t >> 6, lane = t & 63;
    const int n = n0 + q;
    const int b = n / HW;
    const int g = lane >> 3;
    const float* vb = v + (size_t)b*HW*CH + lane*4;
    float4 acc = {0.0f, 0.0f, 0.0f, 0.0f};
    #pragma unroll
    for (int p = 0; p < NP; ++p) {
        const int j = g*NP + p;
        const float4 wv = *(const float4*)&wtab[q][j][0];
        const int4  iv = *(const int4*)&itab[q][j][0];
        const float4 c0 = *(const float4*)(vb + iv.x);
        const float4 c1 = *(const float4*)(vb + iv.y);
        const float4 c2 = *(const float4*)(vb + iv.z);
        const float4 c3 = *(const float4*)(vb + iv.w);
        acc.x += wv.x*c0.x + wv.y*c1.x + wv.z*c2.x + wv.w*c3.x;
        acc.y += wv.x*c0.y + wv.y*c1.y + wv.z*c2.y + wv.w*c3.y;
        acc.z += wv.x*c0.z + wv.y*c1.z + wv.z*c2.z + wv.w*c3.z;
        acc.w += wv.x*c0.w + wv.y*c1.w + wv.z*c2.w + wv.w*c3.w;
    }
    unsigned int hp0, lp0, hp1, lp1;
    split2(acc.x, acc.y, hp0, lp0);
    split2(acc.z, acc.w, hp1, lp1);
    *(uint2*)&sh[(size_t)n*CH + lane*4] = make_uint2(hp0, hp1);
    *(uint2*)&sl[(size_t)n*CH + lane*4] = make_uint2(lp0, lp1);
}

// ===================== FALLBACK KERNELS (round-5 verified) =====================
__global__ __launch_bounds__(256)
void xt_split_kernel(const float* __restrict__ x,
                     unsigned short* __restrict__ hi,
                     unsigned short* __restrict__ lo)
{
    __shared__ float lds[64][68];
    const int hw0 = blockIdx.x * 64;
    const int k0  = blockIdx.y * 64;
    const int b   = blockIdx.z;
    const int t = threadIdx.x;
    #pragma unroll
    for (int p = 0; p < 4; ++p) {
        const int kr = (t >> 4) + p * 16;
        const int hc = (t & 15) * 4;
        *(float4*)&lds[kr][hc] =
            *(const float4*)(x + ((size_t)b * CH + k0 + kr) * HW + hw0 + hc);
    }
    __syncthreads();
    const int ml = t >> 2;
    const int kc = (t & 3) * 16;
    unsigned int hbuf[8], lbuf[8];
    #pragma unroll
    for (int j = 0; j < 16; j += 2)
        split2(lds[kc + j][ml], lds[kc + j + 1][ml], hbuf[j >> 1], lbuf[j >> 1]);
    const size_t row = (size_t)(b * HW + hw0 + ml) * CH + k0 + kc;
    *(uint4*)&hi[row]     = *(uint4*)&hbuf[0];
    *(uint4*)&hi[row + 8] = *(uint4*)&hbuf[4];
    *(uint4*)&lo[row]     = *(uint4*)&lbuf[0];
    *(uint4*)&lo[row + 8] = *(uint4*)&lbuf[4];
}

__global__ __launch_bounds__(256)
void wt_split_kernel(const float* __restrict__ w,
                     unsigned short* __restrict__ hi,
                     unsigned short* __restrict__ lo)
{
    __shared__ float lds[64][68];
    const int kt = blockIdx.x * 64, nt = blockIdx.y * 64;
    const int t = threadIdx.x;
    #pragma unroll
    for (int p = 0; p < 4; ++p) {
        const int kr = (t >> 4) + p * 16, nc = (t & 15) * 4;
        *(float4*)&lds[kr][nc] = *(const float4*)(w + (size_t)(kt + kr) * CH + nt + nc);
    }
    __syncthreads();
    const int nl = t >> 2, kc = (t & 3) * 16;
    #pragma unroll
    for (int j = 0; j < 16; j += 2) {
        const float f0 = lds[kc + j][nl], f1 = lds[kc + j + 1][nl];
        unsigned int hp, lp;
        split2(f0, f1, hp, lp);
        *(unsigned int*)&hi[(size_t)(nt + nl) * CH + kt + kc + j] = hp;
        *(unsigned int*)&lo[(size_t)(nt + nl) * CH + kt + kc + j] = lp;
    }
}

__global__ __launch_bounds__(256)
void wt2_split_kernel(const float* __restrict__ w_off,
                      const float* __restrict__ w_mask,
                      const float* __restrict__ b_off,
                      const float* __restrict__ b_mask,
                      unsigned short* __restrict__ hi,
                      unsigned short* __restrict__ lo,
                      float* __restrict__ bcat)
{
    const int n = threadIdx.x;
    if (blockIdx.x == 0) {
        bcat[n] = (n < NOFF) ? b_off[n] : ((n < NTOT) ? b_mask[n - NOFF] : 0.0f);
    }
    const int k0 = blockIdx.x * 16;
    #pragma unroll
    for (int j = 0; j < 16; j += 2) {
        const int k = k0 + j;
        float f0 = 0.0f, f1 = 0.0f;
        if (n < NOFF) {
            f0 = w_off[(size_t)k * NOFF + n];
            f1 = w_off[(size_t)(k + 1) * NOFF + n];
        } else if (n < NTOT) {
            f0 = w_mask[(size_t)k * NMSK + (n - NOFF)];
            f1 = w_mask[(size_t)(k + 1) * NMSK + (n - NOFF)];
        }
        unsigned int hp, lp;
        split2(f0, f1, hp, lp);
        *(unsigned int*)&hi[(size_t)n * CH + k] = hp;
        *(unsigned int*)&lo[(size_t)n * CH + k] = lp;
    }
}

__global__ __launch_bounds__(256)
void gemm_in_mfma(const unsigned short* __restrict__ xhi,
                  const unsigned short* __restrict__ xlo,
                  const unsigned short* __restrict__ whi,
                  const unsigned short* __restrict__ wlo,
                  const float* __restrict__ bias,
                  float* __restrict__ v)
{
    const int m0 = blockIdx.x * 256;
    const int n0 = blockIdx.y * 64;
    const int t = threadIdx.x;
    const int lane = t & 63, wv = t >> 6;
    const int mblk = m0 + wv * 64;
    const int fm = lane & 15;
    const int q  = lane >> 4;

    f32x4 acc[4][4];
    const f32x4 zero = {0.0f, 0.0f, 0.0f, 0.0f};
    #pragma unroll
    for (int i = 0; i < 4; ++i)
        #pragma unroll
        for (int j = 0; j < 4; ++j) acc[i][j] = zero;

    const unsigned short *xrh[4], *xrl[4], *wrh[4], *wrl[4];
    #pragma unroll
    for (int mt = 0; mt < 4; ++mt) {
        xrh[mt] = xhi + (size_t)(mblk + mt*16 + fm) * CH + q * 8;
        xrl[mt] = xlo + (size_t)(mblk + mt*16 + fm) * CH + q * 8;
    }
    #pragma unroll
    for (int nt = 0; nt < 4; ++nt) {
        wrh[nt] = whi + (size_t)(n0 + nt*16 + fm) * CH + q * 8;
        wrl[nt] = wlo + (size_t)(n0 + nt*16 + fm) * CH + q * 8;
    }

    for (int k0 = 0; k0 < CH; k0 += 32) {
        s16x8 wh[4], wl[4], ah[4], al[4];
        #pragma unroll
        for (int nt = 0; nt < 4; ++nt) {
            wh[nt] = *(const s16x8*)(wrh[nt] + k0);
            wl[nt] = *(const s16x8*)(wrl[nt] + k0);
        }
        #pragma unroll
        for (int mt = 0; mt < 4; ++mt) {
            ah[mt] = *(const s16x8*)(xrh[mt] + k0);
            al[mt] = *(const s16x8*)(xrl[mt] + k0);
        }
        #pragma unroll
        for (int nt = 0; nt < 4; ++nt)
            #pragma unroll
            for (int mt = 0; mt < 4; ++mt) {
                acc[nt][mt] = __builtin_amdgcn_mfma_f32_16x16x32_bf16(wh[nt], ah[mt], acc[nt][mt], 0, 0, 0);
                acc[nt][mt] = __builtin_amdgcn_mfma_f32_16x16x32_bf16(wh[nt], al[mt], acc[nt][mt], 0, 0, 0);
                acc[nt][mt] = __builtin_amdgcn_mfma_f32_16x16x32_bf16(wl[nt], ah[mt], acc[nt][mt], 0, 0, 0);
            }
    }

    #pragma unroll
    for (int nt = 0; nt < 4; ++nt) {
        const float4 b4 = *(const float4*)&bias[n0 + nt*16 + q*4];
        #pragma unroll
        for (int mt = 0; mt < 4; ++mt) {
            f32x4 o = acc[nt][mt];
            o[0] += b4.x; o[1] += b4.y; o[2] += b4.z; o[3] += b4.w;
            *(f32x4*)&v[(size_t)(mblk + mt*16 + fm) * CH + n0 + nt*16 + q*4] = o;
        }
    }
}

__global__ __launch_bounds__(256)
void dw_ln_gelu_nhwc_split(const unsigned short* __restrict__ xhi,
                           const unsigned short* __restrict__ xlo,
                           const float* __restrict__ dw_w,
                           const float* __restrict__ dw_b,
                           const float* __restrict__ ln_g,
                           const float* __restrict__ ln_b,
                           unsigned short* __restrict__ fh,
                           unsigned short* __restrict__ fl)
{
    __shared__ float wt[NP][CH];
    __shared__ float lbias[CH], lgam[CH], lbet[CH];
    const int t = threadIdx.x;
    {
        const float* wp = dw_w + t * NP;
        #pragma unroll
        for (int p = 0; p < NP; ++p) wt[p][t] = wp[p];
        lbias[t] = dw_b[t]; lgam[t] = ln_g[t]; lbet[t] = ln_b[t];
    }
    __syncthreads();

    const int per  = DWBLK / 8;
    const int bid  = blockIdx.x;
    const int sw   = (bid & 7) * per + (bid >> 3);
    const int q    = t >> 6, lane = t & 63;
    const int n    = sw * POSB + q;
    const int b    = n / HW;
    const int hw   = n % HW;
    const int h    = hw / WDIM, w = hw % WDIM;
    const int c4   = lane * 4;
    const size_t base = (size_t)b * HW * CH + c4;

    float ax = 0.0f, ay = 0.0f, az = 0.0f, aw = 0.0f;
    #pragma unroll
    for (int p = 0; p < NP; ++p) {
        const int hh = h + p / 3 - 1;
        const int ww = w + p % 3 - 1;
        if ((unsigned)hh >= (unsigned)HDIM || (unsigned)ww >= (unsigned)WDIM)
            continue;
        const size_t idx = base + (size_t)(hh * WDIM + ww) * CH;
        const ushort4 uh = *(const ushort4*)(xhi + idx);
        const ushort4 ul = *(const ushort4*)(xlo + idx);
        const float4 wv = *(const float4*)&wt[p][c4];
        ax = fmaf(__uint_as_float((unsigned)uh.x << 16), wv.x,
             fmaf(__uint_as_float((unsigned)ul.x << 16), wv.x, ax));
        ay = fmaf(__uint_as_float((unsigned)uh.y << 16), wv.y,
             fmaf(__uint_as_float((unsigned)ul.y << 16), wv.y, ay));
        az = fmaf(__uint_as_float((unsigned)uh.z << 16), wv.z,
             fmaf(__uint_as_float((unsigned)ul.z << 16), wv.z, az));
        aw = fmaf(__uint_as_float((unsigned)uh.w << 16), wv.w,
             fmaf(__uint_as_float((unsigned)ul.w << 16), wv.w, aw));
    }
    {
        const float4 b4 = *(const float4*)&lbias[c4];
        ax += b4.x; ay += b4.y; az += b4.z; aw += b4.w;
    }
    float s1 = ax + ay + az + aw;
    float s2 = ax*ax + ay*ay + az*az + aw*aw;
    #pragma unroll
    for (int off = 32; off > 0; off >>= 1) {
        s1 += __shfl_xor(s1, off);
        s2 += __shfl_xor(s2, off);
    }
    const float mean = s1 * (1.0f / 256.0f);
    const float rstd = rsqrtf(s2 * (1.0f / 256.0f) - mean * mean + 1e-5f);
    const float4 g4 = *(const float4*)&lgam[c4];
    const float4 e4 = *(const float4*)&lbet[c4];
    const float x0 = (ax - mean) * rstd * g4.x + e4.x;
    const float x1 = (ay - mean) * rstd * g4.y + e4.y;
    const float x2 = (az - mean) * rstd * g4.z + e4.z;
    const float x3 = (aw - mean) * rstd * g4.w + e4.w;
    const float o0 = 0.5f * x0 * (1.0f + erff(x0 * 0.70710678118654752f));
    const float o1 = 0.5f * x1 * (1.0f + erff(x1 * 0.70710678118654752f));
    const float o2 = 0.5f * x2 * (1.0f + erff(x2 * 0.70710678118654752f));
    const float o3 = 0.5f * x3 * (1.0f + erff(x3 * 0.70710678118654752f));
    unsigned int hp0, lp0, hp1, lp1;
    split2(o0, o1, hp0, lp0);
    split2(o2, o3, hp1, lp1);
    *(uint2*)&fh[(size_t)n * CH + c4] = make_uint2(hp0, hp1);
    *(uint2*)&fl[(size_t)n * CH + c4] = make_uint2(lp0, lp1);
}

__global__ __launch_bounds__(256)
void gemm_out_bf16(const unsigned short* __restrict__ shp,
                   const unsigned short* __restrict__ slp,
                   const unsigned short* __restrict__ whi,
                   const unsigned short* __restrict__ wlo,
                   const float* __restrict__ bias,
                   const float* __restrict__ bn_g,
                   const float* __restrict__ bn_b,
                   const float* __restrict__ bn_mean,
                   const float* __restrict__ bn_var,
                   float* __restrict__ y)
{
    const int m0 = blockIdx.x * 256;
    const int n0 = blockIdx.y * 64;
    const int t = threadIdx.x;
    const int lane = t & 63, wv = t >> 6;
    const int mblk = m0 + wv * 64;
    const int fm = lane & 15;
    const int q  = lane >> 4;

    f32x4 acc[4][4];
    const f32x4 zero = {0.0f, 0.0f, 0.0f, 0.0f};
    #pragma unroll
    for (int i = 0; i < 4; ++i)
        #pragma unroll
        for (int j = 0; j < 4; ++j) acc[i][j] = zero;

    const unsigned short *xrh[4], *xrl[4], *wrh[4], *wrl[4];
    #pragma unroll
    for (int mt = 0; mt < 4; ++mt) {
        xrh[mt] = shp + (size_t)(mblk + mt*16 + fm) * CH + q * 8;
        xrl[mt] = slp + (size_t)(mblk + mt*16 + fm) * CH + q * 8;
    }
    #pragma unroll
    for (int nt = 0; nt < 4; ++nt) {
        wrh[nt] = whi + (size_t)(n0 + nt*16 + fm) * CH + q * 8;
        wrl[nt] = wlo + (size_t)(n0 + nt*16 + fm) * CH + q * 8;
    }

    for (int k0 = 0; k0 < CH; k0 += 32) {
        s16x8 wh[4], wl[4], ah[4], al[4];
        #pragma unroll
        for (int nt = 0; nt < 4; ++nt) {
            wh[nt] = *(const s16x8*)(wrh[nt] + k0);
            wl[nt] = *(const s16x8*)(wrl[nt] + k0);
        }
        #pragma unroll
        for (int mt = 0; mt < 4; ++mt) {
            ah[mt] = *(const s16x8*)(xrh[mt] + k0);
            al[mt] = *(const s16x8*)(xrl[mt] + k0);
        }
        #pragma unroll
        for (int nt = 0; nt < 4; ++nt)
            #pragma unroll
            for (int mt = 0; mt < 4; ++mt) {
                acc[nt][mt] = __builtin_amdgcn_mfma_f32_16x16x32_bf16(wh[nt], ah[mt], acc[nt][mt], 0, 0, 0);
                acc[nt][mt] = __builtin_amdgcn_mfma_f32_16x16x32_bf16(wh[nt], al[mt], acc[nt][mt], 0, 0, 0);
                acc[nt][mt] = __builtin_amdgcn_mfma_f32_16x16x32_bf16(wl[nt], ah[mt], acc[nt][mt], 0, 0, 0);
            }
    }

    #pragma unroll
    for (int nt = 0; nt < 4; ++nt) {
        #pragma unroll
        for (int r = 0; r < 4; ++r) {
            const int n = n0 + nt*16 + q*4 + r;
            const float sc = bn_g[n] * rsqrtf(bn_var[n] + 1e-5f);
            const float sb = bn_b[n] - bn_mean[n] * sc;
            const float bs = bias[n];
            #pragma unroll
            for (int mt = 0; mt < 4; ++mt) {
                const int mm = mblk + mt*16;
                const size_t base = (size_t)(mm / HW) * CH * HW + (mm % HW);
                float val = (acc[nt][mt][r] + bs) * sc + sb;
                y[base + (size_t)n * HW + fm] = val / (1.0f + expf(-val));
            }
        }
    }
}

extern "C" void kernel_launch(void* const* d_in, const int* in_sizes, int n_in,
                              void* d_out, int out_size, void* d_ws, size_t ws_size,
                              hipStream_t stream) {
    const float* x      = (const float*)d_in[0];
    const float* w_in   = (const float*)d_in[1];
    const float* b_in   = (const float*)d_in[2];
    const float* dw_w   = (const float*)d_in[3];
    const float* dw_b   = (const float*)d_in[4];
    const float* ln_g   = (const float*)d_in[5];
    const float* ln_b   = (const float*)d_in[6];
    const float* w_off  = (const float*)d_in[7];
    const float* b_off  = (const float*)d_in[8];
    const float* w_mask = (const float*)d_in[9];
    const float* b_mask = (const float*)d_in[10];
    const float* w_out  = (const float*)d_in[11];
    const float* b_out  = (const float*)d_in[12];
    const float* bn_g   = (const float*)d_in[13];
    const float* bn_b   = (const float*)d_in[14];
    const float* bn_mean= (const float*)d_in[15];
    const float* bn_var = (const float*)d_in[16];
    float* out = (float*)d_out;

    const size_t SZ = (size_t)MTOT * CH;                 // elements
    // Layout: v | xt_hi,xt_lo | fh,fl | omb | weights | bcat
    const size_t need_new =
        4 * SZ * sizeof(float)
        + 6 * (size_t)CH * CH * sizeof(unsigned short)
        + CH * sizeof(float);

    if (ws_size >= need_new) {
        // -------- main path: 5 dispatches --------
        float* ws = (float*)d_ws;
        float* v    = ws;                                          // SZ f32
        unsigned short* xt_hi = (unsigned short*)(v + SZ);         // SZ us
        unsigned short* xt_lo = xt_hi + SZ;                        // SZ us
        unsigned short* fh    = xt_lo + SZ;                        // SZ us
        unsigned short* fl    = fh + SZ;                           // SZ us
        float* omb  = (float*)(fl + SZ);                           // SZ f32
        unsigned short* wt_hi  = (unsigned short*)(omb + SZ);
        unsigned short* wt_lo  = wt_hi + CH * CH;
        unsigned short* wt2_hi = wt_lo + CH * CH;
        unsigned short* wt2_lo = wt2_hi + CH * CH;
        unsigned short* wt3_hi = wt2_lo + CH * CH;
        unsigned short* wt3_lo = wt3_hi + CH * CH;
        float* bcat = (float*)(wt3_lo + CH * CH);                  // 256 f32
        // sh/sl overlay xt region (xt fully consumed before sample writes).
        unsigned short* sh = xt_hi;
        unsigned short* sl = xt_lo;

        prep_kernel<<<dim3(XTBLK + 48), dim3(256), 0, stream>>>(
            x, xt_hi, xt_lo, w_out, wt_hi, wt_lo, w_in, wt3_hi, wt3_lo,
            w_off, w_mask, b_off, b_mask, wt2_hi, wt2_lo, bcat);
        dw2_ln_gelu_split<<<dim3(DW2BLK), dim3(256), 0, stream>>>(
            xt_hi, xt_lo, dw_w, dw_b, ln_g, ln_b, fh, fl);
        gemm_dual64<<<dim3(2 * NBLKG), dim3(256), 0, stream>>>(
            xt_hi, xt_lo, wt3_hi, wt3_lo, b_in, v,
            fh, fl, wt2_hi, wt2_lo, bcat, omb);
        sample_kernel_omb_split<<<dim3(DWBLK), dim3(256), 0, stream>>>(v, omb, sh, sl);
        gemm_out_64x128<<<dim3(NBLKG), dim3(256), 0, stream>>>(
            sh, sl, wt_hi, wt_lo, b_out, bn_g, bn_b, bn_mean, bn_var, out);
    } else {
        // -------- fallback: round-5 verified path --------
        float* ws = (float*)d_ws;
        float* v    = ws;
        unsigned short* xt_hi = (unsigned short*)(v + SZ);
        unsigned short* xt_lo = xt_hi + SZ;
        unsigned short* fh    = xt_lo + SZ;
        unsigned short* fl    = fh + SZ;
        float* omb  = (float*)(fl + SZ);
        unsigned short* wt_hi  = (unsigned short*)(omb + SZ);
        unsigned short* wt_lo  = wt_hi + CH * CH;
        unsigned short* wt2_hi = wt_lo + CH * CH;
        unsigned short* wt2_lo = wt2_hi + CH * CH;
        unsigned short* wt3_hi = wt2_lo + CH * CH;
        unsigned short* wt3_lo = wt3_hi + CH * CH;
        float* bcat = (float*)(wt3_lo + CH * CH);
        unsigned short* sh = xt_hi;
        unsigned short* sl = xt_lo;

        wt_split_kernel<<<dim3(4, 4), dim3(256), 0, stream>>>(w_out, wt_hi, wt_lo);
        wt_split_kernel<<<dim3(4, 4), dim3(256), 0, stream>>>(w_in, wt3_hi, wt3_lo);
        wt2_split_kernel<<<dim3(16), dim3(256), 0, stream>>>(
            w_off, w_mask, b_off, b_mask, wt2_hi, wt2_lo, bcat);
        xt_split_kernel<<<dim3(HW/64, CH/64, BATCH), dim3(256), 0, stream>>>(x, xt_hi, xt_lo);
        gemm_in_mfma<<<dim3(MTOT/256, CH/64), dim3(256), 0, stream>>>(
            xt_hi, xt_lo, wt3_hi, wt3_lo, b_in, v);
        dw_ln_gelu_nhwc_split<<<dim3(DWBLK), dim3(256), 0, stream>>>(
            xt_hi, xt_lo, dw_w, dw_b, ln_g, ln_b, fh, fl);
        gemm_in_mfma<<<dim3(MTOT/256, CH/64), dim3(256), 0, stream>>>(
            fh, fl, wt2_hi, wt2_lo, bcat, omb);
        sample_kernel_omb_split<<<dim3(DWBLK), dim3(256), 0, stream>>>(v, omb, sh, sl);
        gemm_out_bf16<<<dim3(MTOT/256, CH/64), dim3(256), 0, stream>>>(
            sh, sl, wt_hi, wt_lo, b_out, bn_g, bn_b, bn_mean, bn_var, out);
    }
}